// Round 1
// baseline (3916.083 us; speedup 1.0000x reference)
//
#include <hip/hip_runtime.h>
#include <cstdint>
#include <cstddef>

#define TT 2048
#define CC 768
#define KK 5

// ---------------- device RNG hash ----------------
__device__ __forceinline__ unsigned int mix_hash(unsigned int a, unsigned int b) {
  unsigned long long x = (((unsigned long long)a) << 32) | (unsigned long long)b;
  x ^= x >> 33; x *= 0xff51afd7ed558ccdULL;
  x ^= x >> 33; x *= 0xc4ceb9fe1a85ec53ULL;
  x ^= x >> 33;
  return (unsigned int)(x & 0xffffffffu);
}

// ---------------- row norms ----------------
__global__ __launch_bounds__(256) void rownorm_kernel(const float* __restrict__ z1, const float* __restrict__ z2,
                                                      float* __restrict__ sq, float* __restrict__ inv) {
  int r = blockIdx.x;
  const float* p = (r < 4 * TT) ? (z1 + (size_t)r * CC) : (z2 + (size_t)(r - 4 * TT) * CC);
  float s = 0.f;
  for (int k = threadIdx.x; k < CC; k += 256) { float v = p[k]; s += v * v; }
  __shared__ float red[256];
  red[threadIdx.x] = s; __syncthreads();
  for (int off = 128; off > 0; off >>= 1) {
    if (threadIdx.x < off) red[threadIdx.x] += red[threadIdx.x + off];
    __syncthreads();
  }
  if (threadIdx.x == 0) { sq[r] = red[0]; inv[r] = rsqrtf(red[0] + 1e-12f); }
}

// ---------------- gram: G[i][j] = dot(A_i, B_j), A,B are 2048x768 ----------------
__global__ __launch_bounds__(256) void gram_kernel(const float* __restrict__ A, const float* __restrict__ B,
                                                   float* __restrict__ G) {
  __shared__ float As[32][68];
  __shared__ float Bs[32][68];
  int tx = threadIdx.x & 15, ty = threadIdx.x >> 4;
  int bm = blockIdx.y * 64, bn = blockIdx.x * 64;
  float acc[4][4] = {{0.f}};
  for (int kk = 0; kk < CC; kk += 32) {
    for (int l = threadIdx.x; l < 2048; l += 256) {
      int m = l >> 5, k = l & 31;
      As[k][m] = A[(size_t)(bm + m) * CC + kk + k];
      Bs[k][m] = B[(size_t)(bn + m) * CC + kk + k];
    }
    __syncthreads();
#pragma unroll
    for (int k = 0; k < 32; ++k) {
      float4 a4 = *(const float4*)&As[k][ty * 4];
      float4 b4 = *(const float4*)&Bs[k][tx * 4];
      float av[4] = {a4.x, a4.y, a4.z, a4.w};
      float bv[4] = {b4.x, b4.y, b4.z, b4.w};
#pragma unroll
      for (int i = 0; i < 4; ++i)
#pragma unroll
        for (int j = 0; j < 4; ++j) acc[i][j] = fmaf(av[i], bv[j], acc[i][j]);
    }
    __syncthreads();
  }
#pragma unroll
  for (int i = 0; i < 4; ++i)
#pragma unroll
    for (int j = 0; j < 4; ++j)
      G[(size_t)(bm + ty * 4 + i) * TT + bn + tx * 4 + j] = acc[i][j];
}

// ---------------- top-5 smallest per row, excluding self ----------------
// mode 0: key[j] = sq[j] - 2*G[i][j]        (sq-dist ranking)
// mode 1: key[j] = -G[i][j]*inv[j]          (cos-dist ranking)
__global__ __launch_bounds__(256) void top5_kernel(const float* __restrict__ G, const float* __restrict__ sq,
                                                   const float* __restrict__ inv, int mode, int* __restrict__ out) {
  int i = blockIdx.x;
  __shared__ float vred[256];
  __shared__ int ired[256];
  __shared__ int sel_sh[KK];
  for (int r = 0; r < KK; ++r) {
    float best = INFINITY; int bidx = TT;
    for (int j = threadIdx.x; j < TT; j += 256) {
      if (j == i) continue;
      bool skip = false;
      for (int t = 0; t < r; ++t) if (sel_sh[t] == j) skip = true;
      if (skip) continue;
      float g = G[(size_t)i * TT + j];
      float key = (mode == 0) ? (sq[j] - 2.f * g) : (-g * inv[j]);
      if (key < best || (key == best && j < bidx)) { best = key; bidx = j; }
    }
    vred[threadIdx.x] = best; ired[threadIdx.x] = bidx;
    __syncthreads();
    for (int off = 128; off > 0; off >>= 1) {
      if (threadIdx.x < off) {
        float v2 = vred[threadIdx.x + off]; int i2 = ired[threadIdx.x + off];
        if (v2 < vred[threadIdx.x] || (v2 == vred[threadIdx.x] && i2 < ired[threadIdx.x])) {
          vred[threadIdx.x] = v2; ired[threadIdx.x] = i2;
        }
      }
      __syncthreads();
    }
    if (threadIdx.x == 0) sel_sh[r] = ired[0];
    __syncthreads();
  }
  if (threadIdx.x < KK) out[(size_t)i * KK + threadIdx.x] = sel_sh[threadIdx.x];
}

// ---------------- argmin of cos-dist per row (along_col=0) or per column (along_col=1) ----------------
__global__ __launch_bounds__(256) void argmin_kernel(const float* __restrict__ G, const float* __restrict__ invOther,
                                                     int along_col, int* __restrict__ out) {
  int i = blockIdx.x;
  __shared__ float vred[256];
  __shared__ int ired[256];
  float best = INFINITY; int bidx = TT;
  for (int j = threadIdx.x; j < TT; j += 256) {
    float g = along_col ? G[(size_t)j * TT + i] : G[(size_t)i * TT + j];
    float key = -g * invOther[j];
    if (key < best || (key == best && j < bidx)) { best = key; bidx = j; }
  }
  vred[threadIdx.x] = best; ired[threadIdx.x] = bidx;
  __syncthreads();
  for (int off = 128; off > 0; off >>= 1) {
    if (threadIdx.x < off) {
      float v2 = vred[threadIdx.x + off]; int i2 = ired[threadIdx.x + off];
      if (v2 < vred[threadIdx.x] || (v2 == vred[threadIdx.x] && i2 < ired[threadIdx.x])) {
        vred[threadIdx.x] = v2; ired[threadIdx.x] = i2;
      }
    }
    __syncthreads();
  }
  if (threadIdx.x == 0) out[i] = ired[0];
}

// ---------------- mutual matching ----------------
__global__ __launch_bounds__(256) void mutual_kernel(const int* __restrict__ b_of_a, const int* __restrict__ a_of_b,
                                                     int* __restrict__ idxB_of_A, int* __restrict__ matchedB,
                                                     int* __restrict__ unmatched, int* __restrict__ scalars) {
  __shared__ int cnt_sh;
  for (int j = threadIdx.x; j < TT; j += 256) matchedB[j] = 0;
  __syncthreads();
  for (int i = threadIdx.x; i < TT; i += 256) {
    int b = b_of_a[i];
    bool mut = (a_of_b[b] == i);
    idxB_of_A[i] = mut ? b : -1;
    if (mut) matchedB[b] = 1;  // at most one writer per b (mutual matches are 1-1)
  }
  __syncthreads();
  if (threadIdx.x == 0) cnt_sh = 0;
  __syncthreads();
  for (int j = threadIdx.x; j < TT; j += 256) {
    if (!matchedB[j]) { int p = atomicAdd(&cnt_sh, 1); unmatched[p] = j; }
  }
  __syncthreads();
  if (threadIdx.x == 0) {
    int c = cnt_sh;
    if (c == 0) { unmatched[0] = 0; c = 1; }
    scalars[0] = c;
  }
}

// ---------------- wave-level dot of two 768-float rows ----------------
__device__ __forceinline__ float wave_dot(const float* __restrict__ x, const float* __restrict__ y) {
  int lane = threadIdx.x & 63;
  float s = 0.f;
#pragma unroll
  for (int m = 0; m < CC / 64; ++m) s = fmaf(x[lane + m * 64], y[lane + m * 64], s);
#pragma unroll
  for (int off = 32; off > 0; off >>= 1) s += __shfl_down(s, off, 64);
  return s;  // valid on lane 0
}

// ---------------- NRC hinge per A-row ----------------
__global__ __launch_bounds__(256) void nrc_hinge_kernel(const float* __restrict__ Bd, const float* __restrict__ invB,
                                                        const int* __restrict__ neighA, const int* __restrict__ idxB_of_A,
                                                        const int* __restrict__ unmatched, const int* __restrict__ scalars,
                                                        unsigned int seed, float* __restrict__ acc) {
  int i = blockIdx.x;
  __shared__ int targets[10];
  __shared__ int tmask[KK];
  __shared__ float dots[10];
  if (threadIdx.x == 0) {
    unsigned int neg_count = (unsigned int)scalars[0];
    for (int k = 0; k < KK; ++k) {
      int nb = neighA[(size_t)i * KK + k];
      int pb = idxB_of_A[nb];
      tmask[k] = (pb >= 0) ? 1 : 0;
      targets[k] = (pb >= 0) ? pb : 0;
      unsigned int r = mix_hash(seed ^ 0xA5A5u, (unsigned)(i * KK + k)) & (TT - 1);
      targets[KK + k] = unmatched[r % neg_count];
    }
  }
  __syncthreads();
  int idx = idxB_of_A[i];
  int u = idx >= 0 ? idx : 0;
  int wave = threadIdx.x >> 6;
  for (int t = wave; t < 10; t += 4) {
    float d = wave_dot(Bd + (size_t)u * CC, Bd + (size_t)targets[t] * CC);
    if ((threadIdx.x & 63) == 0) dots[t] = d;
  }
  __syncthreads();
  if (threadIdx.x == 0) {
    float hsum = 0.f; int pcnt = 0;
    float iu = invB[u];
    for (int k = 0; k < KK; ++k) {
      if (tmask[k]) {
        float dpos = 1.f - dots[k] * iu * invB[targets[k]];
        float dneg = 1.f - dots[KK + k] * iu * invB[targets[KK + k]];
        float h = dpos - dneg + 0.4f;
        hsum += (h > 0.f) ? h : 0.f;
        pcnt++;
      }
    }
    if (idx >= 0 && pcnt > 0) {
      atomicAdd(&acc[0], hsum / (float)pcnt);
      atomicAdd(&acc[1], 1.0f);
    }
  }
}

// ---------------- crossbrain hinge per row ----------------
__global__ __launch_bounds__(256) void cb_hinge_kernel(const float* __restrict__ Bd, const float* __restrict__ invB,
                                                       const int* __restrict__ neighA, unsigned int seed,
                                                       float* __restrict__ acc) {
  int i = blockIdx.x;
  __shared__ int targets[10];
  __shared__ float dots[10];
  if (threadIdx.x == 0) {
    int pos[KK];
    for (int k = 0; k < KK; ++k) { pos[k] = neighA[(size_t)i * KK + k]; targets[k] = pos[k]; }
    unsigned int ctr = 0;
    for (int k = 0; k < KK; ++k) {
      int cand;
      while (true) {
        unsigned int h = mix_hash(seed ^ (unsigned)i, ctr++);
        cand = (int)(h & (TT - 1));
        bool bad = (cand == i);
        for (int t = 0; t < KK; ++t) bad = bad || (cand == pos[t]);
        for (int t = 0; t < k; ++t) bad = bad || (cand == targets[KK + t]);
        if (!bad) break;
      }
      targets[KK + k] = cand;
    }
  }
  __syncthreads();
  int wave = threadIdx.x >> 6;
  for (int t = wave; t < 10; t += 4) {
    float d = wave_dot(Bd + (size_t)i * CC, Bd + (size_t)targets[t] * CC);
    if ((threadIdx.x & 63) == 0) dots[t] = d;
  }
  __syncthreads();
  if (threadIdx.x == 0) {
    float hsum = 0.f;
    float ii = invB[i];
    const float lo = -1.f + 1e-8f, hi = 1.f - 1e-8f;
    for (int k = 0; k < KK; ++k) {
      float sp = fminf(fmaxf(dots[k] * ii * invB[targets[k]], lo), hi);
      float sn = fminf(fmaxf(dots[KK + k] * ii * invB[targets[KK + k]], lo), hi);
      float h = sn - sp + 0.05f;  // (1-sp)-(1-sn)+margin
      hsum += (h > 0.f) ? h : 0.f;
    }
    atomicAdd(acc, hsum);
  }
}

// ---------------- final combine ----------------
__global__ void final_kernel(const float* __restrict__ cb_acc, const float* __restrict__ nrc_acc,
                             float* __restrict__ out) {
  float loss2 = 0.f;
  for (int c = 0; c < 8; ++c) loss2 += cb_acc[c] * (1.0f / 10240.0f);  // /(T*K)
  loss2 *= 0.25f;                                                     // /Bn
  float loss3 = 0.f;
  for (int d = 0; d < 2; ++d) {
    float s = 0.f;
    for (int t = 0; t < 6; ++t) {
      float cnt = nrc_acc[(d * 6 + t) * 2 + 1];
      float sum = nrc_acc[(d * 6 + t) * 2 + 0];
      s += (cnt > 0.f) ? (sum / cnt) : 0.f;
    }
    loss3 += s * (1.f / 6.f);
  }
  out[0] = 10.f * loss2 + 10.f * loss3;
}

// ---------------- host-side numpy RandomState(seed).permutation(12)[:6] ----------------
namespace {
struct MT19937 {
  uint32_t mt[624]; int mti;
  void seed(uint32_t s) {
    mt[0] = s;
    for (int i = 1; i < 624; ++i) mt[i] = 1812433253u * (mt[i - 1] ^ (mt[i - 1] >> 30)) + (uint32_t)i;
    mti = 624;
  }
  uint32_t next() {
    if (mti >= 624) {
      for (int i = 0; i < 624; ++i) {
        uint32_t y = (mt[i] & 0x80000000u) | (mt[(i + 1) % 624] & 0x7fffffffu);
        uint32_t v = y >> 1;
        if (y & 1u) v ^= 0x9908b0dfu;
        mt[i] = mt[(i + 397) % 624] ^ v;
      }
      mti = 0;
    }
    uint32_t y = mt[mti++];
    y ^= y >> 11; y ^= (y << 7) & 0x9d2c5680u; y ^= (y << 15) & 0xefc60000u; y ^= y >> 18;
    return y;
  }
  uint32_t interval(uint32_t mx) {  // uniform 0..mx inclusive (numpy rk_interval)
    uint32_t mask = mx;
    mask |= mask >> 1; mask |= mask >> 2; mask |= mask >> 4; mask |= mask >> 8; mask |= mask >> 16;
    while (true) { uint32_t v = next() & mask; if (v <= mx) return v; }
  }
};
inline void np_perm12_first6(uint32_t seed, int* sel6) {
  int a[12]; for (int i = 0; i < 12; ++i) a[i] = i;
  MT19937 r; r.seed(seed);
  for (int i = 11; i >= 1; --i) { uint32_t j = r.interval((uint32_t)i); int t = a[i]; a[i] = a[j]; a[j] = t; }
  for (int i = 0; i < 6; ++i) sel6[i] = a[i];
}
}  // namespace

extern "C" void kernel_launch(void* const* d_in, const int* in_sizes, int n_in,
                              void* d_out, int out_size, void* d_ws, size_t ws_size,
                              hipStream_t stream) {
  const float* z1 = (const float*)d_in[0];
  const float* z2 = (const float*)d_in[1];
  float* out = (float*)d_out;

  char* base = (char*)d_ws;
  size_t off = 0;
  auto alloc = [&](size_t bytes) -> void* {
    void* p = base + off;
    off = (off + bytes + 255) & ~(size_t)255;
    return p;
  };
  float* gram     = (float*)alloc((size_t)TT * TT * 4);
  float* sq       = (float*)alloc((size_t)8 * TT * 4);
  float* inv      = (float*)alloc((size_t)8 * TT * 4);
  int*   neigh1   = (int*)alloc((size_t)8 * TT * KK * 4);  // sq-dist neighbors
  int*   neighC   = (int*)alloc((size_t)8 * TT * KK * 4);  // cos-dist neighbors
  int*   b_of_a   = (int*)alloc((size_t)TT * 4);
  int*   a_of_b   = (int*)alloc((size_t)TT * 4);
  int*   idxB     = (int*)alloc((size_t)TT * 4);
  int*   matchedB = (int*)alloc((size_t)TT * 4);
  int*   unmatched= (int*)alloc((size_t)TT * 4);
  int*   scalars  = (int*)alloc(64);
  float* accs     = (float*)alloc(64 * 4);  // cb_acc[8] then nrc_acc[24]
  float* cb_acc   = accs;
  float* nrc_acc  = accs + 8;

  hipMemsetAsync(accs, 0, 64 * 4, stream);

  auto slice = [&](int s) -> const float* {
    return (s < 4) ? (z1 + (size_t)s * TT * CC) : (z2 + (size_t)(s - 4) * TT * CC);
  };

  rownorm_kernel<<<8 * TT, 256, 0, stream>>>(z1, z2, sq, inv);

  dim3 ggrid(TT / 64, TT / 64);
  // self grams -> neighbor sets
  for (int s = 0; s < 8; ++s) {
    gram_kernel<<<ggrid, 256, 0, stream>>>(slice(s), slice(s), gram);
    top5_kernel<<<TT, 256, 0, stream>>>(gram, sq + s * TT, inv + s * TT, 0, neigh1 + (size_t)s * TT * KK);
    top5_kernel<<<TT, 256, 0, stream>>>(gram, sq + s * TT, inv + s * TT, 1, neighC + (size_t)s * TT * KK);
  }

  // crossbrain: combos 0..3 = (A=z1[b], B=z2[b]); 4..7 = (A=z2[b], B=z1[b])
  for (int c = 0; c < 8; ++c) {
    int sa = c;
    int sb = (c < 4) ? (c + 4) : (c - 4);
    cb_hinge_kernel<<<TT, 256, 0, stream>>>(slice(sb), inv + sb * TT, neigh1 + (size_t)sa * TT * KK,
                                            0x13579BDFu + 0x9E3779B9u * (unsigned)c, cb_acc + c);
  }

  // NRC pair selection (replicates np.random.RandomState(seed).permutation(12)[:6])
  int sel0[6], sel1[6];
  np_perm12_first6(0u, sel0);
  np_perm12_first6(1u, sel1);
  static const int PP[12] = {0, 0, 0, 1, 1, 1, 2, 2, 2, 3, 3, 3};
  static const int QQ[12] = {1, 2, 3, 0, 2, 3, 0, 1, 3, 0, 1, 2};

  for (int d = 0; d < 2; ++d) {
    const int* sel = (d == 0) ? sel0 : sel1;
    for (int t = 0; t < 6; ++t) {
      int pi = PP[sel[t]], qi = QQ[sel[t]];
      int sa = (d == 0) ? pi : 4 + pi;       // A slice
      int sb = (d == 0) ? 4 + qi : qi;       // B slice
      gram_kernel<<<ggrid, 256, 0, stream>>>(slice(sa), slice(sb), gram);
      argmin_kernel<<<TT, 256, 0, stream>>>(gram, inv + sb * TT, 0, b_of_a);
      argmin_kernel<<<TT, 256, 0, stream>>>(gram, inv + sa * TT, 1, a_of_b);
      mutual_kernel<<<1, 256, 0, stream>>>(b_of_a, a_of_b, idxB, matchedB, unmatched, scalars);
      nrc_hinge_kernel<<<TT, 256, 0, stream>>>(slice(sb), inv + sb * TT, neighC + (size_t)sa * TT * KK,
                                               idxB, unmatched, scalars,
                                               0xC0FFEE11u + 0x9E3779B9u * (unsigned)(d * 6 + t),
                                               nrc_acc + (d * 6 + t) * 2);
    }
  }

  final_kernel<<<1, 1, 0, stream>>>(cb_acc, nrc_acc, out);
}

// Round 2
// 3381.870 us; speedup vs baseline: 1.1580x; 1.1580x over previous
//
#include <hip/hip_runtime.h>
#include <cstdint>
#include <cstddef>

#define TT 2048
#define CC 768
#define KK 5

typedef __attribute__((ext_vector_type(8))) short short8;
typedef __attribute__((ext_vector_type(4))) float float4v;

// ---------------- device RNG hash ----------------
__device__ __forceinline__ unsigned int mix_hash(unsigned int a, unsigned int b) {
  unsigned long long x = (((unsigned long long)a) << 32) | (unsigned long long)b;
  x ^= x >> 33; x *= 0xff51afd7ed558ccdULL;
  x ^= x >> 33; x *= 0xc4ceb9fe1a85ec53ULL;
  x ^= x >> 33;
  return (unsigned int)(x & 0xffffffffu);
}

__device__ __forceinline__ unsigned short f2bf(float x) {  // RNE fp32->bf16
  union { float f; unsigned int u; } v; v.f = x;
  unsigned int r = v.u + 0x7fffu + ((v.u >> 16) & 1u);
  return (unsigned short)(r >> 16);
}

__device__ __forceinline__ void gload_lds16(const void* g, void* l) {
  __builtin_amdgcn_global_load_lds(
      (const __attribute__((address_space(1))) unsigned int*)g,
      (__attribute__((address_space(3))) unsigned int*)l, 16, 0, 0);
}

// ---------------- fp32 -> bf16 convert (both tensors into one buffer) ----------------
__global__ __launch_bounds__(256) void tobf16_kernel(const float* __restrict__ z1, const float* __restrict__ z2,
                                                     unsigned short* __restrict__ out) {
  size_t i = ((size_t)blockIdx.x * 256 + threadIdx.x) * 8;
  const size_t half = (size_t)4 * TT * CC;
  const float* src = (i < half) ? (z1 + i) : (z2 + (i - half));
  float4 a = ((const float4*)src)[0];
  float4 b = ((const float4*)src)[1];
  short8 o;
  o[0] = (short)f2bf(a.x); o[1] = (short)f2bf(a.y); o[2] = (short)f2bf(a.z); o[3] = (short)f2bf(a.w);
  o[4] = (short)f2bf(b.x); o[5] = (short)f2bf(b.y); o[6] = (short)f2bf(b.z); o[7] = (short)f2bf(b.w);
  *(short8*)(out + i) = o;
}

// ---------------- row norms (from fp32) ----------------
__global__ __launch_bounds__(256) void rownorm_kernel(const float* __restrict__ z1, const float* __restrict__ z2,
                                                      float* __restrict__ sq, float* __restrict__ inv) {
  int r = blockIdx.x;
  const float* p = (r < 4 * TT) ? (z1 + (size_t)r * CC) : (z2 + (size_t)(r - 4 * TT) * CC);
  float s = 0.f;
  for (int k = threadIdx.x; k < CC; k += 256) { float v = p[k]; s += v * v; }
  __shared__ float red[256];
  red[threadIdx.x] = s; __syncthreads();
  for (int off = 128; off > 0; off >>= 1) {
    if (threadIdx.x < off) red[threadIdx.x] += red[threadIdx.x + off];
    __syncthreads();
  }
  if (threadIdx.x == 0) { sq[r] = red[0]; inv[r] = rsqrtf(red[0] + 1e-12f); }
}

// ---------------- bf16 MFMA gram: G[i][j] = dot(A_i, B_j) (m97 structure) ----------------
__global__ __launch_bounds__(256) void gram_mfma_kernel(const unsigned short* __restrict__ A,
                                                        const unsigned short* __restrict__ B,
                                                        float* __restrict__ G) {
  __shared__ unsigned short As[128 * 32];
  __shared__ unsigned short Bs[128 * 32];
  const int bm = blockIdx.y * 128, bn = blockIdx.x * 128;
  const int lane = threadIdx.x & 63, waveId = threadIdx.x >> 6;
  const int wm = (waveId >> 1) * 64, wn = (waveId & 1) * 64;
  const int lrow = lane & 15, lquad = lane >> 4;

  float4v acc[4][4];
#pragma unroll
  for (int i = 0; i < 4; ++i)
#pragma unroll
    for (int j = 0; j < 4; ++j) acc[i][j] = (float4v){0.f, 0.f, 0.f, 0.f};

  for (int kk = 0; kk < CC; kk += 32) {
#pragma unroll
    for (int c = 0; c < 2; ++c) {
      int l = c * 256 + threadIdx.x;
      int row = l >> 2, kc = (l & 3) * 8;
      gload_lds16(A + (size_t)(bm + row) * CC + kk + kc, &As[l * 8]);
      gload_lds16(B + (size_t)(bn + row) * CC + kk + kc, &Bs[l * 8]);
    }
    __syncthreads();
    short8 af[4], bfr[4];
#pragma unroll
    for (int i = 0; i < 4; ++i) {
      af[i]  = *(const short8*)&As[(wm + i * 16 + lrow) * 32 + lquad * 8];
      bfr[i] = *(const short8*)&Bs[(wn + i * 16 + lrow) * 32 + lquad * 8];
    }
#pragma unroll
    for (int i = 0; i < 4; ++i)
#pragma unroll
      for (int j = 0; j < 4; ++j)
        acc[i][j] = __builtin_amdgcn_mfma_f32_16x16x32_bf16(af[i], bfr[j], acc[i][j], 0, 0, 0);
    __syncthreads();
  }
#pragma unroll
  for (int i = 0; i < 4; ++i) {
    int row0 = bm + wm + i * 16 + lquad * 4;
#pragma unroll
    for (int j = 0; j < 4; ++j) {
      int col = bn + wn + j * 16 + lrow;
#pragma unroll
      for (int r = 0; r < 4; ++r) G[(size_t)(row0 + r) * TT + col] = acc[i][j][r];
    }
  }
}

// ---------------- fused dual-mode top-5 (single pass over G row, LDS-cached keys) ----------------
__global__ __launch_bounds__(256) void top5_fused_kernel(const float* __restrict__ G, const float* __restrict__ sq,
                                                         const float* __restrict__ inv, int* __restrict__ out0,
                                                         int* __restrict__ out1) {
  int i = blockIdx.x;
  __shared__ float k0[TT];
  __shared__ float k1[TT];
  __shared__ float vred[256];
  __shared__ int ired[256];
  __shared__ int sel_sh[2][KK];
  for (int j = threadIdx.x; j < TT; j += 256) {
    float g = G[(size_t)i * TT + j];
    k0[j] = sq[j] - 2.f * g;
    k1[j] = -g * inv[j];
  }
  __syncthreads();
  if (threadIdx.x == 0) { k0[i] = INFINITY; k1[i] = INFINITY; }
  __syncthreads();
  for (int mode = 0; mode < 2; ++mode) {
    float* ks = mode ? k1 : k0;
    for (int r = 0; r < KK; ++r) {
      float best = INFINITY; int bidx = TT;
      for (int j = threadIdx.x; j < TT; j += 256) {
        float v = ks[j];
        if (v < best || (v == best && j < bidx)) { best = v; bidx = j; }
      }
      vred[threadIdx.x] = best; ired[threadIdx.x] = bidx;
      __syncthreads();
      for (int off = 128; off > 0; off >>= 1) {
        if (threadIdx.x < off) {
          float v2 = vred[threadIdx.x + off]; int i2 = ired[threadIdx.x + off];
          if (v2 < vred[threadIdx.x] || (v2 == vred[threadIdx.x] && i2 < ired[threadIdx.x])) {
            vred[threadIdx.x] = v2; ired[threadIdx.x] = i2;
          }
        }
        __syncthreads();
      }
      if (threadIdx.x == 0) { sel_sh[mode][r] = ired[0]; ks[ired[0]] = INFINITY; }
      __syncthreads();
    }
  }
  if (threadIdx.x < KK) {
    out0[(size_t)i * KK + threadIdx.x] = sel_sh[0][threadIdx.x];
    out1[(size_t)i * KK + threadIdx.x] = sel_sh[1][threadIdx.x];
  }
}

// ---------------- row argmin of cos-dist: b_of_a[i] = argmin_j -G[i][j]*invB[j] ----------------
__global__ __launch_bounds__(256) void argmin_row_kernel(const float* __restrict__ G, const float* __restrict__ invB,
                                                         int* __restrict__ out) {
  int i = blockIdx.x;
  __shared__ float vred[256];
  __shared__ int ired[256];
  float best = INFINITY; int bidx = TT;
  for (int j = threadIdx.x; j < TT; j += 256) {
    float key = -G[(size_t)i * TT + j] * invB[j];
    if (key < best || (key == best && j < bidx)) { best = key; bidx = j; }
  }
  vred[threadIdx.x] = best; ired[threadIdx.x] = bidx;
  __syncthreads();
  for (int off = 128; off > 0; off >>= 1) {
    if (threadIdx.x < off) {
      float v2 = vred[threadIdx.x + off]; int i2 = ired[threadIdx.x + off];
      if (v2 < vred[threadIdx.x] || (v2 == vred[threadIdx.x] && i2 < ired[threadIdx.x])) {
        vred[threadIdx.x] = v2; ired[threadIdx.x] = i2;
      }
    }
    __syncthreads();
  }
  if (threadIdx.x == 0) out[i] = ired[0];
}

// ---------------- col argmin (coalesced): a_of_b[c] = argmin_r -G[r][c]*invA[r] ----------------
__global__ __launch_bounds__(256) void argmin_col_kernel(const float* __restrict__ G, const float* __restrict__ invA,
                                                         int* __restrict__ out) {
  int cl = threadIdx.x & 63;
  int g = threadIdx.x >> 6;
  int c = blockIdx.x * 64 + cl;
  float best = INFINITY; int bidx = TT;
  for (int r = g; r < TT; r += 4) {
    float key = -G[(size_t)r * TT + c] * invA[r];
    if (key < best) { best = key; bidx = r; }
  }
  __shared__ float vs[256];
  __shared__ int is_[256];
  vs[threadIdx.x] = best; is_[threadIdx.x] = bidx;
  __syncthreads();
  if (g == 0) {
#pragma unroll
    for (int q = 1; q < 4; ++q) {
      float v2 = vs[cl + q * 64]; int i2 = is_[cl + q * 64];
      if (v2 < best || (v2 == best && i2 < bidx)) { best = v2; bidx = i2; }
    }
    out[c] = bidx;
  }
}

// ---------------- mutual matching ----------------
__global__ __launch_bounds__(256) void mutual_kernel(const int* __restrict__ b_of_a, const int* __restrict__ a_of_b,
                                                     int* __restrict__ idxB_of_A, int* __restrict__ matchedB,
                                                     int* __restrict__ unmatched, int* __restrict__ scalars) {
  __shared__ int cnt_sh;
  for (int j = threadIdx.x; j < TT; j += 256) matchedB[j] = 0;
  __syncthreads();
  for (int i = threadIdx.x; i < TT; i += 256) {
    int b = b_of_a[i];
    bool mut = (a_of_b[b] == i);
    idxB_of_A[i] = mut ? b : -1;
    if (mut) matchedB[b] = 1;
  }
  __syncthreads();
  if (threadIdx.x == 0) cnt_sh = 0;
  __syncthreads();
  for (int j = threadIdx.x; j < TT; j += 256) {
    if (!matchedB[j]) { int p = atomicAdd(&cnt_sh, 1); unmatched[p] = j; }
  }
  __syncthreads();
  if (threadIdx.x == 0) {
    int c = cnt_sh;
    if (c == 0) { unmatched[0] = 0; c = 1; }
    scalars[0] = c;
  }
}

// ---------------- wave-level dot of two 768-float rows ----------------
__device__ __forceinline__ float wave_dot(const float* __restrict__ x, const float* __restrict__ y) {
  int lane = threadIdx.x & 63;
  float s = 0.f;
#pragma unroll
  for (int m = 0; m < CC / 64; ++m) s = fmaf(x[lane + m * 64], y[lane + m * 64], s);
#pragma unroll
  for (int off = 32; off > 0; off >>= 1) s += __shfl_down(s, off, 64);
  return s;
}

// ---------------- NRC hinge per A-row ----------------
__global__ __launch_bounds__(256) void nrc_hinge_kernel(const float* __restrict__ Bd, const float* __restrict__ invB,
                                                        const int* __restrict__ neighA, const int* __restrict__ idxB_of_A,
                                                        const int* __restrict__ unmatched, const int* __restrict__ scalars,
                                                        unsigned int seed, float* __restrict__ acc) {
  int i = blockIdx.x;
  __shared__ int targets[10];
  __shared__ int tmask[KK];
  __shared__ float dots[10];
  if (threadIdx.x == 0) {
    unsigned int neg_count = (unsigned int)scalars[0];
    for (int k = 0; k < KK; ++k) {
      int nb = neighA[(size_t)i * KK + k];
      int pb = idxB_of_A[nb];
      tmask[k] = (pb >= 0) ? 1 : 0;
      targets[k] = (pb >= 0) ? pb : 0;
      unsigned int r = mix_hash(seed ^ 0xA5A5u, (unsigned)(i * KK + k)) & (TT - 1);
      targets[KK + k] = unmatched[r % neg_count];
    }
  }
  __syncthreads();
  int idx = idxB_of_A[i];
  int u = idx >= 0 ? idx : 0;
  int wave = threadIdx.x >> 6;
  for (int t = wave; t < 10; t += 4) {
    float d = wave_dot(Bd + (size_t)u * CC, Bd + (size_t)targets[t] * CC);
    if ((threadIdx.x & 63) == 0) dots[t] = d;
  }
  __syncthreads();
  if (threadIdx.x == 0) {
    float hsum = 0.f; int pcnt = 0;
    float iu = invB[u];
    for (int k = 0; k < KK; ++k) {
      if (tmask[k]) {
        float dpos = 1.f - dots[k] * iu * invB[targets[k]];
        float dneg = 1.f - dots[KK + k] * iu * invB[targets[KK + k]];
        float h = dpos - dneg + 0.4f;
        hsum += (h > 0.f) ? h : 0.f;
        pcnt++;
      }
    }
    if (idx >= 0 && pcnt > 0) {
      atomicAdd(&acc[0], hsum / (float)pcnt);
      atomicAdd(&acc[1], 1.0f);
    }
  }
}

// ---------------- crossbrain hinge per row ----------------
__global__ __launch_bounds__(256) void cb_hinge_kernel(const float* __restrict__ Bd, const float* __restrict__ invB,
                                                       const int* __restrict__ neighA, unsigned int seed,
                                                       float* __restrict__ acc) {
  int i = blockIdx.x;
  __shared__ int targets[10];
  __shared__ float dots[10];
  if (threadIdx.x == 0) {
    int pos[KK];
    for (int k = 0; k < KK; ++k) { pos[k] = neighA[(size_t)i * KK + k]; targets[k] = pos[k]; }
    unsigned int ctr = 0;
    for (int k = 0; k < KK; ++k) {
      int cand;
      while (true) {
        unsigned int h = mix_hash(seed ^ (unsigned)i, ctr++);
        cand = (int)(h & (TT - 1));
        bool bad = (cand == i);
        for (int t = 0; t < KK; ++t) bad = bad || (cand == pos[t]);
        for (int t = 0; t < k; ++t) bad = bad || (cand == targets[KK + t]);
        if (!bad) break;
      }
      targets[KK + k] = cand;
    }
  }
  __syncthreads();
  int wave = threadIdx.x >> 6;
  for (int t = wave; t < 10; t += 4) {
    float d = wave_dot(Bd + (size_t)i * CC, Bd + (size_t)targets[t] * CC);
    if ((threadIdx.x & 63) == 0) dots[t] = d;
  }
  __syncthreads();
  if (threadIdx.x == 0) {
    float hsum = 0.f;
    float ii = invB[i];
    const float lo = -1.f + 1e-8f, hi = 1.f - 1e-8f;
    for (int k = 0; k < KK; ++k) {
      float sp = fminf(fmaxf(dots[k] * ii * invB[targets[k]], lo), hi);
      float sn = fminf(fmaxf(dots[KK + k] * ii * invB[targets[KK + k]], lo), hi);
      float h = sn - sp + 0.05f;
      hsum += (h > 0.f) ? h : 0.f;
    }
    atomicAdd(acc, hsum);
  }
}

// ---------------- final combine ----------------
__global__ void final_kernel(const float* __restrict__ cb_acc, const float* __restrict__ nrc_acc,
                             float* __restrict__ out) {
  float loss2 = 0.f;
  for (int c = 0; c < 8; ++c) loss2 += cb_acc[c] * (1.0f / 10240.0f);
  loss2 *= 0.25f;
  float loss3 = 0.f;
  for (int d = 0; d < 2; ++d) {
    float s = 0.f;
    for (int t = 0; t < 6; ++t) {
      float cnt = nrc_acc[(d * 6 + t) * 2 + 1];
      float sum = nrc_acc[(d * 6 + t) * 2 + 0];
      s += (cnt > 0.f) ? (sum / cnt) : 0.f;
    }
    loss3 += s * (1.f / 6.f);
  }
  out[0] = 10.f * loss2 + 10.f * loss3;
}

// ---------------- host-side numpy RandomState(seed).permutation(12)[:6] ----------------
namespace {
struct MT19937 {
  uint32_t mt[624]; int mti;
  void seed(uint32_t s) {
    mt[0] = s;
    for (int i = 1; i < 624; ++i) mt[i] = 1812433253u * (mt[i - 1] ^ (mt[i - 1] >> 30)) + (uint32_t)i;
    mti = 624;
  }
  uint32_t next() {
    if (mti >= 624) {
      for (int i = 0; i < 624; ++i) {
        uint32_t y = (mt[i] & 0x80000000u) | (mt[(i + 1) % 624] & 0x7fffffffu);
        uint32_t v = y >> 1;
        if (y & 1u) v ^= 0x9908b0dfu;
        mt[i] = mt[(i + 397) % 624] ^ v;
      }
      mti = 0;
    }
    uint32_t y = mt[mti++];
    y ^= y >> 11; y ^= (y << 7) & 0x9d2c5680u; y ^= (y << 15) & 0xefc60000u; y ^= y >> 18;
    return y;
  }
  uint32_t interval(uint32_t mx) {
    uint32_t mask = mx;
    mask |= mask >> 1; mask |= mask >> 2; mask |= mask >> 4; mask |= mask >> 8; mask |= mask >> 16;
    while (true) { uint32_t v = next() & mask; if (v <= mx) return v; }
  }
};
inline void np_perm12_first6(uint32_t seed, int* sel6) {
  int a[12]; for (int i = 0; i < 12; ++i) a[i] = i;
  MT19937 r; r.seed(seed);
  for (int i = 11; i >= 1; --i) { uint32_t j = r.interval((uint32_t)i); int t = a[i]; a[i] = a[j]; a[j] = t; }
  for (int i = 0; i < 6; ++i) sel6[i] = a[i];
}
}  // namespace

extern "C" void kernel_launch(void* const* d_in, const int* in_sizes, int n_in,
                              void* d_out, int out_size, void* d_ws, size_t ws_size,
                              hipStream_t stream) {
  const float* z1 = (const float*)d_in[0];
  const float* z2 = (const float*)d_in[1];
  float* out = (float*)d_out;

  char* base = (char*)d_ws;
  size_t off = 0;
  auto alloc = [&](size_t bytes) -> void* {
    void* p = base + off;
    off = (off + bytes + 255) & ~(size_t)255;
    return p;
  };
  float* gram            = (float*)alloc((size_t)TT * TT * 4);
  unsigned short* zb     = (unsigned short*)alloc((size_t)8 * TT * CC * 2);  // bf16 copies
  float* sq              = (float*)alloc((size_t)8 * TT * 4);
  float* inv             = (float*)alloc((size_t)8 * TT * 4);
  int*   neigh1          = (int*)alloc((size_t)8 * TT * KK * 4);
  int*   neighC          = (int*)alloc((size_t)8 * TT * KK * 4);
  int*   b_of_a          = (int*)alloc((size_t)TT * 4);
  int*   a_of_b          = (int*)alloc((size_t)TT * 4);
  int*   idxB            = (int*)alloc((size_t)TT * 4);
  int*   matchedB        = (int*)alloc((size_t)TT * 4);
  int*   unmatched       = (int*)alloc((size_t)TT * 4);
  int*   scalars         = (int*)alloc(64);
  float* accs            = (float*)alloc(64 * 4);
  float* cb_acc          = accs;
  float* nrc_acc         = accs + 8;

  hipMemsetAsync(accs, 0, 64 * 4, stream);

  auto slice = [&](int s) -> const float* {
    return (s < 4) ? (z1 + (size_t)s * TT * CC) : (z2 + (size_t)(s - 4) * TT * CC);
  };
  auto slice_bf = [&](int s) -> const unsigned short* {
    return zb + (size_t)s * TT * CC;
  };

  tobf16_kernel<<<(8 * TT * CC) / (256 * 8), 256, 0, stream>>>(z1, z2, zb);
  rownorm_kernel<<<8 * TT, 256, 0, stream>>>(z1, z2, sq, inv);

  dim3 ggrid(TT / 128, TT / 128);
  // self grams -> both neighbor sets in one pass
  for (int s = 0; s < 8; ++s) {
    gram_mfma_kernel<<<ggrid, 256, 0, stream>>>(slice_bf(s), slice_bf(s), gram);
    top5_fused_kernel<<<TT, 256, 0, stream>>>(gram, sq + s * TT, inv + s * TT,
                                              neigh1 + (size_t)s * TT * KK, neighC + (size_t)s * TT * KK);
  }

  // crossbrain
  for (int c = 0; c < 8; ++c) {
    int sa = c;
    int sb = (c < 4) ? (c + 4) : (c - 4);
    cb_hinge_kernel<<<TT, 256, 0, stream>>>(slice(sb), inv + sb * TT, neigh1 + (size_t)sa * TT * KK,
                                            0x13579BDFu + 0x9E3779B9u * (unsigned)c, cb_acc + c);
  }

  // NRC pair selection (numpy RandomState(seed).permutation(12)[:6])
  int sel0[6], sel1[6];
  np_perm12_first6(0u, sel0);
  np_perm12_first6(1u, sel1);
  static const int PP[12] = {0, 0, 0, 1, 1, 1, 2, 2, 2, 3, 3, 3};
  static const int QQ[12] = {1, 2, 3, 0, 2, 3, 0, 1, 3, 0, 1, 2};

  for (int d = 0; d < 2; ++d) {
    const int* sel = (d == 0) ? sel0 : sel1;
    for (int t = 0; t < 6; ++t) {
      int pi = PP[sel[t]], qi = QQ[sel[t]];
      int sa = (d == 0) ? pi : 4 + pi;
      int sb = (d == 0) ? 4 + qi : qi;
      gram_mfma_kernel<<<ggrid, 256, 0, stream>>>(slice_bf(sa), slice_bf(sb), gram);
      argmin_row_kernel<<<TT, 256, 0, stream>>>(gram, inv + sb * TT, b_of_a);
      argmin_col_kernel<<<TT / 64, 256, 0, stream>>>(gram, inv + sa * TT, a_of_b);
      mutual_kernel<<<1, 256, 0, stream>>>(b_of_a, a_of_b, idxB, matchedB, unmatched, scalars);
      nrc_hinge_kernel<<<TT, 256, 0, stream>>>(slice(sb), inv + sb * TT, neighC + (size_t)sa * TT * KK,
                                               idxB, unmatched, scalars,
                                               0xC0FFEE11u + 0x9E3779B9u * (unsigned)(d * 6 + t),
                                               nrc_acc + (d * 6 + t) * 2);
    }
  }

  final_kernel<<<1, 1, 0, stream>>>(cb_acc, nrc_acc, out);
}

// Round 3
// 1831.313 us; speedup vs baseline: 2.1384x; 1.8467x over previous
//
#include <hip/hip_runtime.h>
#include <cstdint>
#include <cstddef>

#define TT 2048
#define CC 768
#define KK 5

typedef __attribute__((ext_vector_type(8))) short short8;
typedef __attribute__((ext_vector_type(4))) float float4v;

// ---------------- device RNG hash ----------------
__device__ __forceinline__ unsigned int mix_hash(unsigned int a, unsigned int b) {
  unsigned long long x = (((unsigned long long)a) << 32) | (unsigned long long)b;
  x ^= x >> 33; x *= 0xff51afd7ed558ccdULL;
  x ^= x >> 33; x *= 0xc4ceb9fe1a85ec53ULL;
  x ^= x >> 33;
  return (unsigned int)(x & 0xffffffffu);
}

__device__ __forceinline__ unsigned short f2bf(float x) {  // RNE fp32->bf16
  union { float f; unsigned int u; } v; v.f = x;
  unsigned int r = v.u + 0x7fffu + ((v.u >> 16) & 1u);
  return (unsigned short)(r >> 16);
}

__device__ __forceinline__ void gload_lds16(const void* g, void* l) {
  __builtin_amdgcn_global_load_lds(
      (const __attribute__((address_space(1))) unsigned int*)g,
      (__attribute__((address_space(3))) unsigned int*)l, 16, 0, 0);
}

// ---------------- fp32 -> bf16 convert ----------------
__global__ __launch_bounds__(256) void tobf16_kernel(const float* __restrict__ z1, const float* __restrict__ z2,
                                                     unsigned short* __restrict__ out) {
  size_t i = ((size_t)blockIdx.x * 256 + threadIdx.x) * 8;
  const size_t half = (size_t)4 * TT * CC;
  const float* src = (i < half) ? (z1 + i) : (z2 + (i - half));
  float4 a = ((const float4*)src)[0];
  float4 b = ((const float4*)src)[1];
  short8 o;
  o[0] = (short)f2bf(a.x); o[1] = (short)f2bf(a.y); o[2] = (short)f2bf(a.z); o[3] = (short)f2bf(a.w);
  o[4] = (short)f2bf(b.x); o[5] = (short)f2bf(b.y); o[6] = (short)f2bf(b.z); o[7] = (short)f2bf(b.w);
  *(short8*)(out + i) = o;
}

// ---------------- row norms ----------------
__global__ __launch_bounds__(256) void rownorm_kernel(const float* __restrict__ z1, const float* __restrict__ z2,
                                                      float* __restrict__ sq, float* __restrict__ inv) {
  int r = blockIdx.x;
  const float* p = (r < 4 * TT) ? (z1 + (size_t)r * CC) : (z2 + (size_t)(r - 4 * TT) * CC);
  float s = 0.f;
  for (int k = threadIdx.x; k < CC; k += 256) { float v = p[k]; s += v * v; }
  __shared__ float red[256];
  red[threadIdx.x] = s; __syncthreads();
  for (int off = 128; off > 0; off >>= 1) {
    if (threadIdx.x < off) red[threadIdx.x] += red[threadIdx.x + off];
    __syncthreads();
  }
  if (threadIdx.x == 0) { sq[r] = red[0]; inv[r] = rsqrtf(red[0] + 1e-12f); }
}

// ---------------- bf16 MFMA gram ----------------
__global__ __launch_bounds__(256) void gram_mfma_kernel(const unsigned short* __restrict__ A,
                                                        const unsigned short* __restrict__ B,
                                                        float* __restrict__ G) {
  __shared__ unsigned short As[128 * 32];
  __shared__ unsigned short Bs[128 * 32];
  const int bm = blockIdx.y * 128, bn = blockIdx.x * 128;
  const int lane = threadIdx.x & 63, waveId = threadIdx.x >> 6;
  const int wm = (waveId >> 1) * 64, wn = (waveId & 1) * 64;
  const int lrow = lane & 15, lquad = lane >> 4;

  float4v acc[4][4];
#pragma unroll
  for (int i = 0; i < 4; ++i)
#pragma unroll
    for (int j = 0; j < 4; ++j) acc[i][j] = (float4v){0.f, 0.f, 0.f, 0.f};

  for (int kk = 0; kk < CC; kk += 32) {
#pragma unroll
    for (int c = 0; c < 2; ++c) {
      int l = c * 256 + threadIdx.x;
      int row = l >> 2, kc = (l & 3) * 8;
      gload_lds16(A + (size_t)(bm + row) * CC + kk + kc, &As[l * 8]);
      gload_lds16(B + (size_t)(bn + row) * CC + kk + kc, &Bs[l * 8]);
    }
    __syncthreads();
    short8 af[4], bfr[4];
#pragma unroll
    for (int i = 0; i < 4; ++i) {
      af[i]  = *(const short8*)&As[(wm + i * 16 + lrow) * 32 + lquad * 8];
      bfr[i] = *(const short8*)&Bs[(wn + i * 16 + lrow) * 32 + lquad * 8];
    }
#pragma unroll
    for (int i = 0; i < 4; ++i)
#pragma unroll
      for (int j = 0; j < 4; ++j)
        acc[i][j] = __builtin_amdgcn_mfma_f32_16x16x32_bf16(af[i], bfr[j], acc[i][j], 0, 0, 0);
    __syncthreads();
  }
#pragma unroll
  for (int i = 0; i < 4; ++i) {
    int row0 = bm + wm + i * 16 + lquad * 4;
#pragma unroll
    for (int j = 0; j < 4; ++j) {
      int col = bn + wn + j * 16 + lrow;
#pragma unroll
      for (int r = 0; r < 4; ++r) G[(size_t)(row0 + r) * TT + col] = acc[i][j][r];
    }
  }
}

// ---------------- fused dual-mode top-5 (shuffle-reduce rounds) ----------------
__global__ __launch_bounds__(256) void top5_fused_kernel(const float* __restrict__ G, const float* __restrict__ sq,
                                                         const float* __restrict__ inv, int* __restrict__ out0,
                                                         int* __restrict__ out1) {
  int i = blockIdx.x;
  __shared__ float k0[TT];
  __shared__ float k1[TT];
  __shared__ float wv[4];
  __shared__ int wi[4];
  __shared__ int sel_sh[2][KK];
  int lane = threadIdx.x & 63, w = threadIdx.x >> 6;
#pragma unroll
  for (int t = 0; t < 2; ++t) {
    int j4 = (t * 256 + threadIdx.x) * 4;
    float4 g4 = *(const float4*)&G[(size_t)i * TT + j4];
    float4 s4 = *(const float4*)&sq[j4];   // sq/inv are per-slice pointers (TT-aligned slices)
    float4 v4 = *(const float4*)&inv[j4];
    k0[j4 + 0] = s4.x - 2.f * g4.x; k1[j4 + 0] = -g4.x * v4.x;
    k0[j4 + 1] = s4.y - 2.f * g4.y; k1[j4 + 1] = -g4.y * v4.y;
    k0[j4 + 2] = s4.z - 2.f * g4.z; k1[j4 + 2] = -g4.z * v4.z;
    k0[j4 + 3] = s4.w - 2.f * g4.w; k1[j4 + 3] = -g4.w * v4.w;
  }
  __syncthreads();
  if (threadIdx.x == 0) { k0[i] = INFINITY; k1[i] = INFINITY; }
  __syncthreads();
  for (int mode = 0; mode < 2; ++mode) {
    float* ks = mode ? k1 : k0;
    for (int r = 0; r < KK; ++r) {
      float best = INFINITY; int bidx = TT;
      for (int j = threadIdx.x; j < TT; j += 256) {
        float v = ks[j];
        if (v < best) { best = v; bidx = j; }  // j ascending per thread
      }
#pragma unroll
      for (int off = 32; off > 0; off >>= 1) {
        float v2 = __shfl_down(best, off, 64);
        int i2 = __shfl_down(bidx, off, 64);
        if (v2 < best || (v2 == best && i2 < bidx)) { best = v2; bidx = i2; }
      }
      if (lane == 0) { wv[w] = best; wi[w] = bidx; }
      __syncthreads();
      if (threadIdx.x == 0) {
        float b2 = wv[0]; int x2 = wi[0];
#pragma unroll
        for (int q = 1; q < 4; ++q) {
          if (wv[q] < b2 || (wv[q] == b2 && wi[q] < x2)) { b2 = wv[q]; x2 = wi[q]; }
        }
        sel_sh[mode][r] = x2; ks[x2] = INFINITY;
      }
      __syncthreads();
    }
  }
  if (threadIdx.x < KK) {
    out0[(size_t)i * KK + threadIdx.x] = sel_sh[0][threadIdx.x];
    out1[(size_t)i * KK + threadIdx.x] = sel_sh[1][threadIdx.x];
  }
}

// ---------------- tiled dual argmin, stage 1: 64x64 tiles ----------------
// row key (argmin over cols j): -G[i][j]*invB[j] ; col key (argmin over rows i): -G[i][j]*invA[i]
__global__ __launch_bounds__(256) void argmin_tile_kernel(const float* __restrict__ G, const float* __restrict__ invA,
                                                          const float* __restrict__ invB,
                                                          float* __restrict__ prv, int* __restrict__ pri,
                                                          float* __restrict__ pcv, int* __restrict__ pci) {
  int bj = blockIdx.x, bi = blockIdx.y;
  int lane = threadIdx.x & 63, w = threadIdx.x >> 6;
  int j = bj * 64 + lane;
  __shared__ float sA[64];
  if (threadIdx.x < 64) sA[threadIdx.x] = invA[bi * 64 + threadIdx.x];
  float invBj = invB[j];
  __syncthreads();
  float cbest = INFINITY; int cidx = TT;
  for (int r = w; r < 64; r += 4) {
    int i = bi * 64 + r;
    float g = G[(size_t)i * TT + j];
    float kc = -g * sA[r];
    if (kc < cbest) { cbest = kc; cidx = i; }  // rows ascending within wave
    float v = -g * invBj; int idx = j;
#pragma unroll
    for (int off = 32; off > 0; off >>= 1) {
      float v2 = __shfl_down(v, off, 64);
      int i2 = __shfl_down(idx, off, 64);
      if (v2 < v || (v2 == v && i2 < idx)) { v = v2; idx = i2; }
    }
    if (lane == 0) { prv[(size_t)bj * TT + i] = v; pri[(size_t)bj * TT + i] = idx; }
  }
  __shared__ float cv[256];
  __shared__ int ci[256];
  cv[threadIdx.x] = cbest; ci[threadIdx.x] = cidx;
  __syncthreads();
  if (w == 0) {
    float best = cbest; int bidx = cidx;
#pragma unroll
    for (int q = 1; q < 4; ++q) {
      float v2 = cv[lane + q * 64]; int i2 = ci[lane + q * 64];
      if (v2 < best || (v2 == best && i2 < bidx)) { best = v2; bidx = i2; }
    }
    pcv[(size_t)bi * TT + j] = best; pci[(size_t)bi * TT + j] = bidx;
  }
}

// ---------------- argmin stage 2: fold 32 stripes ----------------
__global__ __launch_bounds__(256) void argmin_reduce_kernel(const float* __restrict__ prv, const int* __restrict__ pri,
                                                            const float* __restrict__ pcv, const int* __restrict__ pci,
                                                            int* __restrict__ b_of_a, int* __restrict__ a_of_b) {
  int t = blockIdx.x * 256 + threadIdx.x;  // 0..2*TT-1
  int isRow = t < TT;
  int x = isRow ? t : t - TT;
  const float* pv = isRow ? prv : pcv;
  const int* pi = isRow ? pri : pci;
  float best = INFINITY; int bidx = TT;
  for (int s = 0; s < 32; ++s) {
    float v = pv[(size_t)s * TT + x]; int id = pi[(size_t)s * TT + x];
    if (v < best || (v == best && id < bidx)) { best = v; bidx = id; }
  }
  if (isRow) b_of_a[x] = bidx; else a_of_b[x] = bidx;
}

// ---------------- mutual matching ----------------
__global__ __launch_bounds__(256) void mutual_kernel(const int* __restrict__ b_of_a, const int* __restrict__ a_of_b,
                                                     int* __restrict__ idxB_of_A, int* __restrict__ matchedB,
                                                     int* __restrict__ unmatched, int* __restrict__ scalars) {
  __shared__ int cnt_sh;
  for (int j = threadIdx.x; j < TT; j += 256) matchedB[j] = 0;
  __syncthreads();
  for (int i = threadIdx.x; i < TT; i += 256) {
    int b = b_of_a[i];
    bool mut = (a_of_b[b] == i);
    idxB_of_A[i] = mut ? b : -1;
    if (mut) matchedB[b] = 1;
  }
  __syncthreads();
  if (threadIdx.x == 0) cnt_sh = 0;
  __syncthreads();
  for (int j = threadIdx.x; j < TT; j += 256) {
    if (!matchedB[j]) { int p = atomicAdd(&cnt_sh, 1); unmatched[p] = j; }
  }
  __syncthreads();
  if (threadIdx.x == 0) {
    int c = cnt_sh;
    if (c == 0) { unmatched[0] = 0; c = 1; }
    scalars[0] = c;
  }
}

// ---------------- wave-level dot ----------------
__device__ __forceinline__ float wave_dot(const float* __restrict__ x, const float* __restrict__ y) {
  int lane = threadIdx.x & 63;
  float s = 0.f;
#pragma unroll
  for (int m = 0; m < CC / 64; ++m) s = fmaf(x[lane + m * 64], y[lane + m * 64], s);
#pragma unroll
  for (int off = 32; off > 0; off >>= 1) s += __shfl_down(s, off, 64);
  return s;
}

// ---------------- NRC hinge per A-row ----------------
__global__ __launch_bounds__(256) void nrc_hinge_kernel(const float* __restrict__ Bd, const float* __restrict__ invB,
                                                        const int* __restrict__ neighA, const int* __restrict__ idxB_of_A,
                                                        const int* __restrict__ unmatched, const int* __restrict__ scalars,
                                                        unsigned int seed, float* __restrict__ acc) {
  int i = blockIdx.x;
  __shared__ int targets[10];
  __shared__ int tmask[KK];
  __shared__ float dots[10];
  if (threadIdx.x == 0) {
    unsigned int neg_count = (unsigned int)scalars[0];
    for (int k = 0; k < KK; ++k) {
      int nb = neighA[(size_t)i * KK + k];
      int pb = idxB_of_A[nb];
      tmask[k] = (pb >= 0) ? 1 : 0;
      targets[k] = (pb >= 0) ? pb : 0;
      unsigned int r = mix_hash(seed ^ 0xA5A5u, (unsigned)(i * KK + k)) & (TT - 1);
      targets[KK + k] = unmatched[r % neg_count];
    }
  }
  __syncthreads();
  int idx = idxB_of_A[i];
  int u = idx >= 0 ? idx : 0;
  int wave = threadIdx.x >> 6;
  for (int t = wave; t < 10; t += 4) {
    float d = wave_dot(Bd + (size_t)u * CC, Bd + (size_t)targets[t] * CC);
    if ((threadIdx.x & 63) == 0) dots[t] = d;
  }
  __syncthreads();
  if (threadIdx.x == 0) {
    float hsum = 0.f; int pcnt = 0;
    float iu = invB[u];
    for (int k = 0; k < KK; ++k) {
      if (tmask[k]) {
        float dpos = 1.f - dots[k] * iu * invB[targets[k]];
        float dneg = 1.f - dots[KK + k] * iu * invB[targets[KK + k]];
        float h = dpos - dneg + 0.4f;
        hsum += (h > 0.f) ? h : 0.f;
        pcnt++;
      }
    }
    if (idx >= 0 && pcnt > 0) {
      atomicAdd(&acc[0], hsum / (float)pcnt);
      atomicAdd(&acc[1], 1.0f);
    }
  }
}

// ---------------- crossbrain hinge per row ----------------
__global__ __launch_bounds__(256) void cb_hinge_kernel(const float* __restrict__ Bd, const float* __restrict__ invB,
                                                       const int* __restrict__ neighA, unsigned int seed,
                                                       float* __restrict__ acc) {
  int i = blockIdx.x;
  __shared__ int targets[10];
  __shared__ float dots[10];
  if (threadIdx.x == 0) {
    int pos[KK];
    for (int k = 0; k < KK; ++k) { pos[k] = neighA[(size_t)i * KK + k]; targets[k] = pos[k]; }
    unsigned int ctr = 0;
    for (int k = 0; k < KK; ++k) {
      int cand;
      while (true) {
        unsigned int h = mix_hash(seed ^ (unsigned)i, ctr++);
        cand = (int)(h & (TT - 1));
        bool bad = (cand == i);
        for (int t = 0; t < KK; ++t) bad = bad || (cand == pos[t]);
        for (int t = 0; t < k; ++t) bad = bad || (cand == targets[KK + t]);
        if (!bad) break;
      }
      targets[KK + k] = cand;
    }
  }
  __syncthreads();
  int wave = threadIdx.x >> 6;
  for (int t = wave; t < 10; t += 4) {
    float d = wave_dot(Bd + (size_t)i * CC, Bd + (size_t)targets[t] * CC);
    if ((threadIdx.x & 63) == 0) dots[t] = d;
  }
  __syncthreads();
  if (threadIdx.x == 0) {
    float hsum = 0.f;
    float ii = invB[i];
    const float lo = -1.f + 1e-8f, hi = 1.f - 1e-8f;
    for (int k = 0; k < KK; ++k) {
      float sp = fminf(fmaxf(dots[k] * ii * invB[targets[k]], lo), hi);
      float sn = fminf(fmaxf(dots[KK + k] * ii * invB[targets[KK + k]], lo), hi);
      float h = sn - sp + 0.05f;
      hsum += (h > 0.f) ? h : 0.f;
    }
    atomicAdd(acc, hsum);
  }
}

// ---------------- final combine ----------------
__global__ void final_kernel(const float* __restrict__ cb_acc, const float* __restrict__ nrc_acc,
                             float* __restrict__ out) {
  float loss2 = 0.f;
  for (int c = 0; c < 8; ++c) loss2 += cb_acc[c] * (1.0f / 10240.0f);
  loss2 *= 0.25f;
  float loss3 = 0.f;
  for (int d = 0; d < 2; ++d) {
    float s = 0.f;
    for (int t = 0; t < 6; ++t) {
      float cnt = nrc_acc[(d * 6 + t) * 2 + 1];
      float sum = nrc_acc[(d * 6 + t) * 2 + 0];
      s += (cnt > 0.f) ? (sum / cnt) : 0.f;
    }
    loss3 += s * (1.f / 6.f);
  }
  out[0] = 10.f * loss2 + 10.f * loss3;
}

// ---------------- host-side numpy RandomState(seed).permutation(12)[:6] ----------------
namespace {
struct MT19937 {
  uint32_t mt[624]; int mti;
  void seed(uint32_t s) {
    mt[0] = s;
    for (int i = 1; i < 624; ++i) mt[i] = 1812433253u * (mt[i - 1] ^ (mt[i - 1] >> 30)) + (uint32_t)i;
    mti = 624;
  }
  uint32_t next() {
    if (mti >= 624) {
      for (int i = 0; i < 624; ++i) {
        uint32_t y = (mt[i] & 0x80000000u) | (mt[(i + 1) % 624] & 0x7fffffffu);
        uint32_t v = y >> 1;
        if (y & 1u) v ^= 0x9908b0dfu;
        mt[i] = mt[(i + 397) % 624] ^ v;
      }
      mti = 0;
    }
    uint32_t y = mt[mti++];
    y ^= y >> 11; y ^= (y << 7) & 0x9d2c5680u; y ^= (y << 15) & 0xefc60000u; y ^= y >> 18;
    return y;
  }
  uint32_t interval(uint32_t mx) {
    uint32_t mask = mx;
    mask |= mask >> 1; mask |= mask >> 2; mask |= mask >> 4; mask |= mask >> 8; mask |= mask >> 16;
    while (true) { uint32_t v = next() & mask; if (v <= mx) return v; }
  }
};
inline void np_perm12_first6(uint32_t seed, int* sel6) {
  int a[12]; for (int i = 0; i < 12; ++i) a[i] = i;
  MT19937 r; r.seed(seed);
  for (int i = 11; i >= 1; --i) { uint32_t j = r.interval((uint32_t)i); int t = a[i]; a[i] = a[j]; a[j] = t; }
  for (int i = 0; i < 6; ++i) sel6[i] = a[i];
}
}  // namespace

extern "C" void kernel_launch(void* const* d_in, const int* in_sizes, int n_in,
                              void* d_out, int out_size, void* d_ws, size_t ws_size,
                              hipStream_t stream) {
  const float* z1 = (const float*)d_in[0];
  const float* z2 = (const float*)d_in[1];
  float* out = (float*)d_out;

  char* base = (char*)d_ws;
  size_t off = 0;
  auto alloc = [&](size_t bytes) -> void* {
    void* p = base + off;
    off = (off + bytes + 255) & ~(size_t)255;
    return p;
  };
  float* gram            = (float*)alloc((size_t)TT * TT * 4);
  unsigned short* zb     = (unsigned short*)alloc((size_t)8 * TT * CC * 2);
  float* sq              = (float*)alloc((size_t)8 * TT * 4);
  float* inv             = (float*)alloc((size_t)8 * TT * 4);
  int*   neigh1          = (int*)alloc((size_t)8 * TT * KK * 4);
  int*   neighC          = (int*)alloc((size_t)8 * TT * KK * 4);
  float* prv             = (float*)alloc((size_t)32 * TT * 4);
  int*   pri             = (int*)alloc((size_t)32 * TT * 4);
  float* pcv             = (float*)alloc((size_t)32 * TT * 4);
  int*   pci             = (int*)alloc((size_t)32 * TT * 4);
  int*   b_of_a          = (int*)alloc((size_t)TT * 4);
  int*   a_of_b          = (int*)alloc((size_t)TT * 4);
  int*   idxB            = (int*)alloc((size_t)TT * 4);
  int*   matchedB        = (int*)alloc((size_t)TT * 4);
  int*   unmatched       = (int*)alloc((size_t)TT * 4);
  int*   scalars         = (int*)alloc(64);
  float* accs            = (float*)alloc(64 * 4);
  float* cb_acc          = accs;
  float* nrc_acc         = accs + 8;

  hipMemsetAsync(accs, 0, 64 * 4, stream);

  auto slice = [&](int s) -> const float* {
    return (s < 4) ? (z1 + (size_t)s * TT * CC) : (z2 + (size_t)(s - 4) * TT * CC);
  };
  auto slice_bf = [&](int s) -> const unsigned short* {
    return zb + (size_t)s * TT * CC;
  };

  tobf16_kernel<<<(8 * TT * CC) / (256 * 8), 256, 0, stream>>>(z1, z2, zb);
  rownorm_kernel<<<8 * TT, 256, 0, stream>>>(z1, z2, sq, inv);

  dim3 ggrid(TT / 128, TT / 128);
  for (int s = 0; s < 8; ++s) {
    gram_mfma_kernel<<<ggrid, 256, 0, stream>>>(slice_bf(s), slice_bf(s), gram);
    top5_fused_kernel<<<TT, 256, 0, stream>>>(gram, sq + s * TT, inv + s * TT,
                                              neigh1 + (size_t)s * TT * KK, neighC + (size_t)s * TT * KK);
  }

  for (int c = 0; c < 8; ++c) {
    int sa = c;
    int sb = (c < 4) ? (c + 4) : (c - 4);
    cb_hinge_kernel<<<TT, 256, 0, stream>>>(slice(sb), inv + sb * TT, neigh1 + (size_t)sa * TT * KK,
                                            0x13579BDFu + 0x9E3779B9u * (unsigned)c, cb_acc + c);
  }

  int sel0[6], sel1[6];
  np_perm12_first6(0u, sel0);
  np_perm12_first6(1u, sel1);
  static const int PP[12] = {0, 0, 0, 1, 1, 1, 2, 2, 2, 3, 3, 3};
  static const int QQ[12] = {1, 2, 3, 0, 2, 3, 0, 1, 3, 0, 1, 2};

  dim3 agrid(32, 32);
  for (int d = 0; d < 2; ++d) {
    const int* sel = (d == 0) ? sel0 : sel1;
    for (int t = 0; t < 6; ++t) {
      int pi_ = PP[sel[t]], qi = QQ[sel[t]];
      int sa = (d == 0) ? pi_ : 4 + pi_;
      int sb = (d == 0) ? 4 + qi : qi;
      gram_mfma_kernel<<<ggrid, 256, 0, stream>>>(slice_bf(sa), slice_bf(sb), gram);
      argmin_tile_kernel<<<agrid, 256, 0, stream>>>(gram, inv + sa * TT, inv + sb * TT, prv, pri, pcv, pci);
      argmin_reduce_kernel<<<2 * TT / 256, 256, 0, stream>>>(prv, pri, pcv, pci, b_of_a, a_of_b);
      mutual_kernel<<<1, 256, 0, stream>>>(b_of_a, a_of_b, idxB, matchedB, unmatched, scalars);
      nrc_hinge_kernel<<<TT, 256, 0, stream>>>(slice(sb), inv + sb * TT, neighC + (size_t)sa * TT * KK,
                                               idxB, unmatched, scalars,
                                               0xC0FFEE11u + 0x9E3779B9u * (unsigned)(d * 6 + t),
                                               nrc_acc + (d * 6 + t) * 2);
    }
  }

  final_kernel<<<1, 1, 0, stream>>>(cb_acc, nrc_acc, out);
}

// Round 4
// 1086.397 us; speedup vs baseline: 3.6047x; 1.6857x over previous
//
#include <hip/hip_runtime.h>
#include <cstdint>
#include <cstddef>

#define TT 2048
#define CC 768
#define KK 5

typedef __attribute__((ext_vector_type(8))) short short8;
typedef __attribute__((ext_vector_type(4))) float float4v;

struct PairTab { int sa[12]; int sb[12]; };

// ---------------- device RNG hash ----------------
__device__ __forceinline__ unsigned int mix_hash(unsigned int a, unsigned int b) {
  unsigned long long x = (((unsigned long long)a) << 32) | (unsigned long long)b;
  x ^= x >> 33; x *= 0xff51afd7ed558ccdULL;
  x ^= x >> 33; x *= 0xc4ceb9fe1a85ec53ULL;
  x ^= x >> 33;
  return (unsigned int)(x & 0xffffffffu);
}

__device__ __forceinline__ unsigned short f2bf(float x) {  // RNE fp32->bf16
  union { float f; unsigned int u; } v; v.f = x;
  unsigned int r = v.u + 0x7fffu + ((v.u >> 16) & 1u);
  return (unsigned short)(r >> 16);
}

__device__ __forceinline__ void gload_lds16(const void* g, void* l) {
  __builtin_amdgcn_global_load_lds(
      (const __attribute__((address_space(1))) unsigned int*)g,
      (__attribute__((address_space(3))) unsigned int*)l, 16, 0, 0);
}

__device__ __forceinline__ const float* slice_f(const float* z1, const float* z2, int s) {
  return (s < 4) ? (z1 + (size_t)s * TT * CC) : (z2 + (size_t)(s - 4) * TT * CC);
}

// ---------------- fp32 -> bf16 convert ----------------
__global__ __launch_bounds__(256) void tobf16_kernel(const float* __restrict__ z1, const float* __restrict__ z2,
                                                     unsigned short* __restrict__ out) {
  size_t i = ((size_t)blockIdx.x * 256 + threadIdx.x) * 8;
  const size_t half = (size_t)4 * TT * CC;
  const float* src = (i < half) ? (z1 + i) : (z2 + (i - half));
  float4 a = ((const float4*)src)[0];
  float4 b = ((const float4*)src)[1];
  short8 o;
  o[0] = (short)f2bf(a.x); o[1] = (short)f2bf(a.y); o[2] = (short)f2bf(a.z); o[3] = (short)f2bf(a.w);
  o[4] = (short)f2bf(b.x); o[5] = (short)f2bf(b.y); o[6] = (short)f2bf(b.z); o[7] = (short)f2bf(b.w);
  *(short8*)(out + i) = o;
}

// ---------------- row norms ----------------
__global__ __launch_bounds__(256) void rownorm_kernel(const float* __restrict__ z1, const float* __restrict__ z2,
                                                      float* __restrict__ sq, float* __restrict__ inv) {
  int r = blockIdx.x;
  const float* p = (r < 4 * TT) ? (z1 + (size_t)r * CC) : (z2 + (size_t)(r - 4 * TT) * CC);
  float s = 0.f;
  for (int k = threadIdx.x; k < CC; k += 256) { float v = p[k]; s += v * v; }
  __shared__ float red[256];
  red[threadIdx.x] = s; __syncthreads();
  for (int off = 128; off > 0; off >>= 1) {
    if (threadIdx.x < off) red[threadIdx.x] += red[threadIdx.x + off];
    __syncthreads();
  }
  if (threadIdx.x == 0) { sq[r] = red[0]; inv[r] = rsqrtf(red[0] + 1e-12f); }
}

// ---------------- bf16 MFMA gram core ----------------
__device__ __forceinline__ void gram_body(const unsigned short* __restrict__ A,
                                          const unsigned short* __restrict__ B,
                                          float* __restrict__ G, int bm, int bn) {
  __shared__ unsigned short As[128 * 32];
  __shared__ unsigned short Bs[128 * 32];
  const int lane = threadIdx.x & 63, waveId = threadIdx.x >> 6;
  const int wm = (waveId >> 1) * 64, wn = (waveId & 1) * 64;
  const int lrow = lane & 15, lquad = lane >> 4;

  float4v acc[4][4];
#pragma unroll
  for (int i = 0; i < 4; ++i)
#pragma unroll
    for (int j = 0; j < 4; ++j) acc[i][j] = (float4v){0.f, 0.f, 0.f, 0.f};

  for (int kk = 0; kk < CC; kk += 32) {
#pragma unroll
    for (int c = 0; c < 2; ++c) {
      int l = c * 256 + threadIdx.x;
      int row = l >> 2, kc = (l & 3) * 8;
      gload_lds16(A + (size_t)(bm + row) * CC + kk + kc, &As[l * 8]);
      gload_lds16(B + (size_t)(bn + row) * CC + kk + kc, &Bs[l * 8]);
    }
    __syncthreads();
    short8 af[4], bfr[4];
#pragma unroll
    for (int i = 0; i < 4; ++i) {
      af[i]  = *(const short8*)&As[(wm + i * 16 + lrow) * 32 + lquad * 8];
      bfr[i] = *(const short8*)&Bs[(wn + i * 16 + lrow) * 32 + lquad * 8];
    }
#pragma unroll
    for (int i = 0; i < 4; ++i)
#pragma unroll
      for (int j = 0; j < 4; ++j)
        acc[i][j] = __builtin_amdgcn_mfma_f32_16x16x32_bf16(af[i], bfr[j], acc[i][j], 0, 0, 0);
    __syncthreads();
  }
#pragma unroll
  for (int i = 0; i < 4; ++i) {
    int row0 = bm + wm + i * 16 + lquad * 4;
#pragma unroll
    for (int j = 0; j < 4; ++j) {
      int col = bn + wn + j * 16 + lrow;
#pragma unroll
      for (int r = 0; r < 4; ++r) G[(size_t)(row0 + r) * TT + col] = acc[i][j][r];
    }
  }
}

// self grams: blockIdx.z = slice s in 0..7, gram slot s
__global__ __launch_bounds__(256) void gram_self_batched(const unsigned short* __restrict__ zb,
                                                         float* __restrict__ gram) {
  int s = blockIdx.z;
  const unsigned short* A = zb + (size_t)s * TT * CC;
  float* G = gram + (size_t)s * TT * TT;
  gram_body(A, A, G, blockIdx.y * 128, blockIdx.x * 128);
}

// cross grams: blockIdx.z = pair p in 0..11, gram slot p
__global__ __launch_bounds__(256) void gram_cross_batched(const unsigned short* __restrict__ zb,
                                                          float* __restrict__ gram, PairTab tab) {
  int p = blockIdx.z;
  const unsigned short* A = zb + (size_t)tab.sa[p] * TT * CC;
  const unsigned short* B = zb + (size_t)tab.sb[p] * TT * CC;
  float* G = gram + (size_t)p * TT * TT;
  gram_body(A, B, G, blockIdx.y * 128, blockIdx.x * 128);
}

// ---------------- fused dual-mode top-5, batched over 8 slices ----------------
__global__ __launch_bounds__(256) void top5_batched(const float* __restrict__ gram, const float* __restrict__ sqAll,
                                                    const float* __restrict__ invAll, int* __restrict__ out0,
                                                    int* __restrict__ out1) {
  int i = blockIdx.x;
  int s = blockIdx.y;
  const float* G = gram + (size_t)s * TT * TT;
  const float* sq = sqAll + (size_t)s * TT;
  const float* inv = invAll + (size_t)s * TT;
  __shared__ float k0[TT];
  __shared__ float k1[TT];
  __shared__ float wv[4];
  __shared__ int wi[4];
  __shared__ int sel_sh[2][KK];
  int lane = threadIdx.x & 63, w = threadIdx.x >> 6;
#pragma unroll
  for (int t = 0; t < 2; ++t) {
    int j4 = (t * 256 + threadIdx.x) * 4;
    float4 g4 = *(const float4*)&G[(size_t)i * TT + j4];
    float4 s4 = *(const float4*)&sq[j4];
    float4 v4 = *(const float4*)&inv[j4];
    k0[j4 + 0] = s4.x - 2.f * g4.x; k1[j4 + 0] = -g4.x * v4.x;
    k0[j4 + 1] = s4.y - 2.f * g4.y; k1[j4 + 1] = -g4.y * v4.y;
    k0[j4 + 2] = s4.z - 2.f * g4.z; k1[j4 + 2] = -g4.z * v4.z;
    k0[j4 + 3] = s4.w - 2.f * g4.w; k1[j4 + 3] = -g4.w * v4.w;
  }
  __syncthreads();
  if (threadIdx.x == 0) { k0[i] = INFINITY; k1[i] = INFINITY; }
  __syncthreads();
  for (int mode = 0; mode < 2; ++mode) {
    float* ks = mode ? k1 : k0;
    for (int r = 0; r < KK; ++r) {
      float best = INFINITY; int bidx = TT;
      for (int j = threadIdx.x; j < TT; j += 256) {
        float v = ks[j];
        if (v < best) { best = v; bidx = j; }
      }
#pragma unroll
      for (int off = 32; off > 0; off >>= 1) {
        float v2 = __shfl_down(best, off, 64);
        int i2 = __shfl_down(bidx, off, 64);
        if (v2 < best || (v2 == best && i2 < bidx)) { best = v2; bidx = i2; }
      }
      if (lane == 0) { wv[w] = best; wi[w] = bidx; }
      __syncthreads();
      if (threadIdx.x == 0) {
        float b2 = wv[0]; int x2 = wi[0];
#pragma unroll
        for (int q = 1; q < 4; ++q) {
          if (wv[q] < b2 || (wv[q] == b2 && wi[q] < x2)) { b2 = wv[q]; x2 = wi[q]; }
        }
        sel_sh[mode][r] = x2; ks[x2] = INFINITY;
      }
      __syncthreads();
    }
  }
  if (threadIdx.x < KK) {
    out0[((size_t)s * TT + i) * KK + threadIdx.x] = sel_sh[0][threadIdx.x];
    out1[((size_t)s * TT + i) * KK + threadIdx.x] = sel_sh[1][threadIdx.x];
  }
}

// ---------------- tiled dual argmin stage 1, batched over 12 pairs ----------------
__global__ __launch_bounds__(256) void argmin_tile_batched(const float* __restrict__ gram,
                                                           const float* __restrict__ invAll, PairTab tab,
                                                           float* __restrict__ prv, int* __restrict__ pri,
                                                           float* __restrict__ pcv, int* __restrict__ pci) {
  int p = blockIdx.z;
  const float* G = gram + (size_t)p * TT * TT;
  const float* invA = invAll + (size_t)tab.sa[p] * TT;
  const float* invB = invAll + (size_t)tab.sb[p] * TT;
  int bj = blockIdx.x, bi = blockIdx.y;
  int lane = threadIdx.x & 63, w = threadIdx.x >> 6;
  int j = bj * 64 + lane;
  __shared__ float sA[64];
  if (threadIdx.x < 64) sA[threadIdx.x] = invA[bi * 64 + threadIdx.x];
  float invBj = invB[j];
  __syncthreads();
  float cbest = INFINITY; int cidx = TT;
  for (int r = w; r < 64; r += 4) {
    int i = bi * 64 + r;
    float g = G[(size_t)i * TT + j];
    float kc = -g * sA[r];
    if (kc < cbest) { cbest = kc; cidx = i; }
    float v = -g * invBj; int idx = j;
#pragma unroll
    for (int off = 32; off > 0; off >>= 1) {
      float v2 = __shfl_down(v, off, 64);
      int i2 = __shfl_down(idx, off, 64);
      if (v2 < v || (v2 == v && i2 < idx)) { v = v2; idx = i2; }
    }
    if (lane == 0) {
      prv[((size_t)p * 32 + bj) * TT + i] = v;
      pri[((size_t)p * 32 + bj) * TT + i] = idx;
    }
  }
  __shared__ float cv[256];
  __shared__ int ci[256];
  cv[threadIdx.x] = cbest; ci[threadIdx.x] = cidx;
  __syncthreads();
  if (w == 0) {
    float best = cbest; int bidx = cidx;
#pragma unroll
    for (int q = 1; q < 4; ++q) {
      float v2 = cv[lane + q * 64]; int i2 = ci[lane + q * 64];
      if (v2 < best || (v2 == best && i2 < bidx)) { best = v2; bidx = i2; }
    }
    pcv[((size_t)p * 32 + bi) * TT + j] = best;
    pci[((size_t)p * 32 + bi) * TT + j] = bidx;
  }
}

// ---------------- argmin stage 2, batched ----------------
__global__ __launch_bounds__(256) void argmin_reduce_batched(const float* __restrict__ prv, const int* __restrict__ pri,
                                                             const float* __restrict__ pcv, const int* __restrict__ pci,
                                                             int* __restrict__ b_of_a, int* __restrict__ a_of_b) {
  int p = blockIdx.y;
  int t = blockIdx.x * 256 + threadIdx.x;  // 0..2*TT-1
  int isRow = t < TT;
  int x = isRow ? t : t - TT;
  const float* pv = (isRow ? prv : pcv) + (size_t)p * 32 * TT;
  const int* pi = (isRow ? pri : pci) + (size_t)p * 32 * TT;
  float best = INFINITY; int bidx = TT;
  for (int s = 0; s < 32; ++s) {
    float v = pv[(size_t)s * TT + x]; int id = pi[(size_t)s * TT + x];
    if (v < best || (v == best && id < bidx)) { best = v; bidx = id; }
  }
  if (isRow) b_of_a[(size_t)p * TT + x] = bidx;
  else       a_of_b[(size_t)p * TT + x] = bidx;
}

// ---------------- mutual matching, batched: one block per pair ----------------
__global__ __launch_bounds__(256) void mutual_batched(const int* __restrict__ b_of_a_all,
                                                      const int* __restrict__ a_of_b_all,
                                                      int* __restrict__ idxB_all, int* __restrict__ matchedB_all,
                                                      int* __restrict__ unmatched_all, int* __restrict__ scalars_all) {
  int p = blockIdx.x;
  const int* b_of_a = b_of_a_all + (size_t)p * TT;
  const int* a_of_b = a_of_b_all + (size_t)p * TT;
  int* idxB_of_A = idxB_all + (size_t)p * TT;
  int* matchedB = matchedB_all + (size_t)p * TT;
  int* unmatched = unmatched_all + (size_t)p * TT;
  __shared__ int cnt_sh;
  for (int j = threadIdx.x; j < TT; j += 256) matchedB[j] = 0;
  __syncthreads();
  for (int i = threadIdx.x; i < TT; i += 256) {
    int b = b_of_a[i];
    bool mut = (a_of_b[b] == i);
    idxB_of_A[i] = mut ? b : -1;
    if (mut) matchedB[b] = 1;
  }
  __syncthreads();
  if (threadIdx.x == 0) cnt_sh = 0;
  __syncthreads();
  for (int j = threadIdx.x; j < TT; j += 256) {
    if (!matchedB[j]) { int q = atomicAdd(&cnt_sh, 1); unmatched[q] = j; }
  }
  __syncthreads();
  if (threadIdx.x == 0) {
    int c = cnt_sh;
    if (c == 0) { unmatched[0] = 0; c = 1; }
    scalars_all[p * 16] = c;
  }
}

// ---------------- wave-level dot ----------------
__device__ __forceinline__ float wave_dot(const float* __restrict__ x, const float* __restrict__ y) {
  int lane = threadIdx.x & 63;
  float s = 0.f;
#pragma unroll
  for (int m = 0; m < CC / 64; ++m) s = fmaf(x[lane + m * 64], y[lane + m * 64], s);
#pragma unroll
  for (int off = 32; off > 0; off >>= 1) s += __shfl_down(s, off, 64);
  return s;
}

// ---------------- NRC hinge, batched over 12 pairs ----------------
__global__ __launch_bounds__(256) void nrc_hinge_batched(const float* __restrict__ z1, const float* __restrict__ z2,
                                                         const float* __restrict__ invAll,
                                                         const int* __restrict__ neighC,
                                                         const int* __restrict__ idxB_all,
                                                         const int* __restrict__ unmatched_all,
                                                         const int* __restrict__ scalars_all,
                                                         PairTab tab, float* __restrict__ nrc_acc) {
  int p = blockIdx.y;
  int i = blockIdx.x;
  int sa = tab.sa[p], sb = tab.sb[p];
  const float* Bd = slice_f(z1, z2, sb);
  const float* invB = invAll + (size_t)sb * TT;
  const int* neighA = neighC + (size_t)sa * TT * KK;
  const int* idxB_of_A = idxB_all + (size_t)p * TT;
  const int* unmatched = unmatched_all + (size_t)p * TT;
  unsigned int seed = 0xC0FFEE11u + 0x9E3779B9u * (unsigned)p;
  float* acc = nrc_acc + p * 2;

  __shared__ int targets[10];
  __shared__ int tmask[KK];
  __shared__ float dots[10];
  if (threadIdx.x == 0) {
    unsigned int neg_count = (unsigned int)scalars_all[p * 16];
    for (int k = 0; k < KK; ++k) {
      int nb = neighA[(size_t)i * KK + k];
      int pb = idxB_of_A[nb];
      tmask[k] = (pb >= 0) ? 1 : 0;
      targets[k] = (pb >= 0) ? pb : 0;
      unsigned int r = mix_hash(seed ^ 0xA5A5u, (unsigned)(i * KK + k)) & (TT - 1);
      targets[KK + k] = unmatched[r % neg_count];
    }
  }
  __syncthreads();
  int idx = idxB_of_A[i];
  int u = idx >= 0 ? idx : 0;
  int wave = threadIdx.x >> 6;
  for (int t = wave; t < 10; t += 4) {
    float d = wave_dot(Bd + (size_t)u * CC, Bd + (size_t)targets[t] * CC);
    if ((threadIdx.x & 63) == 0) dots[t] = d;
  }
  __syncthreads();
  if (threadIdx.x == 0) {
    float hsum = 0.f; int pcnt = 0;
    float iu = invB[u];
    for (int k = 0; k < KK; ++k) {
      if (tmask[k]) {
        float dpos = 1.f - dots[k] * iu * invB[targets[k]];
        float dneg = 1.f - dots[KK + k] * iu * invB[targets[KK + k]];
        float h = dpos - dneg + 0.4f;
        hsum += (h > 0.f) ? h : 0.f;
        pcnt++;
      }
    }
    if (idx >= 0 && pcnt > 0) {
      atomicAdd(&acc[0], hsum / (float)pcnt);
      atomicAdd(&acc[1], 1.0f);
    }
  }
}

// ---------------- crossbrain hinge, batched over 8 combos ----------------
__global__ __launch_bounds__(256) void cb_hinge_batched(const float* __restrict__ z1, const float* __restrict__ z2,
                                                        const float* __restrict__ invAll,
                                                        const int* __restrict__ neigh1,
                                                        float* __restrict__ cb_acc) {
  int c = blockIdx.y;
  int i = blockIdx.x;
  int sa = c;
  int sb = (c < 4) ? (c + 4) : (c - 4);
  const float* Bd = slice_f(z1, z2, sb);
  const float* invB = invAll + (size_t)sb * TT;
  const int* neighA = neigh1 + (size_t)sa * TT * KK;
  unsigned int seed = 0x13579BDFu + 0x9E3779B9u * (unsigned)c;

  __shared__ int targets[10];
  __shared__ float dots[10];
  if (threadIdx.x == 0) {
    int pos[KK];
    for (int k = 0; k < KK; ++k) { pos[k] = neighA[(size_t)i * KK + k]; targets[k] = pos[k]; }
    unsigned int ctr = 0;
    for (int k = 0; k < KK; ++k) {
      int cand;
      while (true) {
        unsigned int h = mix_hash(seed ^ (unsigned)i, ctr++);
        cand = (int)(h & (TT - 1));
        bool bad = (cand == i);
        for (int t = 0; t < KK; ++t) bad = bad || (cand == pos[t]);
        for (int t = 0; t < k; ++t) bad = bad || (cand == targets[KK + t]);
        if (!bad) break;
      }
      targets[KK + k] = cand;
    }
  }
  __syncthreads();
  int wave = threadIdx.x >> 6;
  for (int t = wave; t < 10; t += 4) {
    float d = wave_dot(Bd + (size_t)i * CC, Bd + (size_t)targets[t] * CC);
    if ((threadIdx.x & 63) == 0) dots[t] = d;
  }
  __syncthreads();
  if (threadIdx.x == 0) {
    float hsum = 0.f;
    float ii = invB[i];
    const float lo = -1.f + 1e-8f, hi = 1.f - 1e-8f;
    for (int k = 0; k < KK; ++k) {
      float sp = fminf(fmaxf(dots[k] * ii * invB[targets[k]], lo), hi);
      float sn = fminf(fmaxf(dots[KK + k] * ii * invB[targets[KK + k]], lo), hi);
      float h = sn - sp + 0.05f;
      hsum += (h > 0.f) ? h : 0.f;
    }
    atomicAdd(&cb_acc[c], hsum);
  }
}

// ---------------- final combine ----------------
__global__ void final_kernel(const float* __restrict__ cb_acc, const float* __restrict__ nrc_acc,
                             float* __restrict__ out) {
  float loss2 = 0.f;
  for (int c = 0; c < 8; ++c) loss2 += cb_acc[c] * (1.0f / 10240.0f);
  loss2 *= 0.25f;
  float loss3 = 0.f;
  for (int d = 0; d < 2; ++d) {
    float s = 0.f;
    for (int t = 0; t < 6; ++t) {
      float cnt = nrc_acc[(d * 6 + t) * 2 + 1];
      float sum = nrc_acc[(d * 6 + t) * 2 + 0];
      s += (cnt > 0.f) ? (sum / cnt) : 0.f;
    }
    loss3 += s * (1.f / 6.f);
  }
  out[0] = 10.f * loss2 + 10.f * loss3;
}

// ---------------- host-side numpy RandomState(seed).permutation(12)[:6] ----------------
namespace {
struct MT19937 {
  uint32_t mt[624]; int mti;
  void seed(uint32_t s) {
    mt[0] = s;
    for (int i = 1; i < 624; ++i) mt[i] = 1812433253u * (mt[i - 1] ^ (mt[i - 1] >> 30)) + (uint32_t)i;
    mti = 624;
  }
  uint32_t next() {
    if (mti >= 624) {
      for (int i = 0; i < 624; ++i) {
        uint32_t y = (mt[i] & 0x80000000u) | (mt[(i + 1) % 624] & 0x7fffffffu);
        uint32_t v = y >> 1;
        if (y & 1u) v ^= 0x9908b0dfu;
        mt[i] = mt[(i + 397) % 624] ^ v;
      }
      mti = 0;
    }
    uint32_t y = mt[mti++];
    y ^= y >> 11; y ^= (y << 7) & 0x9d2c5680u; y ^= (y << 15) & 0xefc60000u; y ^= y >> 18;
    return y;
  }
  uint32_t interval(uint32_t mx) {
    uint32_t mask = mx;
    mask |= mask >> 1; mask |= mask >> 2; mask |= mask >> 4; mask |= mask >> 8; mask |= mask >> 16;
    while (true) { uint32_t v = next() & mask; if (v <= mx) return v; }
  }
};
inline void np_perm12_first6(uint32_t seed, int* sel6) {
  int a[12]; for (int i = 0; i < 12; ++i) a[i] = i;
  MT19937 r; r.seed(seed);
  for (int i = 11; i >= 1; --i) { uint32_t j = r.interval((uint32_t)i); int t = a[i]; a[i] = a[j]; a[j] = t; }
  for (int i = 0; i < 6; ++i) sel6[i] = a[i];
}
}  // namespace

extern "C" void kernel_launch(void* const* d_in, const int* in_sizes, int n_in,
                              void* d_out, int out_size, void* d_ws, size_t ws_size,
                              hipStream_t stream) {
  const float* z1 = (const float*)d_in[0];
  const float* z2 = (const float*)d_in[1];
  float* out = (float*)d_out;

  char* base = (char*)d_ws;
  size_t off = 0;
  auto alloc = [&](size_t bytes) -> void* {
    void* p = base + off;
    off = (off + bytes + 255) & ~(size_t)255;
    return p;
  };
  float* gram            = (float*)alloc((size_t)12 * TT * TT * 4);   // 201.3 MB: self uses slots 0..7, cross 0..11
  unsigned short* zb     = (unsigned short*)alloc((size_t)8 * TT * CC * 2);  // 25.2 MB
  float* sq              = (float*)alloc((size_t)8 * TT * 4);
  float* inv             = (float*)alloc((size_t)8 * TT * 4);
  int*   neigh1          = (int*)alloc((size_t)8 * TT * KK * 4);
  int*   neighC          = (int*)alloc((size_t)8 * TT * KK * 4);
  float* prv             = (float*)alloc((size_t)12 * 32 * TT * 4);
  int*   pri             = (int*)alloc((size_t)12 * 32 * TT * 4);
  float* pcv             = (float*)alloc((size_t)12 * 32 * TT * 4);
  int*   pci             = (int*)alloc((size_t)12 * 32 * TT * 4);
  int*   b_of_a          = (int*)alloc((size_t)12 * TT * 4);
  int*   a_of_b          = (int*)alloc((size_t)12 * TT * 4);
  int*   idxB            = (int*)alloc((size_t)12 * TT * 4);
  int*   matchedB        = (int*)alloc((size_t)12 * TT * 4);
  int*   unmatched       = (int*)alloc((size_t)12 * TT * 4);
  int*   scalars         = (int*)alloc(12 * 16 * 4);
  float* accs            = (float*)alloc(64 * 4);
  float* cb_acc          = accs;
  float* nrc_acc         = accs + 8;

  hipMemsetAsync(accs, 0, 64 * 4, stream);

  // prep
  tobf16_kernel<<<(8 * TT * CC) / (256 * 8), 256, 0, stream>>>(z1, z2, zb);
  rownorm_kernel<<<8 * TT, 256, 0, stream>>>(z1, z2, sq, inv);

  // self phase: 1 gram launch + 1 top5 launch
  gram_self_batched<<<dim3(TT / 128, TT / 128, 8), 256, 0, stream>>>(zb, gram);
  top5_batched<<<dim3(TT, 8), 256, 0, stream>>>(gram, sq, inv, neigh1, neighC);

  // crossbrain: 1 launch
  cb_hinge_batched<<<dim3(TT, 8), 256, 0, stream>>>(z1, z2, inv, neigh1, cb_acc);

  // NRC pair selection (numpy RandomState(seed).permutation(12)[:6])
  int sel0[6], sel1[6];
  np_perm12_first6(0u, sel0);
  np_perm12_first6(1u, sel1);
  static const int PP[12] = {0, 0, 0, 1, 1, 1, 2, 2, 2, 3, 3, 3};
  static const int QQ[12] = {1, 2, 3, 0, 2, 3, 0, 1, 3, 0, 1, 2};
  PairTab tab;
  for (int d = 0; d < 2; ++d) {
    const int* sel = (d == 0) ? sel0 : sel1;
    for (int t = 0; t < 6; ++t) {
      int pi_ = PP[sel[t]], qi = QQ[sel[t]];
      int p = d * 6 + t;
      tab.sa[p] = (d == 0) ? pi_ : 4 + pi_;
      tab.sb[p] = (d == 0) ? 4 + qi : qi;
    }
  }

  // cross phase: fully batched
  gram_cross_batched<<<dim3(TT / 128, TT / 128, 12), 256, 0, stream>>>(zb, gram, tab);
  argmin_tile_batched<<<dim3(32, 32, 12), 256, 0, stream>>>(gram, inv, tab, prv, pri, pcv, pci);
  argmin_reduce_batched<<<dim3(2 * TT / 256, 12), 256, 0, stream>>>(prv, pri, pcv, pci, b_of_a, a_of_b);
  mutual_batched<<<12, 256, 0, stream>>>(b_of_a, a_of_b, idxB, matchedB, unmatched, scalars);
  nrc_hinge_batched<<<dim3(TT, 12), 256, 0, stream>>>(z1, z2, inv, neighC, idxB, unmatched, scalars, tab, nrc_acc);

  final_kernel<<<1, 1, 0, stream>>>(cb_acc, nrc_acc, out);
}

// Round 5
// 970.404 us; speedup vs baseline: 4.0355x; 1.1195x over previous
//
#include <hip/hip_runtime.h>
#include <cstdint>
#include <cstddef>

#define TT 2048
#define CC 768
#define KK 5

typedef __attribute__((ext_vector_type(8))) short short8;
typedef __attribute__((ext_vector_type(4))) float float4v;

struct PairTab { int sa[12]; int sb[12]; };

// ---------------- device RNG hash ----------------
__device__ __forceinline__ unsigned int mix_hash(unsigned int a, unsigned int b) {
  unsigned long long x = (((unsigned long long)a) << 32) | (unsigned long long)b;
  x ^= x >> 33; x *= 0xff51afd7ed558ccdULL;
  x ^= x >> 33; x *= 0xc4ceb9fe1a85ec53ULL;
  x ^= x >> 33;
  return (unsigned int)(x & 0xffffffffu);
}

__device__ __forceinline__ unsigned short f2bf(float x) {  // RNE fp32->bf16
  union { float f; unsigned int u; } v; v.f = x;
  unsigned int r = v.u + 0x7fffu + ((v.u >> 16) & 1u);
  return (unsigned short)(r >> 16);
}

__device__ __forceinline__ void gload_lds16(const void* g, void* l) {
  __builtin_amdgcn_global_load_lds(
      (const __attribute__((address_space(1))) unsigned int*)g,
      (__attribute__((address_space(3))) unsigned int*)l, 16, 0, 0);
}

// ---------------- fp32 -> bf16 convert ----------------
__global__ __launch_bounds__(256) void tobf16_kernel(const float* __restrict__ z1, const float* __restrict__ z2,
                                                     unsigned short* __restrict__ out) {
  size_t i = ((size_t)blockIdx.x * 256 + threadIdx.x) * 8;
  const size_t half = (size_t)4 * TT * CC;
  const float* src = (i < half) ? (z1 + i) : (z2 + (i - half));
  float4 a = ((const float4*)src)[0];
  float4 b = ((const float4*)src)[1];
  short8 o;
  o[0] = (short)f2bf(a.x); o[1] = (short)f2bf(a.y); o[2] = (short)f2bf(a.z); o[3] = (short)f2bf(a.w);
  o[4] = (short)f2bf(b.x); o[5] = (short)f2bf(b.y); o[6] = (short)f2bf(b.z); o[7] = (short)f2bf(b.w);
  *(short8*)(out + i) = o;
}

// ---------------- row norms ----------------
__global__ __launch_bounds__(256) void rownorm_kernel(const float* __restrict__ z1, const float* __restrict__ z2,
                                                      float* __restrict__ sq, float* __restrict__ inv) {
  int r = blockIdx.x;
  const float* p = (r < 4 * TT) ? (z1 + (size_t)r * CC) : (z2 + (size_t)(r - 4 * TT) * CC);
  float s = 0.f;
  for (int k = threadIdx.x; k < CC; k += 256) { float v = p[k]; s += v * v; }
  __shared__ float red[256];
  red[threadIdx.x] = s; __syncthreads();
  for (int off = 128; off > 0; off >>= 1) {
    if (threadIdx.x < off) red[threadIdx.x] += red[threadIdx.x + off];
    __syncthreads();
  }
  if (threadIdx.x == 0) { sq[r] = red[0]; inv[r] = rsqrtf(red[0] + 1e-12f); }
}

// ---------------- self grams (materialized, slots 0..7) ----------------
__global__ __launch_bounds__(256) void gram_self_batched(const unsigned short* __restrict__ zb,
                                                         float* __restrict__ gram) {
  __shared__ unsigned short As[128 * 32];
  __shared__ unsigned short Bs[128 * 32];
  int s = blockIdx.z;
  const unsigned short* A = zb + (size_t)s * TT * CC;
  float* G = gram + (size_t)s * TT * TT;
  const int bm = blockIdx.y * 128, bn = blockIdx.x * 128;
  const int lane = threadIdx.x & 63, waveId = threadIdx.x >> 6;
  const int wm = (waveId >> 1) * 64, wn = (waveId & 1) * 64;
  const int lrow = lane & 15, lquad = lane >> 4;

  float4v acc[4][4];
#pragma unroll
  for (int i = 0; i < 4; ++i)
#pragma unroll
    for (int j = 0; j < 4; ++j) acc[i][j] = (float4v){0.f, 0.f, 0.f, 0.f};

  for (int kk = 0; kk < CC; kk += 32) {
#pragma unroll
    for (int c = 0; c < 2; ++c) {
      int l = c * 256 + threadIdx.x;
      int row = l >> 2, kc = (l & 3) * 8;
      gload_lds16(A + (size_t)(bm + row) * CC + kk + kc, &As[l * 8]);
      gload_lds16(A + (size_t)(bn + row) * CC + kk + kc, &Bs[l * 8]);
    }
    __syncthreads();
    short8 af[4], bfr[4];
#pragma unroll
    for (int i = 0; i < 4; ++i) {
      af[i]  = *(const short8*)&As[(wm + i * 16 + lrow) * 32 + lquad * 8];
      bfr[i] = *(const short8*)&Bs[(wn + i * 16 + lrow) * 32 + lquad * 8];
    }
#pragma unroll
    for (int i = 0; i < 4; ++i)
#pragma unroll
      for (int j = 0; j < 4; ++j)
        acc[i][j] = __builtin_amdgcn_mfma_f32_16x16x32_bf16(af[i], bfr[j], acc[i][j], 0, 0, 0);
    __syncthreads();
  }
#pragma unroll
  for (int i = 0; i < 4; ++i) {
    int row0 = bm + wm + i * 16 + lquad * 4;
#pragma unroll
    for (int j = 0; j < 4; ++j) {
      int col = bn + wn + j * 16 + lrow;
#pragma unroll
      for (int r = 0; r < 4; ++r) G[(size_t)(row0 + r) * TT + col] = acc[i][j][r];
    }
  }
}

// ---------------- cross gram + fused dual argmin partials (no G materialization) ----------------
__global__ __launch_bounds__(256) void gram_cross_argmin(const unsigned short* __restrict__ zb,
                                                         const float* __restrict__ invAll, PairTab tab,
                                                         float* __restrict__ prow_v, int* __restrict__ prow_i,
                                                         float* __restrict__ pcol_v, int* __restrict__ pcol_i) {
  __shared__ unsigned short As[128 * 32];
  __shared__ unsigned short Bs[128 * 32];
  __shared__ float sInvA[128], sInvB[128];
  __shared__ float rowv[2][128]; __shared__ int rowi[2][128];
  __shared__ float colv[2][128]; __shared__ int coli[2][128];

  int p = blockIdx.z;
  const unsigned short* A = zb + (size_t)tab.sa[p] * TT * CC;
  const unsigned short* B = zb + (size_t)tab.sb[p] * TT * CC;
  const float* invA = invAll + (size_t)tab.sa[p] * TT;
  const float* invB = invAll + (size_t)tab.sb[p] * TT;
  const int bm = blockIdx.y * 128, bn = blockIdx.x * 128;
  const int lane = threadIdx.x & 63, waveId = threadIdx.x >> 6;
  const int wm = (waveId >> 1) * 64, wn = (waveId & 1) * 64;
  const int lrow = lane & 15, lquad = lane >> 4;

  if (threadIdx.x < 128) sInvA[threadIdx.x] = invA[bm + threadIdx.x];
  else sInvB[threadIdx.x - 128] = invB[bn + threadIdx.x - 128];

  float4v acc[4][4];
#pragma unroll
  for (int i = 0; i < 4; ++i)
#pragma unroll
    for (int j = 0; j < 4; ++j) acc[i][j] = (float4v){0.f, 0.f, 0.f, 0.f};

  for (int kk = 0; kk < CC; kk += 32) {
#pragma unroll
    for (int c = 0; c < 2; ++c) {
      int l = c * 256 + threadIdx.x;
      int row = l >> 2, kc = (l & 3) * 8;
      gload_lds16(A + (size_t)(bm + row) * CC + kk + kc, &As[l * 8]);
      gload_lds16(B + (size_t)(bn + row) * CC + kk + kc, &Bs[l * 8]);
    }
    __syncthreads();
    short8 af[4], bfr[4];
#pragma unroll
    for (int i = 0; i < 4; ++i) {
      af[i]  = *(const short8*)&As[(wm + i * 16 + lrow) * 32 + lquad * 8];
      bfr[i] = *(const short8*)&Bs[(wn + i * 16 + lrow) * 32 + lquad * 8];
    }
#pragma unroll
    for (int i = 0; i < 4; ++i)
#pragma unroll
      for (int j = 0; j < 4; ++j)
        acc[i][j] = __builtin_amdgcn_mfma_f32_16x16x32_bf16(af[i], bfr[j], acc[i][j], 0, 0, 0);
    __syncthreads();
  }

  // ---- row-min candidates: per (i,r), min over j (ascending col) ----
  float rbv[4][4]; int rbi[4][4];
#pragma unroll
  for (int i = 0; i < 4; ++i)
#pragma unroll
    for (int r = 0; r < 4; ++r) { rbv[i][r] = INFINITY; rbi[i][r] = TT; }
#pragma unroll
  for (int i = 0; i < 4; ++i)
#pragma unroll
    for (int j = 0; j < 4; ++j) {
      int col = bn + wn + j * 16 + lrow;
      float ivb = sInvB[wn + j * 16 + lrow];
#pragma unroll
      for (int r = 0; r < 4; ++r) {
        float v = -acc[i][j][r] * ivb;
        if (v < rbv[i][r]) { rbv[i][r] = v; rbi[i][r] = col; }
      }
    }
  // butterfly across the 16-lane lrow group (masks 1,2,4,8)
#pragma unroll
  for (int m = 1; m <= 8; m <<= 1) {
#pragma unroll
    for (int i = 0; i < 4; ++i)
#pragma unroll
      for (int r = 0; r < 4; ++r) {
        float v2 = __shfl_xor(rbv[i][r], m, 64);
        int i2 = __shfl_xor(rbi[i][r], m, 64);
        if (v2 < rbv[i][r] || (v2 == rbv[i][r] && i2 < rbi[i][r])) { rbv[i][r] = v2; rbi[i][r] = i2; }
      }
  }
  if (lrow == 0) {
#pragma unroll
    for (int i = 0; i < 4; ++i)
#pragma unroll
      for (int r = 0; r < 4; ++r) {
        int lr = wm + i * 16 + lquad * 4 + r;
        rowv[wn >> 6][lr] = rbv[i][r]; rowi[wn >> 6][lr] = rbi[i][r];
      }
  }

  // ---- col-min candidates: per j, min over (i,r) (ascending row) ----
  float cbv[4]; int cbi[4];
#pragma unroll
  for (int j = 0; j < 4; ++j) { cbv[j] = INFINITY; cbi[j] = TT; }
#pragma unroll
  for (int j = 0; j < 4; ++j)
#pragma unroll
    for (int i = 0; i < 4; ++i)
#pragma unroll
      for (int r = 0; r < 4; ++r) {
        int lr = wm + i * 16 + lquad * 4 + r;
        float v = -acc[i][j][r] * sInvA[lr];
        if (v < cbv[j]) { cbv[j] = v; cbi[j] = bm + lr; }
      }
  // butterfly across lquad group (masks 16,32)
#pragma unroll
  for (int m = 16; m <= 32; m <<= 1) {
#pragma unroll
    for (int j = 0; j < 4; ++j) {
      float v2 = __shfl_xor(cbv[j], m, 64);
      int i2 = __shfl_xor(cbi[j], m, 64);
      if (v2 < cbv[j] || (v2 == cbv[j] && i2 < cbi[j])) { cbv[j] = v2; cbi[j] = i2; }
    }
  }
  if (lquad == 0) {
#pragma unroll
    for (int j = 0; j < 4; ++j) {
      int lc = wn + j * 16 + lrow;
      colv[wm >> 6][lc] = cbv[j]; coli[wm >> 6][lc] = cbi[j];
    }
  }
  __syncthreads();

  if (threadIdx.x < 128) {
    int t = threadIdx.x;
    float v0 = rowv[0][t], v1 = rowv[1][t];
    int i0 = rowi[0][t], i1 = rowi[1][t];
    bool take1 = (v1 < v0) || (v1 == v0 && i1 < i0);
    prow_v[((size_t)p * 16 + blockIdx.x) * TT + bm + t] = take1 ? v1 : v0;
    prow_i[((size_t)p * 16 + blockIdx.x) * TT + bm + t] = take1 ? i1 : i0;
  } else {
    int t = threadIdx.x - 128;
    float v0 = colv[0][t], v1 = colv[1][t];
    int i0 = coli[0][t], i1 = coli[1][t];
    bool take1 = (v1 < v0) || (v1 == v0 && i1 < i0);
    pcol_v[((size_t)p * 16 + blockIdx.y) * TT + bn + t] = take1 ? v1 : v0;
    pcol_i[((size_t)p * 16 + blockIdx.y) * TT + bn + t] = take1 ? i1 : i0;
  }
}

// ---------------- argmin stage 2: fold 16 stripes ----------------
__global__ __launch_bounds__(256) void argmin_reduce_batched(const float* __restrict__ prow_v, const int* __restrict__ prow_i,
                                                             const float* __restrict__ pcol_v, const int* __restrict__ pcol_i,
                                                             int* __restrict__ b_of_a, int* __restrict__ a_of_b) {
  int p = blockIdx.y;
  int t = blockIdx.x * 256 + threadIdx.x;  // 0..2*TT-1
  int isRow = t < TT;
  int x = isRow ? t : t - TT;
  const float* pv = (isRow ? prow_v : pcol_v) + (size_t)p * 16 * TT;
  const int* pi = (isRow ? prow_i : pcol_i) + (size_t)p * 16 * TT;
  float best = INFINITY; int bidx = TT;
  for (int s = 0; s < 16; ++s) {
    float v = pv[(size_t)s * TT + x]; int id = pi[(size_t)s * TT + x];
    if (v < best || (v == best && id < bidx)) { best = v; bidx = id; }
  }
  if (isRow) b_of_a[(size_t)p * TT + x] = bidx;
  else       a_of_b[(size_t)p * TT + x] = bidx;
}

// ---------------- fused dual-mode top-5, batched over 8 slices ----------------
__global__ __launch_bounds__(256) void top5_batched(const float* __restrict__ gram, const float* __restrict__ sqAll,
                                                    const float* __restrict__ invAll, int* __restrict__ out0,
                                                    int* __restrict__ out1) {
  int i = blockIdx.x;
  int s = blockIdx.y;
  const float* G = gram + (size_t)s * TT * TT;
  const float* sq = sqAll + (size_t)s * TT;
  const float* inv = invAll + (size_t)s * TT;
  __shared__ float k0[TT];
  __shared__ float k1[TT];
  __shared__ float wv[4];
  __shared__ int wi[4];
  __shared__ int sel_sh[2][KK];
  int lane = threadIdx.x & 63, w = threadIdx.x >> 6;
#pragma unroll
  for (int t = 0; t < 2; ++t) {
    int j4 = (t * 256 + threadIdx.x) * 4;
    float4 g4 = *(const float4*)&G[(size_t)i * TT + j4];
    float4 s4 = *(const float4*)&sq[j4];
    float4 v4 = *(const float4*)&inv[j4];
    k0[j4 + 0] = s4.x - 2.f * g4.x; k1[j4 + 0] = -g4.x * v4.x;
    k0[j4 + 1] = s4.y - 2.f * g4.y; k1[j4 + 1] = -g4.y * v4.y;
    k0[j4 + 2] = s4.z - 2.f * g4.z; k1[j4 + 2] = -g4.z * v4.z;
    k0[j4 + 3] = s4.w - 2.f * g4.w; k1[j4 + 3] = -g4.w * v4.w;
  }
  __syncthreads();
  if (threadIdx.x == 0) { k0[i] = INFINITY; k1[i] = INFINITY; }
  __syncthreads();
  for (int mode = 0; mode < 2; ++mode) {
    float* ks = mode ? k1 : k0;
    for (int r = 0; r < KK; ++r) {
      float best = INFINITY; int bidx = TT;
      for (int j = threadIdx.x; j < TT; j += 256) {
        float v = ks[j];
        if (v < best) { best = v; bidx = j; }
      }
#pragma unroll
      for (int off = 32; off > 0; off >>= 1) {
        float v2 = __shfl_down(best, off, 64);
        int i2 = __shfl_down(bidx, off, 64);
        if (v2 < best || (v2 == best && i2 < bidx)) { best = v2; bidx = i2; }
      }
      if (lane == 0) { wv[w] = best; wi[w] = bidx; }
      __syncthreads();
      if (threadIdx.x == 0) {
        float b2 = wv[0]; int x2 = wi[0];
#pragma unroll
        for (int q = 1; q < 4; ++q) {
          if (wv[q] < b2 || (wv[q] == b2 && wi[q] < x2)) { b2 = wv[q]; x2 = wi[q]; }
        }
        sel_sh[mode][r] = x2; ks[x2] = INFINITY;
      }
      __syncthreads();
    }
  }
  if (threadIdx.x < KK) {
    out0[((size_t)s * TT + i) * KK + threadIdx.x] = sel_sh[0][threadIdx.x];
    out1[((size_t)s * TT + i) * KK + threadIdx.x] = sel_sh[1][threadIdx.x];
  }
}

// ---------------- mutual matching, batched ----------------
__global__ __launch_bounds__(256) void mutual_batched(const int* __restrict__ b_of_a_all,
                                                      const int* __restrict__ a_of_b_all,
                                                      int* __restrict__ idxB_all, int* __restrict__ matchedB_all,
                                                      int* __restrict__ unmatched_all, int* __restrict__ scalars_all) {
  int p = blockIdx.x;
  const int* b_of_a = b_of_a_all + (size_t)p * TT;
  const int* a_of_b = a_of_b_all + (size_t)p * TT;
  int* idxB_of_A = idxB_all + (size_t)p * TT;
  int* matchedB = matchedB_all + (size_t)p * TT;
  int* unmatched = unmatched_all + (size_t)p * TT;
  __shared__ int cnt_sh;
  for (int j = threadIdx.x; j < TT; j += 256) matchedB[j] = 0;
  __syncthreads();
  for (int i = threadIdx.x; i < TT; i += 256) {
    int b = b_of_a[i];
    bool mut = (a_of_b[b] == i);
    idxB_of_A[i] = mut ? b : -1;
    if (mut) matchedB[b] = 1;
  }
  __syncthreads();
  if (threadIdx.x == 0) cnt_sh = 0;
  __syncthreads();
  for (int j = threadIdx.x; j < TT; j += 256) {
    if (!matchedB[j]) { int q = atomicAdd(&cnt_sh, 1); unmatched[q] = j; }
  }
  __syncthreads();
  if (threadIdx.x == 0) {
    int c = cnt_sh;
    if (c == 0) { unmatched[0] = 0; c = 1; }
    scalars_all[p * 16] = c;
  }
}

// ---------------- crossbrain hinge via self-gram gather: one wave per (i, combo) ----------------
__global__ __launch_bounds__(64) void cb_hinge_gather(const float* __restrict__ gram, const float* __restrict__ invAll,
                                                      const int* __restrict__ neigh1, float* __restrict__ cb_acc) {
  int c = blockIdx.y, i = blockIdx.x;
  int sa = c, sb = (c < 4) ? (c + 4) : (c - 4);
  const float* Grow = gram + (size_t)sb * TT * TT + (size_t)i * TT;  // self-gram of sb, row i
  const float* invB = invAll + (size_t)sb * TT;
  const int* neighA = neigh1 + (size_t)sa * TT * KK;
  unsigned int seed = 0x13579BDFu + 0x9E3779B9u * (unsigned)c;
  int lane = threadIdx.x;

  __shared__ int targets[10];
  __shared__ float svals[10];
  if (lane < KK) targets[lane] = neighA[(size_t)i * KK + lane];
  __syncthreads();
  if (lane == 0) {
    int pos[KK];
    for (int k = 0; k < KK; ++k) pos[k] = targets[k];
    unsigned int ctr = 0;
    for (int k = 0; k < KK; ++k) {
      int cand;
      while (true) {
        unsigned int h = mix_hash(seed ^ (unsigned)i, ctr++);
        cand = (int)(h & (TT - 1));
        bool bad = (cand == i);
        for (int t = 0; t < KK; ++t) bad = bad || (cand == pos[t]);
        for (int t = 0; t < k; ++t) bad = bad || (cand == targets[KK + t]);
        if (!bad) break;
      }
      targets[KK + k] = cand;
    }
  }
  __syncthreads();
  if (lane < 10) {
    int t = targets[lane];
    svals[lane] = Grow[t] * invB[t];  // dot(i,t)*inv[t]
  }
  __syncthreads();
  if (lane == 0) {
    float hsum = 0.f;
    float ii = invB[i];
    const float lo = -1.f + 1e-8f, hi = 1.f - 1e-8f;
    for (int k = 0; k < KK; ++k) {
      float sp = fminf(fmaxf(svals[k] * ii, lo), hi);
      float sn = fminf(fmaxf(svals[KK + k] * ii, lo), hi);
      float h = sn - sp + 0.05f;
      hsum += (h > 0.f) ? h : 0.f;
    }
    atomicAdd(&cb_acc[c], hsum);
  }
}

// ---------------- NRC hinge via self-gram gather: one wave per (i, pair) ----------------
__global__ __launch_bounds__(64) void nrc_hinge_gather(const float* __restrict__ gram, const float* __restrict__ invAll,
                                                       const int* __restrict__ neighC, const int* __restrict__ idxB_all,
                                                       const int* __restrict__ unmatched_all,
                                                       const int* __restrict__ scalars_all,
                                                       PairTab tab, float* __restrict__ nrc_acc) {
  int p = blockIdx.y, i = blockIdx.x;
  int sa = tab.sa[p], sb = tab.sb[p];
  const float* Gs = gram + (size_t)sb * TT * TT;  // self-gram of sb
  const float* invB = invAll + (size_t)sb * TT;
  const int* neighA = neighC + (size_t)sa * TT * KK;
  const int* idxB_of_A = idxB_all + (size_t)p * TT;
  const int* unmatched = unmatched_all + (size_t)p * TT;
  unsigned int seed = 0xC0FFEE11u + 0x9E3779B9u * (unsigned)p;
  float* acc = nrc_acc + p * 2;
  int lane = threadIdx.x;

  __shared__ int targets[10];
  __shared__ int tmask[KK];
  __shared__ float svals[10];
  if (lane < KK) {
    int nb = neighA[(size_t)i * KK + lane];
    int pb = idxB_of_A[nb];
    tmask[lane] = (pb >= 0) ? 1 : 0;
    targets[lane] = (pb >= 0) ? pb : 0;
  } else if (lane < 10) {
    int k = lane - KK;
    unsigned int neg_count = (unsigned int)scalars_all[p * 16];
    unsigned int r = mix_hash(seed ^ 0xA5A5u, (unsigned)(i * KK + k)) & (TT - 1);
    targets[lane] = unmatched[r % neg_count];
  }
  __syncthreads();
  int idx = idxB_of_A[i];
  int u = idx >= 0 ? idx : 0;
  if (lane < 10) {
    int t = targets[lane];
    svals[lane] = Gs[(size_t)u * TT + t] * invB[t];
  }
  __syncthreads();
  if (lane == 0) {
    float hsum = 0.f; int pcnt = 0;
    float iu = invB[u];
    for (int k = 0; k < KK; ++k) {
      if (tmask[k]) {
        float dpos = 1.f - svals[k] * iu;
        float dneg = 1.f - svals[KK + k] * iu;
        float h = dpos - dneg + 0.4f;
        hsum += (h > 0.f) ? h : 0.f;
        pcnt++;
      }
    }
    if (idx >= 0 && pcnt > 0) {
      atomicAdd(&acc[0], hsum / (float)pcnt);
      atomicAdd(&acc[1], 1.0f);
    }
  }
}

// ---------------- final combine ----------------
__global__ void final_kernel(const float* __restrict__ cb_acc, const float* __restrict__ nrc_acc,
                             float* __restrict__ out) {
  float loss2 = 0.f;
  for (int c = 0; c < 8; ++c) loss2 += cb_acc[c] * (1.0f / 10240.0f);
  loss2 *= 0.25f;
  float loss3 = 0.f;
  for (int d = 0; d < 2; ++d) {
    float s = 0.f;
    for (int t = 0; t < 6; ++t) {
      float cnt = nrc_acc[(d * 6 + t) * 2 + 1];
      float sum = nrc_acc[(d * 6 + t) * 2 + 0];
      s += (cnt > 0.f) ? (sum / cnt) : 0.f;
    }
    loss3 += s * (1.f / 6.f);
  }
  out[0] = 10.f * loss2 + 10.f * loss3;
}

// ---------------- host-side numpy RandomState(seed).permutation(12)[:6] ----------------
namespace {
struct MT19937 {
  uint32_t mt[624]; int mti;
  void seed(uint32_t s) {
    mt[0] = s;
    for (int i = 1; i < 624; ++i) mt[i] = 1812433253u * (mt[i - 1] ^ (mt[i - 1] >> 30)) + (uint32_t)i;
    mti = 624;
  }
  uint32_t next() {
    if (mti >= 624) {
      for (int i = 0; i < 624; ++i) {
        uint32_t y = (mt[i] & 0x80000000u) | (mt[(i + 1) % 624] & 0x7fffffffu);
        uint32_t v = y >> 1;
        if (y & 1u) v ^= 0x9908b0dfu;
        mt[i] = mt[(i + 397) % 624] ^ v;
      }
      mti = 0;
    }
    uint32_t y = mt[mti++];
    y ^= y >> 11; y ^= (y << 7) & 0x9d2c5680u; y ^= (y << 15) & 0xefc60000u; y ^= y >> 18;
    return y;
  }
  uint32_t interval(uint32_t mx) {
    uint32_t mask = mx;
    mask |= mask >> 1; mask |= mask >> 2; mask |= mask >> 4; mask |= mask >> 8; mask |= mask >> 16;
    while (true) { uint32_t v = next() & mask; if (v <= mx) return v; }
  }
};
inline void np_perm12_first6(uint32_t seed, int* sel6) {
  int a[12]; for (int i = 0; i < 12; ++i) a[i] = i;
  MT19937 r; r.seed(seed);
  for (int i = 11; i >= 1; --i) { uint32_t j = r.interval((uint32_t)i); int t = a[i]; a[i] = a[j]; a[j] = t; }
  for (int i = 0; i < 6; ++i) sel6[i] = a[i];
}
}  // namespace

extern "C" void kernel_launch(void* const* d_in, const int* in_sizes, int n_in,
                              void* d_out, int out_size, void* d_ws, size_t ws_size,
                              hipStream_t stream) {
  const float* z1 = (const float*)d_in[0];
  const float* z2 = (const float*)d_in[1];
  float* out = (float*)d_out;

  char* base = (char*)d_ws;
  size_t off = 0;
  auto alloc = [&](size_t bytes) -> void* {
    void* p = base + off;
    off = (off + bytes + 255) & ~(size_t)255;
    return p;
  };
  float* gram            = (float*)alloc((size_t)8 * TT * TT * 4);   // 134 MB: 8 self grams, kept alive
  unsigned short* zb     = (unsigned short*)alloc((size_t)8 * TT * CC * 2);  // 25.2 MB
  float* sq              = (float*)alloc((size_t)8 * TT * 4);
  float* inv             = (float*)alloc((size_t)8 * TT * 4);
  int*   neigh1          = (int*)alloc((size_t)8 * TT * KK * 4);
  int*   neighC          = (int*)alloc((size_t)8 * TT * KK * 4);
  float* prow_v          = (float*)alloc((size_t)12 * 16 * TT * 4);
  int*   prow_i          = (int*)alloc((size_t)12 * 16 * TT * 4);
  float* pcol_v          = (float*)alloc((size_t)12 * 16 * TT * 4);
  int*   pcol_i          = (int*)alloc((size_t)12 * 16 * TT * 4);
  int*   b_of_a          = (int*)alloc((size_t)12 * TT * 4);
  int*   a_of_b          = (int*)alloc((size_t)12 * TT * 4);
  int*   idxB            = (int*)alloc((size_t)12 * TT * 4);
  int*   matchedB        = (int*)alloc((size_t)12 * TT * 4);
  int*   unmatched       = (int*)alloc((size_t)12 * TT * 4);
  int*   scalars         = (int*)alloc(12 * 16 * 4);
  float* accs            = (float*)alloc(64 * 4);
  float* cb_acc          = accs;
  float* nrc_acc         = accs + 8;

  hipMemsetAsync(accs, 0, 64 * 4, stream);

  // prep
  tobf16_kernel<<<(8 * TT * CC) / (256 * 8), 256, 0, stream>>>(z1, z2, zb);
  rownorm_kernel<<<8 * TT, 256, 0, stream>>>(z1, z2, sq, inv);

  // self phase
  gram_self_batched<<<dim3(TT / 128, TT / 128, 8), 256, 0, stream>>>(zb, gram);
  top5_batched<<<dim3(TT, 8), 256, 0, stream>>>(gram, sq, inv, neigh1, neighC);

  // crossbrain via self-gram gather
  cb_hinge_gather<<<dim3(TT, 8), 64, 0, stream>>>(gram, inv, neigh1, cb_acc);

  // NRC pair selection
  int sel0[6], sel1[6];
  np_perm12_first6(0u, sel0);
  np_perm12_first6(1u, sel1);
  static const int PP[12] = {0, 0, 0, 1, 1, 1, 2, 2, 2, 3, 3, 3};
  static const int QQ[12] = {1, 2, 3, 0, 2, 3, 0, 1, 3, 0, 1, 2};
  PairTab tab;
  for (int d = 0; d < 2; ++d) {
    const int* sel = (d == 0) ? sel0 : sel1;
    for (int t = 0; t < 6; ++t) {
      int pi_ = PP[sel[t]], qi = QQ[sel[t]];
      int p = d * 6 + t;
      tab.sa[p] = (d == 0) ? pi_ : 4 + pi_;
      tab.sb[p] = (d == 0) ? 4 + qi : qi;
    }
  }

  // cross phase: fused gram+argmin (no cross-gram storage)
  gram_cross_argmin<<<dim3(TT / 128, TT / 128, 12), 256, 0, stream>>>(zb, inv, tab, prow_v, prow_i, pcol_v, pcol_i);
  argmin_reduce_batched<<<dim3(2 * TT / 256, 12), 256, 0, stream>>>(prow_v, prow_i, pcol_v, pcol_i, b_of_a, a_of_b);
  mutual_batched<<<12, 256, 0, stream>>>(b_of_a, a_of_b, idxB, matchedB, unmatched, scalars);
  nrc_hinge_gather<<<dim3(TT, 12), 64, 0, stream>>>(gram, inv, neighC, idxB, unmatched, scalars, tab, nrc_acc);

  final_kernel<<<1, 1, 0, stream>>>(cb_acc, nrc_acc, out);
}

// Round 6
// 507.001 us; speedup vs baseline: 7.7240x; 1.9140x over previous
//
#include <hip/hip_runtime.h>
#include <cstdint>
#include <cstddef>

#define TT 2048
#define CC 768
#define KK 5

typedef __attribute__((ext_vector_type(8))) short short8;
typedef __attribute__((ext_vector_type(4))) float float4v;

struct PairTab { int sa[12]; int sb[12]; };

// ---------------- device RNG hash ----------------
__device__ __forceinline__ unsigned int mix_hash(unsigned int a, unsigned int b) {
  unsigned long long x = (((unsigned long long)a) << 32) | (unsigned long long)b;
  x ^= x >> 33; x *= 0xff51afd7ed558ccdULL;
  x ^= x >> 33; x *= 0xc4ceb9fe1a85ec53ULL;
  x ^= x >> 33;
  return (unsigned int)(x & 0xffffffffu);
}

__device__ __forceinline__ unsigned short f2bf(float x) {  // RNE fp32->bf16
  union { float f; unsigned int u; } v; v.f = x;
  unsigned int r = v.u + 0x7fffu + ((v.u >> 16) & 1u);
  return (unsigned short)(r >> 16);
}

__device__ __forceinline__ void gload_lds16(const void* g, void* l) {
  __builtin_amdgcn_global_load_lds(
      (const __attribute__((address_space(1))) unsigned int*)g,
      (__attribute__((address_space(3))) unsigned int*)l, 16, 0, 0);
}

// ---------------- fp32 -> bf16 convert ----------------
__global__ __launch_bounds__(256) void tobf16_kernel(const float* __restrict__ z1, const float* __restrict__ z2,
                                                     unsigned short* __restrict__ out) {
  size_t i = ((size_t)blockIdx.x * 256 + threadIdx.x) * 8;
  const size_t half = (size_t)4 * TT * CC;
  const float* src = (i < half) ? (z1 + i) : (z2 + (i - half));
  float4 a = ((const float4*)src)[0];
  float4 b = ((const float4*)src)[1];
  short8 o;
  o[0] = (short)f2bf(a.x); o[1] = (short)f2bf(a.y); o[2] = (short)f2bf(a.z); o[3] = (short)f2bf(a.w);
  o[4] = (short)f2bf(b.x); o[5] = (short)f2bf(b.y); o[6] = (short)f2bf(b.z); o[7] = (short)f2bf(b.w);
  *(short8*)(out + i) = o;
}

// ---------------- row norms ----------------
__global__ __launch_bounds__(256) void rownorm_kernel(const float* __restrict__ z1, const float* __restrict__ z2,
                                                      float* __restrict__ sq, float* __restrict__ inv) {
  int r = blockIdx.x;
  const float* p = (r < 4 * TT) ? (z1 + (size_t)r * CC) : (z2 + (size_t)(r - 4 * TT) * CC);
  float s = 0.f;
  for (int k = threadIdx.x; k < CC; k += 256) { float v = p[k]; s += v * v; }
  __shared__ float red[256];
  red[threadIdx.x] = s; __syncthreads();
  for (int off = 128; off > 0; off >>= 1) {
    if (threadIdx.x < off) red[threadIdx.x] += red[threadIdx.x + off];
    __syncthreads();
  }
  if (threadIdx.x == 0) { sq[r] = red[0]; inv[r] = rsqrtf(red[0] + 1e-12f); }
}

// ---------------- self grams (materialized, slots 0..7) ----------------
__global__ __launch_bounds__(256) void gram_self_batched(const unsigned short* __restrict__ zb,
                                                         float* __restrict__ gram) {
  __shared__ unsigned short As[128 * 32];
  __shared__ unsigned short Bs[128 * 32];
  int s = blockIdx.z;
  const unsigned short* A = zb + (size_t)s * TT * CC;
  float* G = gram + (size_t)s * TT * TT;
  const int bm = blockIdx.y * 128, bn = blockIdx.x * 128;
  const int lane = threadIdx.x & 63, waveId = threadIdx.x >> 6;
  const int wm = (waveId >> 1) * 64, wn = (waveId & 1) * 64;
  const int lrow = lane & 15, lquad = lane >> 4;

  float4v acc[4][4];
#pragma unroll
  for (int i = 0; i < 4; ++i)
#pragma unroll
    for (int j = 0; j < 4; ++j) acc[i][j] = (float4v){0.f, 0.f, 0.f, 0.f};

  for (int kk = 0; kk < CC; kk += 32) {
#pragma unroll
    for (int c = 0; c < 2; ++c) {
      int l = c * 256 + threadIdx.x;
      int row = l >> 2, kc = (l & 3) * 8;
      gload_lds16(A + (size_t)(bm + row) * CC + kk + kc, &As[l * 8]);
      gload_lds16(A + (size_t)(bn + row) * CC + kk + kc, &Bs[l * 8]);
    }
    __syncthreads();
    short8 af[4], bfr[4];
#pragma unroll
    for (int i = 0; i < 4; ++i) {
      af[i]  = *(const short8*)&As[(wm + i * 16 + lrow) * 32 + lquad * 8];
      bfr[i] = *(const short8*)&Bs[(wn + i * 16 + lrow) * 32 + lquad * 8];
    }
#pragma unroll
    for (int i = 0; i < 4; ++i)
#pragma unroll
      for (int j = 0; j < 4; ++j)
        acc[i][j] = __builtin_amdgcn_mfma_f32_16x16x32_bf16(af[i], bfr[j], acc[i][j], 0, 0, 0);
    __syncthreads();
  }
#pragma unroll
  for (int i = 0; i < 4; ++i) {
    int row0 = bm + wm + i * 16 + lquad * 4;
#pragma unroll
    for (int j = 0; j < 4; ++j) {
      int col = bn + wn + j * 16 + lrow;
#pragma unroll
      for (int r = 0; r < 4; ++r) G[(size_t)(row0 + r) * TT + col] = acc[i][j][r];
    }
  }
}

// ---------------- cross gram + fused dual argmin partials ----------------
__global__ __launch_bounds__(256) void gram_cross_argmin(const unsigned short* __restrict__ zb,
                                                         const float* __restrict__ invAll, PairTab tab,
                                                         float* __restrict__ prow_v, int* __restrict__ prow_i,
                                                         float* __restrict__ pcol_v, int* __restrict__ pcol_i) {
  __shared__ unsigned short As[128 * 32];
  __shared__ unsigned short Bs[128 * 32];
  __shared__ float sInvA[128], sInvB[128];
  __shared__ float rowv[2][128]; __shared__ int rowi[2][128];
  __shared__ float colv[2][128]; __shared__ int coli[2][128];

  int p = blockIdx.z;
  const unsigned short* A = zb + (size_t)tab.sa[p] * TT * CC;
  const unsigned short* B = zb + (size_t)tab.sb[p] * TT * CC;
  const float* invA = invAll + (size_t)tab.sa[p] * TT;
  const float* invB = invAll + (size_t)tab.sb[p] * TT;
  const int bm = blockIdx.y * 128, bn = blockIdx.x * 128;
  const int lane = threadIdx.x & 63, waveId = threadIdx.x >> 6;
  const int wm = (waveId >> 1) * 64, wn = (waveId & 1) * 64;
  const int lrow = lane & 15, lquad = lane >> 4;

  if (threadIdx.x < 128) sInvA[threadIdx.x] = invA[bm + threadIdx.x];
  else sInvB[threadIdx.x - 128] = invB[bn + threadIdx.x - 128];

  float4v acc[4][4];
#pragma unroll
  for (int i = 0; i < 4; ++i)
#pragma unroll
    for (int j = 0; j < 4; ++j) acc[i][j] = (float4v){0.f, 0.f, 0.f, 0.f};

  for (int kk = 0; kk < CC; kk += 32) {
#pragma unroll
    for (int c = 0; c < 2; ++c) {
      int l = c * 256 + threadIdx.x;
      int row = l >> 2, kc = (l & 3) * 8;
      gload_lds16(A + (size_t)(bm + row) * CC + kk + kc, &As[l * 8]);
      gload_lds16(B + (size_t)(bn + row) * CC + kk + kc, &Bs[l * 8]);
    }
    __syncthreads();
    short8 af[4], bfr[4];
#pragma unroll
    for (int i = 0; i < 4; ++i) {
      af[i]  = *(const short8*)&As[(wm + i * 16 + lrow) * 32 + lquad * 8];
      bfr[i] = *(const short8*)&Bs[(wn + i * 16 + lrow) * 32 + lquad * 8];
    }
#pragma unroll
    for (int i = 0; i < 4; ++i)
#pragma unroll
      for (int j = 0; j < 4; ++j)
        acc[i][j] = __builtin_amdgcn_mfma_f32_16x16x32_bf16(af[i], bfr[j], acc[i][j], 0, 0, 0);
    __syncthreads();
  }

  float rbv[4][4]; int rbi[4][4];
#pragma unroll
  for (int i = 0; i < 4; ++i)
#pragma unroll
    for (int r = 0; r < 4; ++r) { rbv[i][r] = INFINITY; rbi[i][r] = TT; }
#pragma unroll
  for (int i = 0; i < 4; ++i)
#pragma unroll
    for (int j = 0; j < 4; ++j) {
      int col = bn + wn + j * 16 + lrow;
      float ivb = sInvB[wn + j * 16 + lrow];
#pragma unroll
      for (int r = 0; r < 4; ++r) {
        float v = -acc[i][j][r] * ivb;
        if (v < rbv[i][r]) { rbv[i][r] = v; rbi[i][r] = col; }
      }
    }
#pragma unroll
  for (int m = 1; m <= 8; m <<= 1) {
#pragma unroll
    for (int i = 0; i < 4; ++i)
#pragma unroll
      for (int r = 0; r < 4; ++r) {
        float v2 = __shfl_xor(rbv[i][r], m, 64);
        int i2 = __shfl_xor(rbi[i][r], m, 64);
        if (v2 < rbv[i][r] || (v2 == rbv[i][r] && i2 < rbi[i][r])) { rbv[i][r] = v2; rbi[i][r] = i2; }
      }
  }
  if (lrow == 0) {
#pragma unroll
    for (int i = 0; i < 4; ++i)
#pragma unroll
      for (int r = 0; r < 4; ++r) {
        int lr = wm + i * 16 + lquad * 4 + r;
        rowv[wn >> 6][lr] = rbv[i][r]; rowi[wn >> 6][lr] = rbi[i][r];
      }
  }

  float cbv[4]; int cbi[4];
#pragma unroll
  for (int j = 0; j < 4; ++j) { cbv[j] = INFINITY; cbi[j] = TT; }
#pragma unroll
  for (int j = 0; j < 4; ++j)
#pragma unroll
    for (int i = 0; i < 4; ++i)
#pragma unroll
      for (int r = 0; r < 4; ++r) {
        int lr = wm + i * 16 + lquad * 4 + r;
        float v = -acc[i][j][r] * sInvA[lr];
        if (v < cbv[j]) { cbv[j] = v; cbi[j] = bm + lr; }
      }
#pragma unroll
  for (int m = 16; m <= 32; m <<= 1) {
#pragma unroll
    for (int j = 0; j < 4; ++j) {
      float v2 = __shfl_xor(cbv[j], m, 64);
      int i2 = __shfl_xor(cbi[j], m, 64);
      if (v2 < cbv[j] || (v2 == cbv[j] && i2 < cbi[j])) { cbv[j] = v2; cbi[j] = i2; }
    }
  }
  if (lquad == 0) {
#pragma unroll
    for (int j = 0; j < 4; ++j) {
      int lc = wn + j * 16 + lrow;
      colv[wm >> 6][lc] = cbv[j]; coli[wm >> 6][lc] = cbi[j];
    }
  }
  __syncthreads();

  if (threadIdx.x < 128) {
    int t = threadIdx.x;
    float v0 = rowv[0][t], v1 = rowv[1][t];
    int i0 = rowi[0][t], i1 = rowi[1][t];
    bool take1 = (v1 < v0) || (v1 == v0 && i1 < i0);
    prow_v[((size_t)p * 16 + blockIdx.x) * TT + bm + t] = take1 ? v1 : v0;
    prow_i[((size_t)p * 16 + blockIdx.x) * TT + bm + t] = take1 ? i1 : i0;
  } else {
    int t = threadIdx.x - 128;
    float v0 = colv[0][t], v1 = colv[1][t];
    int i0 = coli[0][t], i1 = coli[1][t];
    bool take1 = (v1 < v0) || (v1 == v0 && i1 < i0);
    pcol_v[((size_t)p * 16 + blockIdx.y) * TT + bn + t] = take1 ? v1 : v0;
    pcol_i[((size_t)p * 16 + blockIdx.y) * TT + bn + t] = take1 ? i1 : i0;
  }
}

// ---------------- argmin stage 2 ----------------
__global__ __launch_bounds__(256) void argmin_reduce_batched(const float* __restrict__ prow_v, const int* __restrict__ prow_i,
                                                             const float* __restrict__ pcol_v, const int* __restrict__ pcol_i,
                                                             int* __restrict__ b_of_a, int* __restrict__ a_of_b) {
  int p = blockIdx.y;
  int t = blockIdx.x * 256 + threadIdx.x;
  int isRow = t < TT;
  int x = isRow ? t : t - TT;
  const float* pv = (isRow ? prow_v : pcol_v) + (size_t)p * 16 * TT;
  const int* pi = (isRow ? prow_i : pcol_i) + (size_t)p * 16 * TT;
  float best = INFINITY; int bidx = TT;
  for (int s = 0; s < 16; ++s) {
    float v = pv[(size_t)s * TT + x]; int id = pi[(size_t)s * TT + x];
    if (v < best || (v == best && id < bidx)) { best = v; bidx = id; }
  }
  if (isRow) b_of_a[(size_t)p * TT + x] = bidx;
  else       a_of_b[(size_t)p * TT + x] = bidx;
}

// ---------------- fused dual-mode top-5, batched ----------------
__global__ __launch_bounds__(256) void top5_batched(const float* __restrict__ gram, const float* __restrict__ sqAll,
                                                    const float* __restrict__ invAll, int* __restrict__ out0,
                                                    int* __restrict__ out1) {
  int i = blockIdx.x;
  int s = blockIdx.y;
  const float* G = gram + (size_t)s * TT * TT;
  const float* sq = sqAll + (size_t)s * TT;
  const float* inv = invAll + (size_t)s * TT;
  __shared__ float k0[TT];
  __shared__ float k1[TT];
  __shared__ float wv[4];
  __shared__ int wi[4];
  __shared__ int sel_sh[2][KK];
  int lane = threadIdx.x & 63, w = threadIdx.x >> 6;
#pragma unroll
  for (int t = 0; t < 2; ++t) {
    int j4 = (t * 256 + threadIdx.x) * 4;
    float4 g4 = *(const float4*)&G[(size_t)i * TT + j4];
    float4 s4 = *(const float4*)&sq[j4];
    float4 v4 = *(const float4*)&inv[j4];
    k0[j4 + 0] = s4.x - 2.f * g4.x; k1[j4 + 0] = -g4.x * v4.x;
    k0[j4 + 1] = s4.y - 2.f * g4.y; k1[j4 + 1] = -g4.y * v4.y;
    k0[j4 + 2] = s4.z - 2.f * g4.z; k1[j4 + 2] = -g4.z * v4.z;
    k0[j4 + 3] = s4.w - 2.f * g4.w; k1[j4 + 3] = -g4.w * v4.w;
  }
  __syncthreads();
  if (threadIdx.x == 0) { k0[i] = INFINITY; k1[i] = INFINITY; }
  __syncthreads();
  for (int mode = 0; mode < 2; ++mode) {
    float* ks = mode ? k1 : k0;
    for (int r = 0; r < KK; ++r) {
      float best = INFINITY; int bidx = TT;
      for (int j = threadIdx.x; j < TT; j += 256) {
        float v = ks[j];
        if (v < best) { best = v; bidx = j; }
      }
#pragma unroll
      for (int off = 32; off > 0; off >>= 1) {
        float v2 = __shfl_down(best, off, 64);
        int i2 = __shfl_down(bidx, off, 64);
        if (v2 < best || (v2 == best && i2 < bidx)) { best = v2; bidx = i2; }
      }
      if (lane == 0) { wv[w] = best; wi[w] = bidx; }
      __syncthreads();
      if (threadIdx.x == 0) {
        float b2 = wv[0]; int x2 = wi[0];
#pragma unroll
        for (int q = 1; q < 4; ++q) {
          if (wv[q] < b2 || (wv[q] == b2 && wi[q] < x2)) { b2 = wv[q]; x2 = wi[q]; }
        }
        sel_sh[mode][r] = x2; ks[x2] = INFINITY;
      }
      __syncthreads();
    }
  }
  if (threadIdx.x < KK) {
    out0[((size_t)s * TT + i) * KK + threadIdx.x] = sel_sh[0][threadIdx.x];
    out1[((size_t)s * TT + i) * KK + threadIdx.x] = sel_sh[1][threadIdx.x];
  }
}

// ---------------- mutual matching, batched ----------------
__global__ __launch_bounds__(256) void mutual_batched(const int* __restrict__ b_of_a_all,
                                                      const int* __restrict__ a_of_b_all,
                                                      int* __restrict__ idxB_all, int* __restrict__ matchedB_all,
                                                      int* __restrict__ unmatched_all, int* __restrict__ scalars_all) {
  int p = blockIdx.x;
  const int* b_of_a = b_of_a_all + (size_t)p * TT;
  const int* a_of_b = a_of_b_all + (size_t)p * TT;
  int* idxB_of_A = idxB_all + (size_t)p * TT;
  int* matchedB = matchedB_all + (size_t)p * TT;
  int* unmatched = unmatched_all + (size_t)p * TT;
  __shared__ int cnt_sh;
  for (int j = threadIdx.x; j < TT; j += 256) matchedB[j] = 0;
  __syncthreads();
  for (int i = threadIdx.x; i < TT; i += 256) {
    int b = b_of_a[i];
    bool mut = (a_of_b[b] == i);
    idxB_of_A[i] = mut ? b : -1;
    if (mut) matchedB[b] = 1;
  }
  __syncthreads();
  if (threadIdx.x == 0) cnt_sh = 0;
  __syncthreads();
  for (int j = threadIdx.x; j < TT; j += 256) {
    if (!matchedB[j]) { int q = atomicAdd(&cnt_sh, 1); unmatched[q] = j; }
  }
  __syncthreads();
  if (threadIdx.x == 0) {
    int c = cnt_sh;
    if (c == 0) { unmatched[0] = 0; c = 1; }
    scalars_all[p * 16] = c;
  }
}

// ---------------- crossbrain hinge: 64 rows/block, 1 atomic/block ----------------
__global__ __launch_bounds__(256) void cb_hinge_block(const float* __restrict__ gram, const float* __restrict__ invAll,
                                                      const int* __restrict__ neigh1, float* __restrict__ cb_acc) {
  int c = blockIdx.y;
  int i0 = blockIdx.x * 64;
  int sa = c, sb = (c < 4) ? (c + 4) : (c - 4);
  const float* Gs = gram + (size_t)sb * TT * TT;
  const float* invB = invAll + (size_t)sb * TT;
  const int* neighA = neigh1 + (size_t)sa * TT * KK;
  unsigned int seed = 0x13579BDFu + 0x9E3779B9u * (unsigned)c;
  int tid = threadIdx.x;

  __shared__ int targ[64][10];
  __shared__ float sval[64][10];
  // load positives (coalesced)
  for (int t = tid; t < 64 * KK; t += 256) targ[t / KK][t % KK] = neighA[(size_t)i0 * KK + t];
  __syncthreads();
  // per-row rejection sampling for negatives (wave 0, one lane per row)
  if (tid < 64) {
    int i = i0 + tid;
    int pos[KK];
#pragma unroll
    for (int k = 0; k < KK; ++k) pos[k] = targ[tid][k];
    unsigned int ctr = 0;
    for (int k = 0; k < KK; ++k) {
      int cand;
      while (true) {
        unsigned int h = mix_hash(seed ^ (unsigned)i, ctr++);
        cand = (int)(h & (TT - 1));
        bool bad = (cand == i);
        for (int t = 0; t < KK; ++t) bad = bad || (cand == pos[t]);
        for (int t = 0; t < k; ++t) bad = bad || (cand == targ[tid][KK + t]);
        if (!bad) break;
      }
      targ[tid][KK + k] = cand;
    }
  }
  __syncthreads();
  // gather 640 values with all 256 threads
  for (int t = tid; t < 640; t += 256) {
    int il = t / 10, k = t % 10;
    int tt = targ[il][k];
    sval[il][k] = Gs[(size_t)(i0 + il) * TT + tt] * invB[tt];
  }
  __syncthreads();
  // finalize in wave 0, one lane per row; wave-reduce; single atomic
  if (tid < 64) {
    int i = i0 + tid;
    float ii = invB[i];
    const float lo = -1.f + 1e-8f, hi = 1.f - 1e-8f;
    float hsum = 0.f;
#pragma unroll
    for (int k = 0; k < KK; ++k) {
      float sp = fminf(fmaxf(sval[tid][k] * ii, lo), hi);
      float sn = fminf(fmaxf(sval[tid][KK + k] * ii, lo), hi);
      float h = sn - sp + 0.05f;
      hsum += (h > 0.f) ? h : 0.f;
    }
#pragma unroll
    for (int off = 32; off > 0; off >>= 1) hsum += __shfl_down(hsum, off, 64);
    if (tid == 0) atomicAdd(&cb_acc[c], hsum);
  }
}

// ---------------- NRC hinge: 64 rows/block, 2 atomics/block ----------------
__global__ __launch_bounds__(256) void nrc_hinge_block(const float* __restrict__ gram, const float* __restrict__ invAll,
                                                       const int* __restrict__ neighC, const int* __restrict__ idxB_all,
                                                       const int* __restrict__ unmatched_all,
                                                       const int* __restrict__ scalars_all,
                                                       PairTab tab, float* __restrict__ nrc_acc) {
  int p = blockIdx.y;
  int i0 = blockIdx.x * 64;
  int sa = tab.sa[p], sb = tab.sb[p];
  const float* Gs = gram + (size_t)sb * TT * TT;
  const float* invB = invAll + (size_t)sb * TT;
  const int* neighA = neighC + (size_t)sa * TT * KK;
  const int* idxB_of_A = idxB_all + (size_t)p * TT;
  const int* unmatched = unmatched_all + (size_t)p * TT;
  unsigned int seed = 0xC0FFEE11u + 0x9E3779B9u * (unsigned)p;
  float* acc = nrc_acc + p * 2;
  int tid = threadIdx.x;

  __shared__ int targ[64][10];
  __shared__ float sval[64][10];
  __shared__ unsigned int tmask[64];
  __shared__ int su[64];
  if (tid < 64) { tmask[tid] = 0; su[tid] = idxB_of_A[i0 + tid]; }
  __syncthreads();
  unsigned int neg_count = (unsigned int)scalars_all[p * 16];
  // positives: pb = idxB_of_A[neigh]
  for (int t = tid; t < 64 * KK; t += 256) {
    int il = t / KK, k = t % KK;
    int nb = neighA[(size_t)i0 * KK + t];
    int pb = idxB_of_A[nb];
    targ[il][k] = (pb >= 0) ? pb : 0;
    if (pb >= 0) atomicOr(&tmask[il], 1u << k);
  }
  // negatives: direct hash (no dependency)
  for (int t = tid; t < 64 * KK; t += 256) {
    int il = t / KK, k = t % KK;
    int i = i0 + il;
    unsigned int r = mix_hash(seed ^ 0xA5A5u, (unsigned)(i * KK + k)) & (TT - 1);
    targ[il][KK + k] = unmatched[r % neg_count];
  }
  __syncthreads();
  // gather
  for (int t = tid; t < 640; t += 256) {
    int il = t / 10, k = t % 10;
    int u = su[il] >= 0 ? su[il] : 0;
    int tt = targ[il][k];
    sval[il][k] = Gs[(size_t)u * TT + tt] * invB[tt];
  }
  __syncthreads();
  // finalize in wave 0
  if (tid < 64) {
    int idx = su[tid];
    int u = idx >= 0 ? idx : 0;
    float iu = invB[u];
    unsigned int tm = tmask[tid];
    float hsum = 0.f; int pcnt = 0;
#pragma unroll
    for (int k = 0; k < KK; ++k) {
      if (tm & (1u << k)) {
        float dpos = 1.f - sval[tid][k] * iu;
        float dneg = 1.f - sval[tid][KK + k] * iu;
        float h = dpos - dneg + 0.4f;
        hsum += (h > 0.f) ? h : 0.f;
        pcnt++;
      }
    }
    float hs = 0.f, vc = 0.f;
    if (idx >= 0 && pcnt > 0) { hs = hsum / (float)pcnt; vc = 1.0f; }
#pragma unroll
    for (int off = 32; off > 0; off >>= 1) {
      hs += __shfl_down(hs, off, 64);
      vc += __shfl_down(vc, off, 64);
    }
    if (tid == 0) {
      atomicAdd(&acc[0], hs);
      atomicAdd(&acc[1], vc);
    }
  }
}

// ---------------- final combine ----------------
__global__ void final_kernel(const float* __restrict__ cb_acc, const float* __restrict__ nrc_acc,
                             float* __restrict__ out) {
  float loss2 = 0.f;
  for (int c = 0; c < 8; ++c) loss2 += cb_acc[c] * (1.0f / 10240.0f);
  loss2 *= 0.25f;
  float loss3 = 0.f;
  for (int d = 0; d < 2; ++d) {
    float s = 0.f;
    for (int t = 0; t < 6; ++t) {
      float cnt = nrc_acc[(d * 6 + t) * 2 + 1];
      float sum = nrc_acc[(d * 6 + t) * 2 + 0];
      s += (cnt > 0.f) ? (sum / cnt) : 0.f;
    }
    loss3 += s * (1.f / 6.f);
  }
  out[0] = 10.f * loss2 + 10.f * loss3;
}

// ---------------- host-side numpy RandomState(seed).permutation(12)[:6] ----------------
namespace {
struct MT19937 {
  uint32_t mt[624]; int mti;
  void seed(uint32_t s) {
    mt[0] = s;
    for (int i = 1; i < 624; ++i) mt[i] = 1812433253u * (mt[i - 1] ^ (mt[i - 1] >> 30)) + (uint32_t)i;
    mti = 624;
  }
  uint32_t next() {
    if (mti >= 624) {
      for (int i = 0; i < 624; ++i) {
        uint32_t y = (mt[i] & 0x80000000u) | (mt[(i + 1) % 624] & 0x7fffffffu);
        uint32_t v = y >> 1;
        if (y & 1u) v ^= 0x9908b0dfu;
        mt[i] = mt[(i + 397) % 624] ^ v;
      }
      mti = 0;
    }
    uint32_t y = mt[mti++];
    y ^= y >> 11; y ^= (y << 7) & 0x9d2c5680u; y ^= (y << 15) & 0xefc60000u; y ^= y >> 18;
    return y;
  }
  uint32_t interval(uint32_t mx) {
    uint32_t mask = mx;
    mask |= mask >> 1; mask |= mask >> 2; mask |= mask >> 4; mask |= mask >> 8; mask |= mask >> 16;
    while (true) { uint32_t v = next() & mask; if (v <= mx) return v; }
  }
};
inline void np_perm12_first6(uint32_t seed, int* sel6) {
  int a[12]; for (int i = 0; i < 12; ++i) a[i] = i;
  MT19937 r; r.seed(seed);
  for (int i = 11; i >= 1; --i) { uint32_t j = r.interval((uint32_t)i); int t = a[i]; a[i] = a[j]; a[j] = t; }
  for (int i = 0; i < 6; ++i) sel6[i] = a[i];
}
}  // namespace

extern "C" void kernel_launch(void* const* d_in, const int* in_sizes, int n_in,
                              void* d_out, int out_size, void* d_ws, size_t ws_size,
                              hipStream_t stream) {
  const float* z1 = (const float*)d_in[0];
  const float* z2 = (const float*)d_in[1];
  float* out = (float*)d_out;

  char* base = (char*)d_ws;
  size_t off = 0;
  auto alloc = [&](size_t bytes) -> void* {
    void* p = base + off;
    off = (off + bytes + 255) & ~(size_t)255;
    return p;
  };
  float* gram            = (float*)alloc((size_t)8 * TT * TT * 4);   // 134 MB: 8 self grams, kept alive
  unsigned short* zb     = (unsigned short*)alloc((size_t)8 * TT * CC * 2);
  float* sq              = (float*)alloc((size_t)8 * TT * 4);
  float* inv             = (float*)alloc((size_t)8 * TT * 4);
  int*   neigh1          = (int*)alloc((size_t)8 * TT * KK * 4);
  int*   neighC          = (int*)alloc((size_t)8 * TT * KK * 4);
  float* prow_v          = (float*)alloc((size_t)12 * 16 * TT * 4);
  int*   prow_i          = (int*)alloc((size_t)12 * 16 * TT * 4);
  float* pcol_v          = (float*)alloc((size_t)12 * 16 * TT * 4);
  int*   pcol_i          = (int*)alloc((size_t)12 * 16 * TT * 4);
  int*   b_of_a          = (int*)alloc((size_t)12 * TT * 4);
  int*   a_of_b          = (int*)alloc((size_t)12 * TT * 4);
  int*   idxB            = (int*)alloc((size_t)12 * TT * 4);
  int*   matchedB        = (int*)alloc((size_t)12 * TT * 4);
  int*   unmatched       = (int*)alloc((size_t)12 * TT * 4);
  int*   scalars         = (int*)alloc(12 * 16 * 4);
  float* accs            = (float*)alloc(64 * 4);
  float* cb_acc          = accs;
  float* nrc_acc         = accs + 8;

  hipMemsetAsync(accs, 0, 64 * 4, stream);

  // prep
  tobf16_kernel<<<(8 * TT * CC) / (256 * 8), 256, 0, stream>>>(z1, z2, zb);
  rownorm_kernel<<<8 * TT, 256, 0, stream>>>(z1, z2, sq, inv);

  // self phase
  gram_self_batched<<<dim3(TT / 128, TT / 128, 8), 256, 0, stream>>>(zb, gram);
  top5_batched<<<dim3(TT, 8), 256, 0, stream>>>(gram, sq, inv, neigh1, neighC);

  // crossbrain (block-aggregated atomics)
  cb_hinge_block<<<dim3(TT / 64, 8), 256, 0, stream>>>(gram, inv, neigh1, cb_acc);

  // NRC pair selection
  int sel0[6], sel1[6];
  np_perm12_first6(0u, sel0);
  np_perm12_first6(1u, sel1);
  static const int PP[12] = {0, 0, 0, 1, 1, 1, 2, 2, 2, 3, 3, 3};
  static const int QQ[12] = {1, 2, 3, 0, 2, 3, 0, 1, 3, 0, 1, 2};
  PairTab tab;
  for (int d = 0; d < 2; ++d) {
    const int* sel = (d == 0) ? sel0 : sel1;
    for (int t = 0; t < 6; ++t) {
      int pi_ = PP[sel[t]], qi = QQ[sel[t]];
      int p = d * 6 + t;
      tab.sa[p] = (d == 0) ? pi_ : 4 + pi_;
      tab.sb[p] = (d == 0) ? 4 + qi : qi;
    }
  }

  // cross phase
  gram_cross_argmin<<<dim3(TT / 128, TT / 128, 12), 256, 0, stream>>>(zb, inv, tab, prow_v, prow_i, pcol_v, pcol_i);
  argmin_reduce_batched<<<dim3(2 * TT / 256, 12), 256, 0, stream>>>(prow_v, prow_i, pcol_v, pcol_i, b_of_a, a_of_b);
  mutual_batched<<<12, 256, 0, stream>>>(b_of_a, a_of_b, idxB, matchedB, unmatched, scalars);
  nrc_hinge_block<<<dim3(TT / 64, 12), 256, 0, stream>>>(gram, inv, neighC, idxB, unmatched, scalars, tab, nrc_acc);

  final_kernel<<<1, 1, 0, stream>>>(cb_acc, nrc_acc, out);
}

// Round 7
// 488.079 us; speedup vs baseline: 8.0235x; 1.0388x over previous
//
#include <hip/hip_runtime.h>
#include <cstdint>
#include <cstddef>

#define TT 2048
#define CC 768
#define KK 5

typedef __attribute__((ext_vector_type(8))) short short8;
typedef __attribute__((ext_vector_type(4))) float float4v;

struct PairTab { int sa[12]; int sb[12]; };

#define N_SELF_BLK (8 * 136)   // 8 slices x 136 upper-triangle 128x128 tiles
#define N_CROSS_BLK (12 * 256) // 12 pairs x 16x16 tiles

// ---------------- device RNG hash ----------------
__device__ __forceinline__ unsigned int mix_hash(unsigned int a, unsigned int b) {
  unsigned long long x = (((unsigned long long)a) << 32) | (unsigned long long)b;
  x ^= x >> 33; x *= 0xff51afd7ed558ccdULL;
  x ^= x >> 33; x *= 0xc4ceb9fe1a85ec53ULL;
  x ^= x >> 33;
  return (unsigned int)(x & 0xffffffffu);
}

__device__ __forceinline__ unsigned short f2bf(float x) {  // RNE fp32->bf16
  union { float f; unsigned int u; } v; v.f = x;
  unsigned int r = v.u + 0x7fffu + ((v.u >> 16) & 1u);
  return (unsigned short)(r >> 16);
}

__device__ __forceinline__ void gload_lds16(const void* g, void* l) {
  __builtin_amdgcn_global_load_lds(
      (const __attribute__((address_space(1))) unsigned int*)g,
      (__attribute__((address_space(3))) unsigned int*)l, 16, 0, 0);
}

// ---------------- fused prep: fp32->bf16 + row sumsq/inv-norm ----------------
__global__ __launch_bounds__(256) void prep_kernel(const float* __restrict__ z1, const float* __restrict__ z2,
                                                   unsigned short* __restrict__ zb, float* __restrict__ sq,
                                                   float* __restrict__ inv) {
  int r = blockIdx.x;  // 0..16383
  const float* p = (r < 4 * TT) ? (z1 + (size_t)r * CC) : (z2 + (size_t)(r - 4 * TT) * CC);
  unsigned short* o = zb + (size_t)r * CC;
  float ss = 0.f;
  if (threadIdx.x < 192) {  // 192 float4 = 768 floats
    float4 v = ((const float4*)p)[threadIdx.x];
    ss = v.x * v.x + v.y * v.y + v.z * v.z + v.w * v.w;
    ushort4 u;
    u.x = f2bf(v.x); u.y = f2bf(v.y); u.z = f2bf(v.z); u.w = f2bf(v.w);
    ((ushort4*)o)[threadIdx.x] = u;
  }
  __shared__ float red[256];
  red[threadIdx.x] = ss; __syncthreads();
  for (int off = 128; off > 0; off >>= 1) {
    if (threadIdx.x < off) red[threadIdx.x] += red[threadIdx.x + off];
    __syncthreads();
  }
  if (threadIdx.x == 0) { sq[r] = red[0]; inv[r] = rsqrtf(red[0] + 1e-12f); }
}

// ---------------- unified gram kernel: self-triangle tiles + cross tiles with fused argmin ----------------
__global__ __launch_bounds__(256) void gram_all(const unsigned short* __restrict__ zb, float* __restrict__ gram,
                                                const float* __restrict__ invAll, PairTab tab,
                                                float* __restrict__ prow_v, int* __restrict__ prow_i,
                                                float* __restrict__ pcol_v, int* __restrict__ pcol_i) {
  __shared__ unsigned short As[128 * 32];
  __shared__ unsigned short Bs[128 * 32];
  __shared__ float sInvA[128], sInvB[128];
  __shared__ float rowv[2][128]; __shared__ int rowi[2][128];
  __shared__ float colv[2][128]; __shared__ int coli[2][128];

  const int bid = blockIdx.x;
  const bool isSelf = bid < N_SELF_BLK;
  int bm, bn, p = 0, s = 0;
  const unsigned short *A, *B;
  if (isSelf) {
    s = bid / 136;
    int t = bid % 136;
    int ti = 0;
    while (t >= 16 - ti) { t -= 16 - ti; ++ti; }
    int tj = ti + t;           // ti <= tj
    bm = ti * 128; bn = tj * 128;
    A = zb + (size_t)s * TT * CC;
    B = A;
  } else {
    int cb = bid - N_SELF_BLK;
    p = cb >> 8;
    int tile = cb & 255;
    bn = (tile & 15) * 128;   // col tile (bj)
    bm = (tile >> 4) * 128;   // row tile (bi)
    A = zb + (size_t)tab.sa[p] * TT * CC;
    B = zb + (size_t)tab.sb[p] * TT * CC;
    const float* invA = invAll + (size_t)tab.sa[p] * TT;
    const float* invB = invAll + (size_t)tab.sb[p] * TT;
    if (threadIdx.x < 128) sInvA[threadIdx.x] = invA[bm + threadIdx.x];
    else sInvB[threadIdx.x - 128] = invB[bn + threadIdx.x - 128];
  }
  const int lane = threadIdx.x & 63, waveId = threadIdx.x >> 6;
  const int wm = (waveId >> 1) * 64, wn = (waveId & 1) * 64;
  const int lrow = lane & 15, lquad = lane >> 4;

  float4v acc[4][4];
#pragma unroll
  for (int i = 0; i < 4; ++i)
#pragma unroll
    for (int j = 0; j < 4; ++j) acc[i][j] = (float4v){0.f, 0.f, 0.f, 0.f};

  for (int kk = 0; kk < CC; kk += 32) {
#pragma unroll
    for (int c = 0; c < 2; ++c) {
      int l = c * 256 + threadIdx.x;
      int row = l >> 2, kc = (l & 3) * 8;
      gload_lds16(A + (size_t)(bm + row) * CC + kk + kc, &As[l * 8]);
      gload_lds16(B + (size_t)(bn + row) * CC + kk + kc, &Bs[l * 8]);
    }
    __syncthreads();
    short8 af[4], bfr[4];
#pragma unroll
    for (int i = 0; i < 4; ++i) {
      af[i]  = *(const short8*)&As[(wm + i * 16 + lrow) * 32 + lquad * 8];
      bfr[i] = *(const short8*)&Bs[(wn + i * 16 + lrow) * 32 + lquad * 8];
    }
#pragma unroll
    for (int i = 0; i < 4; ++i)
#pragma unroll
      for (int j = 0; j < 4; ++j)
        acc[i][j] = __builtin_amdgcn_mfma_f32_16x16x32_bf16(af[i], bfr[j], acc[i][j], 0, 0, 0);
    __syncthreads();
  }

  if (isSelf) {
    // direct + mirrored stores (dot(ai,aj) == dot(aj,ai) bit-exactly)
    float* G = gram + (size_t)s * TT * TT;
    bool offdiag = (bm != bn);
#pragma unroll
    for (int i = 0; i < 4; ++i) {
      int row0 = bm + wm + i * 16 + lquad * 4;
#pragma unroll
      for (int j = 0; j < 4; ++j) {
        int col = bn + wn + j * 16 + lrow;
#pragma unroll
        for (int r = 0; r < 4; ++r) {
          G[(size_t)(row0 + r) * TT + col] = acc[i][j][r];
          if (offdiag) G[(size_t)col * TT + (row0 + r)] = acc[i][j][r];
        }
      }
    }
    return;
  }

  // ---- cross: fused dual argmin partials ----
  float rbv[4][4]; int rbi[4][4];
#pragma unroll
  for (int i = 0; i < 4; ++i)
#pragma unroll
    for (int r = 0; r < 4; ++r) { rbv[i][r] = INFINITY; rbi[i][r] = TT; }
#pragma unroll
  for (int i = 0; i < 4; ++i)
#pragma unroll
    for (int j = 0; j < 4; ++j) {
      int col = bn + wn + j * 16 + lrow;
      float ivb = sInvB[wn + j * 16 + lrow];
#pragma unroll
      for (int r = 0; r < 4; ++r) {
        float v = -acc[i][j][r] * ivb;
        if (v < rbv[i][r]) { rbv[i][r] = v; rbi[i][r] = col; }
      }
    }
#pragma unroll
  for (int m = 1; m <= 8; m <<= 1) {
#pragma unroll
    for (int i = 0; i < 4; ++i)
#pragma unroll
      for (int r = 0; r < 4; ++r) {
        float v2 = __shfl_xor(rbv[i][r], m, 64);
        int i2 = __shfl_xor(rbi[i][r], m, 64);
        if (v2 < rbv[i][r] || (v2 == rbv[i][r] && i2 < rbi[i][r])) { rbv[i][r] = v2; rbi[i][r] = i2; }
      }
  }
  if (lrow == 0) {
#pragma unroll
    for (int i = 0; i < 4; ++i)
#pragma unroll
      for (int r = 0; r < 4; ++r) {
        int lr = wm + i * 16 + lquad * 4 + r;
        rowv[wn >> 6][lr] = rbv[i][r]; rowi[wn >> 6][lr] = rbi[i][r];
      }
  }

  float cbv[4]; int cbi[4];
#pragma unroll
  for (int j = 0; j < 4; ++j) { cbv[j] = INFINITY; cbi[j] = TT; }
#pragma unroll
  for (int j = 0; j < 4; ++j)
#pragma unroll
    for (int i = 0; i < 4; ++i)
#pragma unroll
      for (int r = 0; r < 4; ++r) {
        int lr = wm + i * 16 + lquad * 4 + r;
        float v = -acc[i][j][r] * sInvA[lr];
        if (v < cbv[j]) { cbv[j] = v; cbi[j] = bm + lr; }
      }
#pragma unroll
  for (int m = 16; m <= 32; m <<= 1) {
#pragma unroll
    for (int j = 0; j < 4; ++j) {
      float v2 = __shfl_xor(cbv[j], m, 64);
      int i2 = __shfl_xor(cbi[j], m, 64);
      if (v2 < cbv[j] || (v2 == cbv[j] && i2 < cbi[j])) { cbv[j] = v2; cbi[j] = i2; }
    }
  }
  if (lquad == 0) {
#pragma unroll
    for (int j = 0; j < 4; ++j) {
      int lc = wn + j * 16 + lrow;
      colv[wm >> 6][lc] = cbv[j]; coli[wm >> 6][lc] = cbi[j];
    }
  }
  __syncthreads();

  int bj = bn >> 7, bi = bm >> 7;
  if (threadIdx.x < 128) {
    int t = threadIdx.x;
    float v0 = rowv[0][t], v1 = rowv[1][t];
    int i0 = rowi[0][t], i1 = rowi[1][t];
    bool take1 = (v1 < v0) || (v1 == v0 && i1 < i0);
    prow_v[((size_t)p * 16 + bj) * TT + bm + t] = take1 ? v1 : v0;
    prow_i[((size_t)p * 16 + bj) * TT + bm + t] = take1 ? i1 : i0;
  } else {
    int t = threadIdx.x - 128;
    float v0 = colv[0][t], v1 = colv[1][t];
    int i0 = coli[0][t], i1 = coli[1][t];
    bool take1 = (v1 < v0) || (v1 == v0 && i1 < i0);
    pcol_v[((size_t)p * 16 + bi) * TT + bn + t] = take1 ? v1 : v0;
    pcol_i[((size_t)p * 16 + bi) * TT + bn + t] = take1 ? i1 : i0;
  }
}

// ---------------- argmin stage 2 ----------------
__global__ __launch_bounds__(256) void argmin_reduce_batched(const float* __restrict__ prow_v, const int* __restrict__ prow_i,
                                                             const float* __restrict__ pcol_v, const int* __restrict__ pcol_i,
                                                             int* __restrict__ b_of_a, int* __restrict__ a_of_b) {
  int p = blockIdx.y;
  int t = blockIdx.x * 256 + threadIdx.x;
  int isRow = t < TT;
  int x = isRow ? t : t - TT;
  const float* pv = (isRow ? prow_v : pcol_v) + (size_t)p * 16 * TT;
  const int* pi = (isRow ? prow_i : pcol_i) + (size_t)p * 16 * TT;
  float best = INFINITY; int bidx = TT;
  for (int s = 0; s < 16; ++s) {
    float v = pv[(size_t)s * TT + x]; int id = pi[(size_t)s * TT + x];
    if (v < best || (v == best && id < bidx)) { best = v; bidx = id; }
  }
  if (isRow) b_of_a[(size_t)p * TT + x] = bidx;
  else       a_of_b[(size_t)p * TT + x] = bidx;
}

// ---------------- fused dual-mode top-5, batched ----------------
__global__ __launch_bounds__(256) void top5_batched(const float* __restrict__ gram, const float* __restrict__ sqAll,
                                                    const float* __restrict__ invAll, int* __restrict__ out0,
                                                    int* __restrict__ out1) {
  int i = blockIdx.x;
  int s = blockIdx.y;
  const float* G = gram + (size_t)s * TT * TT;
  const float* sq = sqAll + (size_t)s * TT;
  const float* inv = invAll + (size_t)s * TT;
  __shared__ float k0[TT];
  __shared__ float k1[TT];
  __shared__ float wv[4];
  __shared__ int wi[4];
  __shared__ int sel_sh[2][KK];
  int lane = threadIdx.x & 63, w = threadIdx.x >> 6;
#pragma unroll
  for (int t = 0; t < 2; ++t) {
    int j4 = (t * 256 + threadIdx.x) * 4;
    float4 g4 = *(const float4*)&G[(size_t)i * TT + j4];
    float4 s4 = *(const float4*)&sq[j4];
    float4 v4 = *(const float4*)&inv[j4];
    k0[j4 + 0] = s4.x - 2.f * g4.x; k1[j4 + 0] = -g4.x * v4.x;
    k0[j4 + 1] = s4.y - 2.f * g4.y; k1[j4 + 1] = -g4.y * v4.y;
    k0[j4 + 2] = s4.z - 2.f * g4.z; k1[j4 + 2] = -g4.z * v4.z;
    k0[j4 + 3] = s4.w - 2.f * g4.w; k1[j4 + 3] = -g4.w * v4.w;
  }
  __syncthreads();
  if (threadIdx.x == 0) { k0[i] = INFINITY; k1[i] = INFINITY; }
  __syncthreads();
  for (int mode = 0; mode < 2; ++mode) {
    float* ks = mode ? k1 : k0;
    for (int r = 0; r < KK; ++r) {
      float best = INFINITY; int bidx = TT;
      for (int j = threadIdx.x; j < TT; j += 256) {
        float v = ks[j];
        if (v < best) { best = v; bidx = j; }
      }
#pragma unroll
      for (int off = 32; off > 0; off >>= 1) {
        float v2 = __shfl_down(best, off, 64);
        int i2 = __shfl_down(bidx, off, 64);
        if (v2 < best || (v2 == best && i2 < bidx)) { best = v2; bidx = i2; }
      }
      if (lane == 0) { wv[w] = best; wi[w] = bidx; }
      __syncthreads();
      if (threadIdx.x == 0) {
        float b2 = wv[0]; int x2 = wi[0];
#pragma unroll
        for (int q = 1; q < 4; ++q) {
          if (wv[q] < b2 || (wv[q] == b2 && wi[q] < x2)) { b2 = wv[q]; x2 = wi[q]; }
        }
        sel_sh[mode][r] = x2; ks[x2] = INFINITY;
      }
      __syncthreads();
    }
  }
  if (threadIdx.x < KK) {
    out0[((size_t)s * TT + i) * KK + threadIdx.x] = sel_sh[0][threadIdx.x];
    out1[((size_t)s * TT + i) * KK + threadIdx.x] = sel_sh[1][threadIdx.x];
  }
}

// ---------------- mutual matching, batched ----------------
__global__ __launch_bounds__(256) void mutual_batched(const int* __restrict__ b_of_a_all,
                                                      const int* __restrict__ a_of_b_all,
                                                      int* __restrict__ idxB_all, int* __restrict__ matchedB_all,
                                                      int* __restrict__ unmatched_all, int* __restrict__ scalars_all) {
  int p = blockIdx.x;
  const int* b_of_a = b_of_a_all + (size_t)p * TT;
  const int* a_of_b = a_of_b_all + (size_t)p * TT;
  int* idxB_of_A = idxB_all + (size_t)p * TT;
  int* matchedB = matchedB_all + (size_t)p * TT;
  int* unmatched = unmatched_all + (size_t)p * TT;
  __shared__ int cnt_sh;
  for (int j = threadIdx.x; j < TT; j += 256) matchedB[j] = 0;
  __syncthreads();
  for (int i = threadIdx.x; i < TT; i += 256) {
    int b = b_of_a[i];
    bool mut = (a_of_b[b] == i);
    idxB_of_A[i] = mut ? b : -1;
    if (mut) matchedB[b] = 1;
  }
  __syncthreads();
  if (threadIdx.x == 0) cnt_sh = 0;
  __syncthreads();
  for (int j = threadIdx.x; j < TT; j += 256) {
    if (!matchedB[j]) { int q = atomicAdd(&cnt_sh, 1); unmatched[q] = j; }
  }
  __syncthreads();
  if (threadIdx.x == 0) {
    int c = cnt_sh;
    if (c == 0) { unmatched[0] = 0; c = 1; }
    scalars_all[p * 16] = c;
  }
}

// ---------------- crossbrain hinge: 64 rows/block, 1 atomic/block ----------------
__global__ __launch_bounds__(256) void cb_hinge_block(const float* __restrict__ gram, const float* __restrict__ invAll,
                                                      const int* __restrict__ neigh1, float* __restrict__ cb_acc) {
  int c = blockIdx.y;
  int i0 = blockIdx.x * 64;
  int sa = c, sb = (c < 4) ? (c + 4) : (c - 4);
  const float* Gs = gram + (size_t)sb * TT * TT;
  const float* invB = invAll + (size_t)sb * TT;
  const int* neighA = neigh1 + (size_t)sa * TT * KK;
  unsigned int seed = 0x13579BDFu + 0x9E3779B9u * (unsigned)c;
  int tid = threadIdx.x;

  __shared__ int targ[64][10];
  __shared__ float sval[64][10];
  for (int t = tid; t < 64 * KK; t += 256) targ[t / KK][t % KK] = neighA[(size_t)i0 * KK + t];
  __syncthreads();
  if (tid < 64) {
    int i = i0 + tid;
    int pos[KK];
#pragma unroll
    for (int k = 0; k < KK; ++k) pos[k] = targ[tid][k];
    unsigned int ctr = 0;
    for (int k = 0; k < KK; ++k) {
      int cand;
      while (true) {
        unsigned int h = mix_hash(seed ^ (unsigned)i, ctr++);
        cand = (int)(h & (TT - 1));
        bool bad = (cand == i);
        for (int t = 0; t < KK; ++t) bad = bad || (cand == pos[t]);
        for (int t = 0; t < k; ++t) bad = bad || (cand == targ[tid][KK + t]);
        if (!bad) break;
      }
      targ[tid][KK + k] = cand;
    }
  }
  __syncthreads();
  for (int t = tid; t < 640; t += 256) {
    int il = t / 10, k = t % 10;
    int tt = targ[il][k];
    sval[il][k] = Gs[(size_t)(i0 + il) * TT + tt] * invB[tt];
  }
  __syncthreads();
  if (tid < 64) {
    int i = i0 + tid;
    float ii = invB[i];
    const float lo = -1.f + 1e-8f, hi = 1.f - 1e-8f;
    float hsum = 0.f;
#pragma unroll
    for (int k = 0; k < KK; ++k) {
      float sp = fminf(fmaxf(sval[tid][k] * ii, lo), hi);
      float sn = fminf(fmaxf(sval[tid][KK + k] * ii, lo), hi);
      float h = sn - sp + 0.05f;
      hsum += (h > 0.f) ? h : 0.f;
    }
#pragma unroll
    for (int off = 32; off > 0; off >>= 1) hsum += __shfl_down(hsum, off, 64);
    if (tid == 0) atomicAdd(&cb_acc[c], hsum);
  }
}

// ---------------- NRC hinge: 64 rows/block, 2 atomics/block ----------------
__global__ __launch_bounds__(256) void nrc_hinge_block(const float* __restrict__ gram, const float* __restrict__ invAll,
                                                       const int* __restrict__ neighC, const int* __restrict__ idxB_all,
                                                       const int* __restrict__ unmatched_all,
                                                       const int* __restrict__ scalars_all,
                                                       PairTab tab, float* __restrict__ nrc_acc) {
  int p = blockIdx.y;
  int i0 = blockIdx.x * 64;
  int sa = tab.sa[p], sb = tab.sb[p];
  const float* Gs = gram + (size_t)sb * TT * TT;
  const float* invB = invAll + (size_t)sb * TT;
  const int* neighA = neighC + (size_t)sa * TT * KK;
  const int* idxB_of_A = idxB_all + (size_t)p * TT;
  const int* unmatched = unmatched_all + (size_t)p * TT;
  unsigned int seed = 0xC0FFEE11u + 0x9E3779B9u * (unsigned)p;
  float* acc = nrc_acc + p * 2;
  int tid = threadIdx.x;

  __shared__ int targ[64][10];
  __shared__ float sval[64][10];
  __shared__ unsigned int tmask[64];
  __shared__ int su[64];
  if (tid < 64) { tmask[tid] = 0; su[tid] = idxB_of_A[i0 + tid]; }
  __syncthreads();
  unsigned int neg_count = (unsigned int)scalars_all[p * 16];
  for (int t = tid; t < 64 * KK; t += 256) {
    int il = t / KK, k = t % KK;
    int nb = neighA[(size_t)i0 * KK + t];
    int pb = idxB_of_A[nb];
    targ[il][k] = (pb >= 0) ? pb : 0;
    if (pb >= 0) atomicOr(&tmask[il], 1u << k);
  }
  for (int t = tid; t < 64 * KK; t += 256) {
    int il = t / KK, k = t % KK;
    int i = i0 + il;
    unsigned int r = mix_hash(seed ^ 0xA5A5u, (unsigned)(i * KK + k)) & (TT - 1);
    targ[il][KK + k] = unmatched[r % neg_count];
  }
  __syncthreads();
  for (int t = tid; t < 640; t += 256) {
    int il = t / 10, k = t % 10;
    int u = su[il] >= 0 ? su[il] : 0;
    int tt = targ[il][k];
    sval[il][k] = Gs[(size_t)u * TT + tt] * invB[tt];
  }
  __syncthreads();
  if (tid < 64) {
    int idx = su[tid];
    int u = idx >= 0 ? idx : 0;
    float iu = invB[u];
    unsigned int tm = tmask[tid];
    float hsum = 0.f; int pcnt = 0;
#pragma unroll
    for (int k = 0; k < KK; ++k) {
      if (tm & (1u << k)) {
        float dpos = 1.f - sval[tid][k] * iu;
        float dneg = 1.f - sval[tid][KK + k] * iu;
        float h = dpos - dneg + 0.4f;
        hsum += (h > 0.f) ? h : 0.f;
        pcnt++;
      }
    }
    float hs = 0.f, vc = 0.f;
    if (idx >= 0 && pcnt > 0) { hs = hsum / (float)pcnt; vc = 1.0f; }
#pragma unroll
    for (int off = 32; off > 0; off >>= 1) {
      hs += __shfl_down(hs, off, 64);
      vc += __shfl_down(vc, off, 64);
    }
    if (tid == 0) {
      atomicAdd(&acc[0], hs);
      atomicAdd(&acc[1], vc);
    }
  }
}

// ---------------- final combine ----------------
__global__ void final_kernel(const float* __restrict__ cb_acc, const float* __restrict__ nrc_acc,
                             float* __restrict__ out) {
  float loss2 = 0.f;
  for (int c = 0; c < 8; ++c) loss2 += cb_acc[c] * (1.0f / 10240.0f);
  loss2 *= 0.25f;
  float loss3 = 0.f;
  for (int d = 0; d < 2; ++d) {
    float s = 0.f;
    for (int t = 0; t < 6; ++t) {
      float cnt = nrc_acc[(d * 6 + t) * 2 + 1];
      float sum = nrc_acc[(d * 6 + t) * 2 + 0];
      s += (cnt > 0.f) ? (sum / cnt) : 0.f;
    }
    loss3 += s * (1.f / 6.f);
  }
  out[0] = 10.f * loss2 + 10.f * loss3;
}

// ---------------- host-side numpy RandomState(seed).permutation(12)[:6] ----------------
namespace {
struct MT19937 {
  uint32_t mt[624]; int mti;
  void seed(uint32_t s) {
    mt[0] = s;
    for (int i = 1; i < 624; ++i) mt[i] = 1812433253u * (mt[i - 1] ^ (mt[i - 1] >> 30)) + (uint32_t)i;
    mti = 624;
  }
  uint32_t next() {
    if (mti >= 624) {
      for (int i = 0; i < 624; ++i) {
        uint32_t y = (mt[i] & 0x80000000u) | (mt[(i + 1) % 624] & 0x7fffffffu);
        uint32_t v = y >> 1;
        if (y & 1u) v ^= 0x9908b0dfu;
        mt[i] = mt[(i + 397) % 624] ^ v;
      }
      mti = 0;
    }
    uint32_t y = mt[mti++];
    y ^= y >> 11; y ^= (y << 7) & 0x9d2c5680u; y ^= (y << 15) & 0xefc60000u; y ^= y >> 18;
    return y;
  }
  uint32_t interval(uint32_t mx) {
    uint32_t mask = mx;
    mask |= mask >> 1; mask |= mask >> 2; mask |= mask >> 4; mask |= mask >> 8; mask |= mask >> 16;
    while (true) { uint32_t v = next() & mask; if (v <= mx) return v; }
  }
};
inline void np_perm12_first6(uint32_t seed, int* sel6) {
  int a[12]; for (int i = 0; i < 12; ++i) a[i] = i;
  MT19937 r; r.seed(seed);
  for (int i = 11; i >= 1; --i) { uint32_t j = r.interval((uint32_t)i); int t = a[i]; a[i] = a[j]; a[j] = t; }
  for (int i = 0; i < 6; ++i) sel6[i] = a[i];
}
}  // namespace

extern "C" void kernel_launch(void* const* d_in, const int* in_sizes, int n_in,
                              void* d_out, int out_size, void* d_ws, size_t ws_size,
                              hipStream_t stream) {
  const float* z1 = (const float*)d_in[0];
  const float* z2 = (const float*)d_in[1];
  float* out = (float*)d_out;

  char* base = (char*)d_ws;
  size_t off = 0;
  auto alloc = [&](size_t bytes) -> void* {
    void* p = base + off;
    off = (off + bytes + 255) & ~(size_t)255;
    return p;
  };
  float* gram            = (float*)alloc((size_t)8 * TT * TT * 4);   // 134 MB self grams
  unsigned short* zb     = (unsigned short*)alloc((size_t)8 * TT * CC * 2);
  float* sq              = (float*)alloc((size_t)8 * TT * 4);
  float* inv             = (float*)alloc((size_t)8 * TT * 4);
  int*   neigh1          = (int*)alloc((size_t)8 * TT * KK * 4);
  int*   neighC          = (int*)alloc((size_t)8 * TT * KK * 4);
  float* prow_v          = (float*)alloc((size_t)12 * 16 * TT * 4);
  int*   prow_i          = (int*)alloc((size_t)12 * 16 * TT * 4);
  float* pcol_v          = (float*)alloc((size_t)12 * 16 * TT * 4);
  int*   pcol_i          = (int*)alloc((size_t)12 * 16 * TT * 4);
  int*   b_of_a          = (int*)alloc((size_t)12 * TT * 4);
  int*   a_of_b          = (int*)alloc((size_t)12 * TT * 4);
  int*   idxB            = (int*)alloc((size_t)12 * TT * 4);
  int*   matchedB        = (int*)alloc((size_t)12 * TT * 4);
  int*   unmatched       = (int*)alloc((size_t)12 * TT * 4);
  int*   scalars         = (int*)alloc(12 * 16 * 4);
  float* accs            = (float*)alloc(64 * 4);
  float* cb_acc          = accs;
  float* nrc_acc         = accs + 8;

  hipMemsetAsync(accs, 0, 64 * 4, stream);

  // NRC pair selection (numpy RandomState(seed).permutation(12)[:6])
  int sel0[6], sel1[6];
  np_perm12_first6(0u, sel0);
  np_perm12_first6(1u, sel1);
  static const int PP[12] = {0, 0, 0, 1, 1, 1, 2, 2, 2, 3, 3, 3};
  static const int QQ[12] = {1, 2, 3, 0, 2, 3, 0, 1, 3, 0, 1, 2};
  PairTab tab;
  for (int d = 0; d < 2; ++d) {
    const int* sel = (d == 0) ? sel0 : sel1;
    for (int t = 0; t < 6; ++t) {
      int pi_ = PP[sel[t]], qi = QQ[sel[t]];
      int p = d * 6 + t;
      tab.sa[p] = (d == 0) ? pi_ : 4 + pi_;
      tab.sb[p] = (d == 0) ? 4 + qi : qi;
    }
  }

  // fused prep (bf16 convert + norms)
  prep_kernel<<<8 * TT, 256, 0, stream>>>(z1, z2, zb, sq, inv);

  // unified gram: self upper-triangle (mirror store) + cross with fused argmin
  gram_all<<<N_SELF_BLK + N_CROSS_BLK, 256, 0, stream>>>(zb, gram, inv, tab, prow_v, prow_i, pcol_v, pcol_i);

  // self-dependent phase
  top5_batched<<<dim3(TT, 8), 256, 0, stream>>>(gram, sq, inv, neigh1, neighC);
  cb_hinge_block<<<dim3(TT / 64, 8), 256, 0, stream>>>(gram, inv, neigh1, cb_acc);

  // cross-dependent phase
  argmin_reduce_batched<<<dim3(2 * TT / 256, 12), 256, 0, stream>>>(prow_v, prow_i, pcol_v, pcol_i, b_of_a, a_of_b);
  mutual_batched<<<12, 256, 0, stream>>>(b_of_a, a_of_b, idxB, matchedB, unmatched, scalars);
  nrc_hinge_block<<<dim3(TT / 64, 12), 256, 0, stream>>>(gram, inv, neighC, idxB, unmatched, scalars, tab, nrc_acc);

  final_kernel<<<1, 1, 0, stream>>>(cb_acc, nrc_acc, out);
}

// Round 8
// 452.074 us; speedup vs baseline: 8.6625x; 1.0796x over previous
//
#include <hip/hip_runtime.h>
#include <cstdint>
#include <cstddef>

#define TT 2048
#define CC 768
#define KK 5

typedef __attribute__((ext_vector_type(8))) short short8;
typedef __attribute__((ext_vector_type(4))) float float4v;

struct PairTab { int sa[12]; int sb[12]; };

#define N_SELF_BLK (8 * 136)   // 8 slices x 136 upper-triangle 128x128 tiles
#define N_CROSS_BLK (12 * 256) // 12 pairs x 256 tiles

// ---------------- device RNG hash ----------------
__device__ __forceinline__ unsigned int mix_hash(unsigned int a, unsigned int b) {
  unsigned long long x = (((unsigned long long)a) << 32) | (unsigned long long)b;
  x ^= x >> 33; x *= 0xff51afd7ed558ccdULL;
  x ^= x >> 33; x *= 0xc4ceb9fe1a85ec53ULL;
  x ^= x >> 33;
  return (unsigned int)(x & 0xffffffffu);
}

__device__ __forceinline__ unsigned short f2bf(float x) {  // RNE fp32->bf16
  union { float f; unsigned int u; } v; v.f = x;
  unsigned int r = v.u + 0x7fffu + ((v.u >> 16) & 1u);
  return (unsigned short)(r >> 16);
}

__device__ __forceinline__ void gload_lds16(const void* g, void* l) {
  __builtin_amdgcn_global_load_lds(
      (const __attribute__((address_space(1))) unsigned int*)g,
      (__attribute__((address_space(3))) unsigned int*)l, 16, 0, 0);
}

// ---------------- fused prep: fp32->bf16 + row sumsq/inv-norm ----------------
__global__ __launch_bounds__(192) void prep_kernel(const float* __restrict__ z1, const float* __restrict__ z2,
                                                   unsigned short* __restrict__ zb, float* __restrict__ sq,
                                                   float* __restrict__ inv) {
  int r = blockIdx.x;  // 0..16383
  const float* p = (r < 4 * TT) ? (z1 + (size_t)r * CC) : (z2 + (size_t)(r - 4 * TT) * CC);
  unsigned short* o = zb + (size_t)r * CC;
  float4 v = ((const float4*)p)[threadIdx.x];
  float s = v.x * v.x + v.y * v.y + v.z * v.z + v.w * v.w;
  ushort4 u;
  u.x = f2bf(v.x); u.y = f2bf(v.y); u.z = f2bf(v.z); u.w = f2bf(v.w);
  ((ushort4*)o)[threadIdx.x] = u;
#pragma unroll
  for (int off = 32; off > 0; off >>= 1) s += __shfl_down(s, off, 64);
  __shared__ float wred[3];
  int lane = threadIdx.x & 63, w = threadIdx.x >> 6;
  if (lane == 0) wred[w] = s;
  __syncthreads();
  if (threadIdx.x == 0) {
    float tot = wred[0] + wred[1] + wred[2];
    sq[r] = tot; inv[r] = rsqrtf(tot + 1e-12f);
  }
}

// ---------------- unified gram kernel: BK=64, XOR-swizzled LDS ----------------
__global__ __launch_bounds__(256) void gram_all(const unsigned short* __restrict__ zb, float* __restrict__ gram,
                                                const float* __restrict__ invAll, PairTab tab,
                                                float* __restrict__ prow_v, int* __restrict__ prow_i,
                                                float* __restrict__ pcol_v, int* __restrict__ pcol_i) {
  __shared__ unsigned short As[128 * 64];
  __shared__ unsigned short Bs[128 * 64];
  __shared__ float sInvA[128], sInvB[128];
  __shared__ float rowv[2][128]; __shared__ int rowi[2][128];
  __shared__ float colv[2][128]; __shared__ int coli[2][128];

  const int bid = blockIdx.x;
  const bool isSelf = bid < N_SELF_BLK;
  int bm, bn, p = 0, s = 0;
  const unsigned short *A, *B;
  if (isSelf) {
    s = bid / 136;
    int t = bid % 136;
    int ti = 0;
    while (t >= 16 - ti) { t -= 16 - ti; ++ti; }
    int tj = ti + t;           // ti <= tj
    bm = ti * 128; bn = tj * 128;
    A = zb + (size_t)s * TT * CC;
    B = A;
  } else {
    int cb = bid - N_SELF_BLK;
    p = cb >> 8;
    int tile = cb & 255;
    bn = (tile & 15) * 128;
    bm = (tile >> 4) * 128;
    A = zb + (size_t)tab.sa[p] * TT * CC;
    B = zb + (size_t)tab.sb[p] * TT * CC;
    const float* invA = invAll + (size_t)tab.sa[p] * TT;
    const float* invB = invAll + (size_t)tab.sb[p] * TT;
    if (threadIdx.x < 128) sInvA[threadIdx.x] = invA[bm + threadIdx.x];
    else sInvB[threadIdx.x - 128] = invB[bn + threadIdx.x - 128];
  }
  const int lane = threadIdx.x & 63, waveId = threadIdx.x >> 6;
  const int wm = (waveId >> 1) * 64, wn = (waveId & 1) * 64;
  const int lrow = lane & 15, lquad = lane >> 4;

  float4v acc[4][4];
#pragma unroll
  for (int i = 0; i < 4; ++i)
#pragma unroll
    for (int j = 0; j < 4; ++j) acc[i][j] = (float4v){0.f, 0.f, 0.f, 0.f};

  for (int kk = 0; kk < CC; kk += 64) {
    // stage 128x64 per matrix; LDS slot l holds global chunk (l&7)^(row&7) -> swizzled layout
#pragma unroll
    for (int c = 0; c < 4; ++c) {
      int l = c * 256 + threadIdx.x;        // 0..1023 chunks of 8 shorts
      int row = l >> 3, pc = l & 7;
      int sc = pc ^ (row & 7);
      gload_lds16(A + (size_t)(bm + row) * CC + kk + sc * 8, &As[l * 8]);
      gload_lds16(B + (size_t)(bn + row) * CC + kk + sc * 8, &Bs[l * 8]);
    }
    __syncthreads();
#pragma unroll
    for (int h = 0; h < 2; ++h) {
      short8 af[4], bfr[4];
#pragma unroll
      for (int i = 0; i < 4; ++i) {
        int ra = wm + i * 16 + lrow;
        int ca = (h * 4 + lquad) ^ (ra & 7);
        af[i] = *(const short8*)&As[ra * 64 + ca * 8];
        int rb = wn + i * 16 + lrow;
        int cb2 = (h * 4 + lquad) ^ (rb & 7);
        bfr[i] = *(const short8*)&Bs[rb * 64 + cb2 * 8];
      }
#pragma unroll
      for (int i = 0; i < 4; ++i)
#pragma unroll
        for (int j = 0; j < 4; ++j)
          acc[i][j] = __builtin_amdgcn_mfma_f32_16x16x32_bf16(af[i], bfr[j], acc[i][j], 0, 0, 0);
    }
    __syncthreads();
  }

  if (isSelf) {
    float* G = gram + (size_t)s * TT * TT;
    bool offdiag = (bm != bn);
#pragma unroll
    for (int i = 0; i < 4; ++i) {
      int row0 = bm + wm + i * 16 + lquad * 4;
#pragma unroll
      for (int j = 0; j < 4; ++j) {
        int col = bn + wn + j * 16 + lrow;
#pragma unroll
        for (int r = 0; r < 4; ++r) {
          G[(size_t)(row0 + r) * TT + col] = acc[i][j][r];
          if (offdiag) G[(size_t)col * TT + (row0 + r)] = acc[i][j][r];
        }
      }
    }
    return;
  }

  // ---- cross: fused dual argmin partials ----
  float rbv[4][4]; int rbi[4][4];
#pragma unroll
  for (int i = 0; i < 4; ++i)
#pragma unroll
    for (int r = 0; r < 4; ++r) { rbv[i][r] = INFINITY; rbi[i][r] = TT; }
#pragma unroll
  for (int i = 0; i < 4; ++i)
#pragma unroll
    for (int j = 0; j < 4; ++j) {
      int col = bn + wn + j * 16 + lrow;
      float ivb = sInvB[wn + j * 16 + lrow];
#pragma unroll
      for (int r = 0; r < 4; ++r) {
        float v = -acc[i][j][r] * ivb;
        if (v < rbv[i][r]) { rbv[i][r] = v; rbi[i][r] = col; }
      }
    }
#pragma unroll
  for (int m = 1; m <= 8; m <<= 1) {
#pragma unroll
    for (int i = 0; i < 4; ++i)
#pragma unroll
      for (int r = 0; r < 4; ++r) {
        float v2 = __shfl_xor(rbv[i][r], m, 64);
        int i2 = __shfl_xor(rbi[i][r], m, 64);
        if (v2 < rbv[i][r] || (v2 == rbv[i][r] && i2 < rbi[i][r])) { rbv[i][r] = v2; rbi[i][r] = i2; }
      }
  }
  if (lrow == 0) {
#pragma unroll
    for (int i = 0; i < 4; ++i)
#pragma unroll
      for (int r = 0; r < 4; ++r) {
        int lr = wm + i * 16 + lquad * 4 + r;
        rowv[wn >> 6][lr] = rbv[i][r]; rowi[wn >> 6][lr] = rbi[i][r];
      }
  }

  float cbv[4]; int cbi[4];
#pragma unroll
  for (int j = 0; j < 4; ++j) { cbv[j] = INFINITY; cbi[j] = TT; }
#pragma unroll
  for (int j = 0; j < 4; ++j)
#pragma unroll
    for (int i = 0; i < 4; ++i)
#pragma unroll
      for (int r = 0; r < 4; ++r) {
        int lr = wm + i * 16 + lquad * 4 + r;
        float v = -acc[i][j][r] * sInvA[lr];
        if (v < cbv[j]) { cbv[j] = v; cbi[j] = bm + lr; }
      }
#pragma unroll
  for (int m = 16; m <= 32; m <<= 1) {
#pragma unroll
    for (int j = 0; j < 4; ++j) {
      float v2 = __shfl_xor(cbv[j], m, 64);
      int i2 = __shfl_xor(cbi[j], m, 64);
      if (v2 < cbv[j] || (v2 == cbv[j] && i2 < cbi[j])) { cbv[j] = v2; cbi[j] = i2; }
    }
  }
  if (lquad == 0) {
#pragma unroll
    for (int j = 0; j < 4; ++j) {
      int lc = wn + j * 16 + lrow;
      colv[wm >> 6][lc] = cbv[j]; coli[wm >> 6][lc] = cbi[j];
    }
  }
  __syncthreads();

  int bj = bn >> 7, bi = bm >> 7;
  if (threadIdx.x < 128) {
    int t = threadIdx.x;
    float v0 = rowv[0][t], v1 = rowv[1][t];
    int i0 = rowi[0][t], i1 = rowi[1][t];
    bool take1 = (v1 < v0) || (v1 == v0 && i1 < i0);
    prow_v[((size_t)p * 16 + bj) * TT + bm + t] = take1 ? v1 : v0;
    prow_i[((size_t)p * 16 + bj) * TT + bm + t] = take1 ? i1 : i0;
  } else {
    int t = threadIdx.x - 128;
    float v0 = colv[0][t], v1 = colv[1][t];
    int i0 = coli[0][t], i1 = coli[1][t];
    bool take1 = (v1 < v0) || (v1 == v0 && i1 < i0);
    pcol_v[((size_t)p * 16 + bi) * TT + bn + t] = take1 ? v1 : v0;
    pcol_i[((size_t)p * 16 + bi) * TT + bn + t] = take1 ? i1 : i0;
  }
}

// ---------------- argmin stage 2 ----------------
__global__ __launch_bounds__(256) void argmin_reduce_batched(const float* __restrict__ prow_v, const int* __restrict__ prow_i,
                                                             const float* __restrict__ pcol_v, const int* __restrict__ pcol_i,
                                                             int* __restrict__ b_of_a, int* __restrict__ a_of_b) {
  int p = blockIdx.y;
  int t = blockIdx.x * 256 + threadIdx.x;
  int isRow = t < TT;
  int x = isRow ? t : t - TT;
  const float* pv = (isRow ? prow_v : pcol_v) + (size_t)p * 16 * TT;
  const int* pi = (isRow ? prow_i : pcol_i) + (size_t)p * 16 * TT;
  float best = INFINITY; int bidx = TT;
  for (int s = 0; s < 16; ++s) {
    float v = pv[(size_t)s * TT + x]; int id = pi[(size_t)s * TT + x];
    if (v < best || (v == best && id < bidx)) { best = v; bidx = id; }
  }
  if (isRow) b_of_a[(size_t)p * TT + x] = bidx;
  else       a_of_b[(size_t)p * TT + x] = bidx;
}

// ---------------- single-pass dual top-5: one wave per row ----------------
__device__ __forceinline__ bool lexlt(float k1, int i1, float k2, int i2) {
  return k1 < k2 || (k1 == k2 && i1 < i2);
}

#define INS5(kk_, ii_, L)                                                        \
  if (lexlt(kk_, ii_, L##k[4], L##i[4])) {                                       \
    L##k[4] = kk_; L##i[4] = ii_;                                                \
    if (lexlt(L##k[4], L##i[4], L##k[3], L##i[3])) {                             \
      float tk = L##k[3]; int ti_ = L##i[3]; L##k[3] = L##k[4]; L##i[3] = L##i[4]; L##k[4] = tk; L##i[4] = ti_; \
      if (lexlt(L##k[3], L##i[3], L##k[2], L##i[2])) {                           \
        tk = L##k[2]; ti_ = L##i[2]; L##k[2] = L##k[3]; L##i[2] = L##i[3]; L##k[3] = tk; L##i[3] = ti_; \
        if (lexlt(L##k[2], L##i[2], L##k[1], L##i[1])) {                         \
          tk = L##k[1]; ti_ = L##i[1]; L##k[1] = L##k[2]; L##i[1] = L##i[2]; L##k[2] = tk; L##i[2] = ti_; \
          if (lexlt(L##k[1], L##i[1], L##k[0], L##i[0])) {                       \
            tk = L##k[0]; ti_ = L##i[0]; L##k[0] = L##k[1]; L##i[0] = L##i[1]; L##k[1] = tk; L##i[1] = ti_; \
          }                                                                      \
        }                                                                        \
      }                                                                          \
    }                                                                            \
  }

__global__ __launch_bounds__(256) void top5_batched(const float* __restrict__ gram, const float* __restrict__ sqAll,
                                                    const float* __restrict__ invAll, int* __restrict__ out0,
                                                    int* __restrict__ out1) {
  int s = blockIdx.y;
  int w = threadIdx.x >> 6, lane = threadIdx.x & 63;
  int i = blockIdx.x * 4 + w;
  const float* G = gram + (size_t)s * TT * TT + (size_t)i * TT;
  const float* sq = sqAll + (size_t)s * TT;
  const float* inv = invAll + (size_t)s * TT;

  float ak[5]; int ai[5];   // mode0 (sq-dist)
  float bk[5]; int bi[5];   // mode1 (cos-dist)
#pragma unroll
  for (int t = 0; t < 5; ++t) { ak[t] = INFINITY; ai[t] = TT; bk[t] = INFINITY; bi[t] = TT; }

#pragma unroll
  for (int step = 0; step < 8; ++step) {
    int j4 = (step * 64 + lane) * 4;
    float4 g4 = *(const float4*)&G[j4];
    float4 s4 = *(const float4*)&sq[j4];
    float4 v4 = *(const float4*)&inv[j4];
#pragma unroll
    for (int c = 0; c < 4; ++c) {
      int j = j4 + c;
      float g = (c == 0) ? g4.x : (c == 1) ? g4.y : (c == 2) ? g4.z : g4.w;
      float sv = (c == 0) ? s4.x : (c == 1) ? s4.y : (c == 2) ? s4.z : s4.w;
      float iv = (c == 0) ? v4.x : (c == 1) ? v4.y : (c == 2) ? v4.z : v4.w;
      float k0 = (j == i) ? INFINITY : sv - 2.f * g;
      float k1 = (j == i) ? INFINITY : -g * iv;
      INS5(k0, j, a)
      INS5(k1, j, b)
    }
  }
  // butterfly merge across 64 lanes
#pragma unroll
  for (int m = 1; m <= 32; m <<= 1) {
    float ok[5]; int oi[5];
#pragma unroll
    for (int t = 0; t < 5; ++t) { ok[t] = __shfl_xor(ak[t], m, 64); oi[t] = __shfl_xor(ai[t], m, 64); }
#pragma unroll
    for (int t = 0; t < 5; ++t) { INS5(ok[t], oi[t], a) }
#pragma unroll
    for (int t = 0; t < 5; ++t) { ok[t] = __shfl_xor(bk[t], m, 64); oi[t] = __shfl_xor(bi[t], m, 64); }
#pragma unroll
    for (int t = 0; t < 5; ++t) { INS5(ok[t], oi[t], b) }
  }
  if (lane < KK) {
    int v0 = (lane == 0) ? ai[0] : (lane == 1) ? ai[1] : (lane == 2) ? ai[2] : (lane == 3) ? ai[3] : ai[4];
    int v1 = (lane == 0) ? bi[0] : (lane == 1) ? bi[1] : (lane == 2) ? bi[2] : (lane == 3) ? bi[3] : bi[4];
    out0[((size_t)s * TT + i) * KK + lane] = v0;
    out1[((size_t)s * TT + i) * KK + lane] = v1;
  }
}

// ---------------- mutual matching, batched ----------------
__global__ __launch_bounds__(256) void mutual_batched(const int* __restrict__ b_of_a_all,
                                                      const int* __restrict__ a_of_b_all,
                                                      int* __restrict__ idxB_all, int* __restrict__ matchedB_all,
                                                      int* __restrict__ unmatched_all, int* __restrict__ scalars_all) {
  int p = blockIdx.x;
  const int* b_of_a = b_of_a_all + (size_t)p * TT;
  const int* a_of_b = a_of_b_all + (size_t)p * TT;
  int* idxB_of_A = idxB_all + (size_t)p * TT;
  int* matchedB = matchedB_all + (size_t)p * TT;
  int* unmatched = unmatched_all + (size_t)p * TT;
  __shared__ int cnt_sh;
  for (int j = threadIdx.x; j < TT; j += 256) matchedB[j] = 0;
  __syncthreads();
  for (int i = threadIdx.x; i < TT; i += 256) {
    int b = b_of_a[i];
    bool mut = (a_of_b[b] == i);
    idxB_of_A[i] = mut ? b : -1;
    if (mut) matchedB[b] = 1;
  }
  __syncthreads();
  if (threadIdx.x == 0) cnt_sh = 0;
  __syncthreads();
  for (int j = threadIdx.x; j < TT; j += 256) {
    if (!matchedB[j]) { int q = atomicAdd(&cnt_sh, 1); unmatched[q] = j; }
  }
  __syncthreads();
  if (threadIdx.x == 0) {
    int c = cnt_sh;
    if (c == 0) { unmatched[0] = 0; c = 1; }
    scalars_all[p * 16] = c;
  }
}

// ---------------- crossbrain hinge: 64 rows/block, 1 atomic/block ----------------
__global__ __launch_bounds__(256) void cb_hinge_block(const float* __restrict__ gram, const float* __restrict__ invAll,
                                                      const int* __restrict__ neigh1, float* __restrict__ cb_acc) {
  int c = blockIdx.y;
  int i0 = blockIdx.x * 64;
  int sa = c, sb = (c < 4) ? (c + 4) : (c - 4);
  const float* Gs = gram + (size_t)sb * TT * TT;
  const float* invB = invAll + (size_t)sb * TT;
  const int* neighA = neigh1 + (size_t)sa * TT * KK;
  unsigned int seed = 0x13579BDFu + 0x9E3779B9u * (unsigned)c;
  int tid = threadIdx.x;

  __shared__ int targ[64][10];
  __shared__ float sval[64][10];
  for (int t = tid; t < 64 * KK; t += 256) targ[t / KK][t % KK] = neighA[(size_t)i0 * KK + t];
  __syncthreads();
  if (tid < 64) {
    int i = i0 + tid;
    int pos[KK];
#pragma unroll
    for (int k = 0; k < KK; ++k) pos[k] = targ[tid][k];
    unsigned int ctr = 0;
    for (int k = 0; k < KK; ++k) {
      int cand;
      while (true) {
        unsigned int h = mix_hash(seed ^ (unsigned)i, ctr++);
        cand = (int)(h & (TT - 1));
        bool bad = (cand == i);
        for (int t = 0; t < KK; ++t) bad = bad || (cand == pos[t]);
        for (int t = 0; t < k; ++t) bad = bad || (cand == targ[tid][KK + t]);
        if (!bad) break;
      }
      targ[tid][KK + k] = cand;
    }
  }
  __syncthreads();
  for (int t = tid; t < 640; t += 256) {
    int il = t / 10, k = t % 10;
    int tt = targ[il][k];
    sval[il][k] = Gs[(size_t)(i0 + il) * TT + tt] * invB[tt];
  }
  __syncthreads();
  if (tid < 64) {
    int i = i0 + tid;
    float ii = invB[i];
    const float lo = -1.f + 1e-8f, hi = 1.f - 1e-8f;
    float hsum = 0.f;
#pragma unroll
    for (int k = 0; k < KK; ++k) {
      float sp = fminf(fmaxf(sval[tid][k] * ii, lo), hi);
      float sn = fminf(fmaxf(sval[tid][KK + k] * ii, lo), hi);
      float h = sn - sp + 0.05f;
      hsum += (h > 0.f) ? h : 0.f;
    }
#pragma unroll
    for (int off = 32; off > 0; off >>= 1) hsum += __shfl_down(hsum, off, 64);
    if (tid == 0) atomicAdd(&cb_acc[c], hsum);
  }
}

// ---------------- NRC hinge: 64 rows/block, 2 atomics/block ----------------
__global__ __launch_bounds__(256) void nrc_hinge_block(const float* __restrict__ gram, const float* __restrict__ invAll,
                                                       const int* __restrict__ neighC, const int* __restrict__ idxB_all,
                                                       const int* __restrict__ unmatched_all,
                                                       const int* __restrict__ scalars_all,
                                                       PairTab tab, float* __restrict__ nrc_acc) {
  int p = blockIdx.y;
  int i0 = blockIdx.x * 64;
  int sa = tab.sa[p], sb = tab.sb[p];
  const float* Gs = gram + (size_t)sb * TT * TT;
  const float* invB = invAll + (size_t)sb * TT;
  const int* neighA = neighC + (size_t)sa * TT * KK;
  const int* idxB_of_A = idxB_all + (size_t)p * TT;
  const int* unmatched = unmatched_all + (size_t)p * TT;
  unsigned int seed = 0xC0FFEE11u + 0x9E3779B9u * (unsigned)p;
  float* acc = nrc_acc + p * 2;
  int tid = threadIdx.x;

  __shared__ int targ[64][10];
  __shared__ float sval[64][10];
  __shared__ unsigned int tmask[64];
  __shared__ int su[64];
  if (tid < 64) { tmask[tid] = 0; su[tid] = idxB_of_A[i0 + tid]; }
  __syncthreads();
  unsigned int neg_count = (unsigned int)scalars_all[p * 16];
  for (int t = tid; t < 64 * KK; t += 256) {
    int il = t / KK, k = t % KK;
    int nb = neighA[(size_t)i0 * KK + t];
    int pb = idxB_of_A[nb];
    targ[il][k] = (pb >= 0) ? pb : 0;
    if (pb >= 0) atomicOr(&tmask[il], 1u << k);
  }
  for (int t = tid; t < 64 * KK; t += 256) {
    int il = t / KK, k = t % KK;
    int i = i0 + il;
    unsigned int r = mix_hash(seed ^ 0xA5A5u, (unsigned)(i * KK + k)) & (TT - 1);
    targ[il][KK + k] = unmatched[r % neg_count];
  }
  __syncthreads();
  for (int t = tid; t < 640; t += 256) {
    int il = t / 10, k = t % 10;
    int u = su[il] >= 0 ? su[il] : 0;
    int tt = targ[il][k];
    sval[il][k] = Gs[(size_t)u * TT + tt] * invB[tt];
  }
  __syncthreads();
  if (tid < 64) {
    int idx = su[tid];
    int u = idx >= 0 ? idx : 0;
    float iu = invB[u];
    unsigned int tm = tmask[tid];
    float hsum = 0.f; int pcnt = 0;
#pragma unroll
    for (int k = 0; k < KK; ++k) {
      if (tm & (1u << k)) {
        float dpos = 1.f - sval[tid][k] * iu;
        float dneg = 1.f - sval[tid][KK + k] * iu;
        float h = dpos - dneg + 0.4f;
        hsum += (h > 0.f) ? h : 0.f;
        pcnt++;
      }
    }
    float hs = 0.f, vc = 0.f;
    if (idx >= 0 && pcnt > 0) { hs = hsum / (float)pcnt; vc = 1.0f; }
#pragma unroll
    for (int off = 32; off > 0; off >>= 1) {
      hs += __shfl_down(hs, off, 64);
      vc += __shfl_down(vc, off, 64);
    }
    if (tid == 0) {
      atomicAdd(&acc[0], hs);
      atomicAdd(&acc[1], vc);
    }
  }
}

// ---------------- final combine ----------------
__global__ void final_kernel(const float* __restrict__ cb_acc, const float* __restrict__ nrc_acc,
                             float* __restrict__ out) {
  float loss2 = 0.f;
  for (int c = 0; c < 8; ++c) loss2 += cb_acc[c] * (1.0f / 10240.0f);
  loss2 *= 0.25f;
  float loss3 = 0.f;
  for (int d = 0; d < 2; ++d) {
    float s = 0.f;
    for (int t = 0; t < 6; ++t) {
      float cnt = nrc_acc[(d * 6 + t) * 2 + 1];
      float sum = nrc_acc[(d * 6 + t) * 2 + 0];
      s += (cnt > 0.f) ? (sum / cnt) : 0.f;
    }
    loss3 += s * (1.f / 6.f);
  }
  out[0] = 10.f * loss2 + 10.f * loss3;
}

// ---------------- host-side numpy RandomState(seed).permutation(12)[:6] ----------------
namespace {
struct MT19937 {
  uint32_t mt[624]; int mti;
  void seed(uint32_t s) {
    mt[0] = s;
    for (int i = 1; i < 624; ++i) mt[i] = 1812433253u * (mt[i - 1] ^ (mt[i - 1] >> 30)) + (uint32_t)i;
    mti = 624;
  }
  uint32_t next() {
    if (mti >= 624) {
      for (int i = 0; i < 624; ++i) {
        uint32_t y = (mt[i] & 0x80000000u) | (mt[(i + 1) % 624] & 0x7fffffffu);
        uint32_t v = y >> 1;
        if (y & 1u) v ^= 0x9908b0dfu;
        mt[i] = mt[(i + 397) % 624] ^ v;
      }
      mti = 0;
    }
    uint32_t y = mt[mti++];
    y ^= y >> 11; y ^= (y << 7) & 0x9d2c5680u; y ^= (y << 15) & 0xefc60000u; y ^= y >> 18;
    return y;
  }
  uint32_t interval(uint32_t mx) {
    uint32_t mask = mx;
    mask |= mask >> 1; mask |= mask >> 2; mask |= mask >> 4; mask |= mask >> 8; mask |= mask >> 16;
    while (true) { uint32_t v = next() & mask; if (v <= mx) return v; }
  }
};
inline void np_perm12_first6(uint32_t seed, int* sel6) {
  int a[12]; for (int i = 0; i < 12; ++i) a[i] = i;
  MT19937 r; r.seed(seed);
  for (int i = 11; i >= 1; --i) { uint32_t j = r.interval((uint32_t)i); int t = a[i]; a[i] = a[j]; a[j] = t; }
  for (int i = 0; i < 6; ++i) sel6[i] = a[i];
}
}  // namespace

extern "C" void kernel_launch(void* const* d_in, const int* in_sizes, int n_in,
                              void* d_out, int out_size, void* d_ws, size_t ws_size,
                              hipStream_t stream) {
  const float* z1 = (const float*)d_in[0];
  const float* z2 = (const float*)d_in[1];
  float* out = (float*)d_out;

  char* base = (char*)d_ws;
  size_t off = 0;
  auto alloc = [&](size_t bytes) -> void* {
    void* p = base + off;
    off = (off + bytes + 255) & ~(size_t)255;
    return p;
  };
  float* gram            = (float*)alloc((size_t)8 * TT * TT * 4);   // 134 MB self grams
  unsigned short* zb     = (unsigned short*)alloc((size_t)8 * TT * CC * 2);
  float* sq              = (float*)alloc((size_t)8 * TT * 4);
  float* inv             = (float*)alloc((size_t)8 * TT * 4);
  int*   neigh1          = (int*)alloc((size_t)8 * TT * KK * 4);
  int*   neighC          = (int*)alloc((size_t)8 * TT * KK * 4);
  float* prow_v          = (float*)alloc((size_t)12 * 16 * TT * 4);
  int*   prow_i          = (int*)alloc((size_t)12 * 16 * TT * 4);
  float* pcol_v          = (float*)alloc((size_t)12 * 16 * TT * 4);
  int*   pcol_i          = (int*)alloc((size_t)12 * 16 * TT * 4);
  int*   b_of_a          = (int*)alloc((size_t)12 * TT * 4);
  int*   a_of_b          = (int*)alloc((size_t)12 * TT * 4);
  int*   idxB            = (int*)alloc((size_t)12 * TT * 4);
  int*   matchedB        = (int*)alloc((size_t)12 * TT * 4);
  int*   unmatched       = (int*)alloc((size_t)12 * TT * 4);
  int*   scalars         = (int*)alloc(12 * 16 * 4);
  float* accs            = (float*)alloc(64 * 4);
  float* cb_acc          = accs;
  float* nrc_acc         = accs + 8;

  hipMemsetAsync(accs, 0, 64 * 4, stream);

  // NRC pair selection (numpy RandomState(seed).permutation(12)[:6])
  int sel0[6], sel1[6];
  np_perm12_first6(0u, sel0);
  np_perm12_first6(1u, sel1);
  static const int PP[12] = {0, 0, 0, 1, 1, 1, 2, 2, 2, 3, 3, 3};
  static const int QQ[12] = {1, 2, 3, 0, 2, 3, 0, 1, 3, 0, 1, 2};
  PairTab tab;
  for (int d = 0; d < 2; ++d) {
    const int* sel = (d == 0) ? sel0 : sel1;
    for (int t = 0; t < 6; ++t) {
      int pi_ = PP[sel[t]], qi = QQ[sel[t]];
      int p = d * 6 + t;
      tab.sa[p] = (d == 0) ? pi_ : 4 + pi_;
      tab.sb[p] = (d == 0) ? 4 + qi : qi;
    }
  }

  // fused prep (bf16 convert + norms), 192 threads = 3 waves, all active
  prep_kernel<<<8 * TT, 192, 0, stream>>>(z1, z2, zb, sq, inv);

  // unified gram: self upper-triangle (mirror store) + cross with fused argmin
  gram_all<<<N_SELF_BLK + N_CROSS_BLK, 256, 0, stream>>>(zb, gram, inv, tab, prow_v, prow_i, pcol_v, pcol_i);

  // self-dependent phase
  top5_batched<<<dim3(TT / 4, 8), 256, 0, stream>>>(gram, sq, inv, neigh1, neighC);
  cb_hinge_block<<<dim3(TT / 64, 8), 256, 0, stream>>>(gram, inv, neigh1, cb_acc);

  // cross-dependent phase
  argmin_reduce_batched<<<dim3(2 * TT / 256, 12), 256, 0, stream>>>(prow_v, prow_i, pcol_v, pcol_i, b_of_a, a_of_b);
  mutual_batched<<<12, 256, 0, stream>>>(b_of_a, a_of_b, idxB, matchedB, unmatched, scalars);
  nrc_hinge_block<<<dim3(TT / 64, 12), 256, 0, stream>>>(gram, inv, neighC, idxB, unmatched, scalars, tab, nrc_acc);

  final_kernel<<<1, 1, 0, stream>>>(cb_acc, nrc_acc, out);
}